// Round 2
// baseline (589.465 us; speedup 1.0000x reference)
//
#include <hip/hip_runtime.h>
#include <math.h>

// ---------------------------------------------------------------------------
// FrameTransformer — R10: VALU-debt reduction + 128x128 tiles where fill=1/CU.
//  * sgemm_exp_k: K-loop peeled into two compile-time halves (kills per-iter
//    source-select address chains); __expf epilogue (VALU 40% was the cap).
//  * glugemm sigmoid -> __expf.
//  * c1L/c1M/o/c3/aogemm moved 128x64 -> 128x128 tiles (exactly 256 blocks
//    = 1/CU; doubles MFMA per staged byte, halves staging volume).
// R9 launch fusion + operand dedup + plane->XCD affinity kept.
// ---------------------------------------------------------------------------

typedef unsigned short u16;
typedef __attribute__((ext_vector_type(4))) float floatx4;
typedef __attribute__((ext_vector_type(8))) short short8;

#define NB 4
static const long long M1 = 1024LL * 1024LL;

__device__ __forceinline__ float bf2f(u16 h) {
    union { unsigned int u; float f; } v;
    v.u = ((unsigned int)h) << 16;
    return v.f;
}
__device__ __forceinline__ u16 f2bf(float x) {
    union { float f; unsigned int u; } v;
    v.f = x;
    unsigned int r = (v.u + 0x7FFFu + ((v.u >> 16) & 1u)) >> 16;
    return (u16)r;
}

__device__ __forceinline__ void async_cp16(const u16* g, u16* lds) {
    __builtin_amdgcn_global_load_lds(
        (const __attribute__((address_space(1))) unsigned int*)g,
        (__attribute__((address_space(3))) unsigned int*)lds, 16, 0, 0);
}

__device__ __forceinline__ float block_sum(float v) {
    __shared__ float sd[4];
    #pragma unroll
    for (int off = 32; off; off >>= 1) v += __shfl_down(v, off, 64);
    int lane = threadIdx.x & 63, wid = threadIdx.x >> 6;
    __syncthreads();
    if (lane == 0) sd[wid] = v;
    __syncthreads();
    return sd[0] + sd[1] + sd[2] + sd[3];
}

// ---------------------------------------------------------------------------
// bf16 NT GEMM: C[M,N] (op)= act( scale*(A·B^T + bias) )
// OUT: 0 = f32 store, 1 = f32 accum, 2 = bf16 store, 3 = bf16 accum.
// ---------------------------------------------------------------------------
template<int BM, int BN, int ACT, int OUT>
__global__ __launch_bounds__(256)
void gemm_bf(const u16* __restrict__ A, const u16* __restrict__ B,
             void* __restrict__ Cv, int K, int lda, int ldb, int ldc,
             long long sAz, long long sBz, long long sCz,
             const float* __restrict__ bias, float scale)
{
    constexpr int MI = BM / 32;
    constexpr int NJ = BN / 32;

    A += (long long)blockIdx.z * sAz;
    B += (long long)blockIdx.z * sBz;
    const long long zc = (long long)blockIdx.z * sCz;

    __shared__ u16 As[BM * 64];
    __shared__ u16 Bs[BN * 64];

    const int id = blockIdx.x + gridDim.x * blockIdx.y;
    const int bx = (id >> 3) % gridDim.x;
    const int by = (id & 7) + 8 * ((id >> 3) / gridDim.x);
    const int m0 = by * BM;
    const int n0 = bx * BN;

    const int lane = threadIdx.x & 63;
    const int w    = threadIdx.x >> 6;
    const int wm   = (w >> 1) * (BM / 2);
    const int wn   = (w & 1) * (BN / 2);
    const int srow = lane >> 2;
    const int scol = (lane & 3) * 8;

    floatx4 acc[MI][NJ];
    #pragma unroll
    for (int i = 0; i < MI; i++)
        #pragma unroll
        for (int j = 0; j < NJ; j++)
            acc[i][j] = floatx4{0.f, 0.f, 0.f, 0.f};

    for (int k0 = 0; k0 < K; k0 += 64) {
        #pragma unroll
        for (int r = 0; r < BM / 32; r++) {
            const int inst = w * (BM / 32) + r;
            const int rg = inst >> 1, kb = inst & 1;
            async_cp16(A + (long long)(m0 + rg * 16 + srow) * lda + k0 + kb * 32 + scol,
                       &As[(rg * 2 + kb) * 512]);
        }
        #pragma unroll
        for (int r = 0; r < BN / 32; r++) {
            const int inst = w * (BN / 32) + r;
            const int rg = inst >> 1, kb = inst & 1;
            async_cp16(B + (long long)(n0 + rg * 16 + srow) * ldb + k0 + kb * 32 + scol,
                       &Bs[(rg * 2 + kb) * 512]);
        }
        __syncthreads();

        #pragma unroll
        for (int s = 0; s < 2; s++) {
            short8 a[MI], b[NJ];
            const int fr = lane & 15;
            const int q  = lane >> 4;
            const int go = (fr * 4 + q) * 8;
            #pragma unroll
            for (int i = 0; i < MI; i++)
                a[i] = *(const short8*)&As[(((wm >> 4) + i) * 2 + s) * 512 + go];
            #pragma unroll
            for (int j = 0; j < NJ; j++)
                b[j] = *(const short8*)&Bs[(((wn >> 4) + j) * 2 + s) * 512 + go];
            #pragma unroll
            for (int i = 0; i < MI; i++)
                #pragma unroll
                for (int j = 0; j < NJ; j++)
                    acc[i][j] = __builtin_amdgcn_mfma_f32_16x16x32_bf16(
                        a[i], b[j], acc[i][j], 0, 0, 0);
        }
        __syncthreads();
    }

    float* Cf = (float*)Cv;
    u16*  Cb  = (u16*)Cv;
    const int cn    = n0 + wn + (lane & 15);
    const int rbase = m0 + wm + (lane >> 4) * 4;
    float bj[NJ];
    #pragma unroll
    for (int j = 0; j < NJ; j++) bj[j] = bias ? bias[cn + j * 16] : 0.f;

    #pragma unroll
    for (int i = 0; i < MI; i++) {
        #pragma unroll
        for (int r = 0; r < 4; r++) {
            const int m = rbase + i * 16 + r;
            #pragma unroll
            for (int j = 0; j < NJ; j++) {
                const int n = cn + j * 16;
                float v = (acc[i][j][r] + bj[j]) * scale;
                if (ACT == 1) v = fmaxf(v, 0.f);
                else if (ACT == 2) { v = fmaxf(v, 0.f); v = v * v; }
                const long long ci = zc + (long long)m * ldc + n;
                if (OUT == 0)      Cf[ci] = v;
                else if (OUT == 1) Cf[ci] += v;
                else if (OUT == 2) Cb[ci] = f2bf(v);
                else               Cb[ci] = f2bf(bf2f(Cb[ci]) + v);
            }
        }
    }
}

// GLU-fused GEMM: X[m,n] (bf16) += (A·B1^T)[m,n] * sigmoid((A·B2^T)[m,n])
__global__ __launch_bounds__(256)
void glugemm_k(const u16* __restrict__ A, const u16* __restrict__ B1,
               const u16* __restrict__ B2, u16* __restrict__ X)
{
    constexpr int BM = 128, BN = 64, MI = 4, NJ = 2;
    __shared__ u16 As[BM * 64];
    __shared__ u16 B1s[BN * 64];
    __shared__ u16 B2s[BN * 64];

    const int id = blockIdx.x + gridDim.x * blockIdx.y;
    const int bx = (id >> 3) % gridDim.x;
    const int by = (id & 7) + 8 * ((id >> 3) / gridDim.x);
    const int m0 = by * BM;
    const int n0 = bx * BN;

    const int lane = threadIdx.x & 63;
    const int w    = threadIdx.x >> 6;
    const int wm   = (w >> 1) * 64;
    const int wn   = (w & 1) * 32;
    const int srow = lane >> 2;
    const int scol = (lane & 3) * 8;

    floatx4 acc1[MI][NJ], acc2[MI][NJ];
    #pragma unroll
    for (int i = 0; i < MI; i++)
        #pragma unroll
        for (int j = 0; j < NJ; j++) {
            acc1[i][j] = floatx4{0.f, 0.f, 0.f, 0.f};
            acc2[i][j] = floatx4{0.f, 0.f, 0.f, 0.f};
        }

    for (int k0 = 0; k0 < 1024; k0 += 64) {
        #pragma unroll
        for (int r = 0; r < 4; r++) {
            const int inst = w * 4 + r;
            const int rg = inst >> 1, kb = inst & 1;
            async_cp16(A + (long long)(m0 + rg * 16 + srow) * 1024 + k0 + kb * 32 + scol,
                       &As[(rg * 2 + kb) * 512]);
        }
        #pragma unroll
        for (int r = 0; r < 2; r++) {
            const int inst = w * 2 + r;
            const int rg = inst >> 1, kb = inst & 1;
            async_cp16(B1 + (long long)(n0 + rg * 16 + srow) * 1024 + k0 + kb * 32 + scol,
                       &B1s[(rg * 2 + kb) * 512]);
            async_cp16(B2 + (long long)(n0 + rg * 16 + srow) * 1024 + k0 + kb * 32 + scol,
                       &B2s[(rg * 2 + kb) * 512]);
        }
        __syncthreads();

        #pragma unroll
        for (int s = 0; s < 2; s++) {
            short8 a[MI], b1[NJ], b2[NJ];
            const int fr = lane & 15;
            const int q  = lane >> 4;
            const int go = (fr * 4 + q) * 8;
            #pragma unroll
            for (int i = 0; i < MI; i++)
                a[i] = *(const short8*)&As[(((wm >> 4) + i) * 2 + s) * 512 + go];
            #pragma unroll
            for (int j = 0; j < NJ; j++) {
                b1[j] = *(const short8*)&B1s[(((wn >> 4) + j) * 2 + s) * 512 + go];
                b2[j] = *(const short8*)&B2s[(((wn >> 4) + j) * 2 + s) * 512 + go];
            }
            #pragma unroll
            for (int i = 0; i < MI; i++)
                #pragma unroll
                for (int j = 0; j < NJ; j++) {
                    acc1[i][j] = __builtin_amdgcn_mfma_f32_16x16x32_bf16(
                        a[i], b1[j], acc1[i][j], 0, 0, 0);
                    acc2[i][j] = __builtin_amdgcn_mfma_f32_16x16x32_bf16(
                        a[i], b2[j], acc2[i][j], 0, 0, 0);
                }
        }
        __syncthreads();
    }

    const int cn    = n0 + wn + (lane & 15);
    const int rbase = m0 + wm + (lane >> 4) * 4;
    #pragma unroll
    for (int i = 0; i < MI; i++)
        #pragma unroll
        for (int r = 0; r < 4; r++) {
            const int m = rbase + i * 16 + r;
            #pragma unroll
            for (int j = 0; j < NJ; j++) {
                const int n = cn + j * 16;
                float g = acc1[i][j][r] / (1.f + __expf(-acc2[i][j][r]));
                u16* xp = &X[(long long)m * 1024 + n];
                *xp = f2bf(bf2f(*xp) + g);
            }
        }
}

// S GEMM + exp + rowsum, plane->XCD affinity (grid 1024 1-D).
// R10: K-loop peeled into two compile-time halves (k<256: Q·K, k>=256: Er·Q);
// __expf epilogue.
#define SGEMM_MMA_STEP                                                        \
    __syncthreads();                                                          \
    _Pragma("unroll")                                                         \
    for (int s = 0; s < 2; s++) {                                             \
        short8 a[MI], b[NJ];                                                  \
        const int fr = lane & 15;                                             \
        const int q  = lane >> 4;                                             \
        const int go = (fr * 4 + q) * 8;                                      \
        _Pragma("unroll")                                                     \
        for (int i = 0; i < MI; i++)                                          \
            a[i] = *(const short8*)&As[(((wm >> 4) + i) * 2 + s) * 512 + go]; \
        _Pragma("unroll")                                                     \
        for (int j = 0; j < NJ; j++)                                          \
            b[j] = *(const short8*)&Bs[(((wn >> 4) + j) * 2 + s) * 512 + go]; \
        _Pragma("unroll")                                                     \
        for (int i = 0; i < MI; i++)                                          \
            _Pragma("unroll")                                                 \
            for (int j = 0; j < NJ; j++)                                      \
                acc[i][j] = __builtin_amdgcn_mfma_f32_16x16x32_bf16(          \
                    a[i], b[j], acc[i][j], 0, 0, 0);                          \
    }                                                                         \
    __syncthreads();

__global__ __launch_bounds__(256)
void sgemm_exp_k(const u16* __restrict__ Qpk, const u16* __restrict__ Kpk,
                 const u16* __restrict__ ErT,
                 u16* __restrict__ S, float* __restrict__ rowsum, float scale)
{
    constexpr int MI = 4, NJ = 4;
    const int i0 = blockIdx.x;
    const int x  = i0 & 7;
    const int j0 = i0 >> 3;            // 0..127
    const int z  = x + 8 * (j0 & 1);   // plane
    const int t  = j0 >> 1;            // 0..63
    const int bx = t & 7, by = t >> 3;

    const u16* Aq = Qpk + (long long)z * 262144;
    const u16* Bk = Kpk + (long long)z * 262144;
    S += (long long)z * M1;
    rowsum += z << 10;

    __shared__ u16 As[128 * 64];
    __shared__ u16 Bs[128 * 64];

    const int m0 = by * 128;
    const int n0 = bx * 128;

    const int lane = threadIdx.x & 63;
    const int w    = threadIdx.x >> 6;
    const int wm   = (w >> 1) * 64;
    const int wn   = (w & 1) * 64;
    const int srow = lane >> 2;
    const int scol = (lane & 3) * 8;

    floatx4 acc[MI][NJ];
    #pragma unroll
    for (int i = 0; i < MI; i++)
        #pragma unroll
        for (int j = 0; j < NJ; j++)
            acc[i][j] = floatx4{0.f, 0.f, 0.f, 0.f};

    // half 1: k in [0,256) — A from Qpk, B from Kpk (compile-time sources)
    for (int k0 = 0; k0 < 256; k0 += 64) {
        #pragma unroll
        for (int r = 0; r < 4; r++) {
            const int inst = w * 4 + r;
            const int rg = inst >> 1, kb = inst & 1;
            const int cb = k0 + kb * 32;
            async_cp16(Aq + (long long)(m0 + rg * 16 + srow) * 256 + cb + scol,
                       &As[(rg * 2 + kb) * 512]);
            async_cp16(Bk + (long long)(n0 + rg * 16 + srow) * 256 + cb + scol,
                       &Bs[(rg * 2 + kb) * 512]);
        }
        SGEMM_MMA_STEP
    }
    // half 2: k in [256,512) — A from ErT (shared, L2-hot), B from Qpk
    for (int k0 = 0; k0 < 256; k0 += 64) {
        #pragma unroll
        for (int r = 0; r < 4; r++) {
            const int inst = w * 4 + r;
            const int rg = inst >> 1, kb = inst & 1;
            const int cb = k0 + kb * 32;
            async_cp16(ErT + (long long)(m0 + rg * 16 + srow) * 256 + cb + scol,
                       &As[(rg * 2 + kb) * 512]);
            async_cp16(Aq + (long long)(n0 + rg * 16 + srow) * 256 + cb + scol,
                       &Bs[(rg * 2 + kb) * 512]);
        }
        SGEMM_MMA_STEP
    }

    const int cn    = n0 + wn + (lane & 15);
    const int rbase = m0 + wm + (lane >> 4) * 4;
    #pragma unroll
    for (int i = 0; i < MI; i++)
        #pragma unroll
        for (int r = 0; r < 4; r++) {
            const int m = rbase + i * 16 + r;
            float part = 0.f;
            #pragma unroll
            for (int j = 0; j < NJ; j++) {
                const int n = cn + j * 16;
                float e = __expf(acc[i][j][r] * scale);
                S[(long long)m * 1024 + n] = f2bf(e);
                part += e;
            }
            #pragma unroll
            for (int off = 8; off; off >>= 1) part += __shfl_xor(part, off, 64);
            if ((lane & 15) == 0) atomicAdd(&rowsum[m], part);
        }
}

// AO GEMM + rowsum divide, plane->XCD affinity (grid 256 1-D),
// 128x128 tile (R10), writes AO in (B,T,F) layout directly.
__global__ __launch_bounds__(256)
void aogemm_k(const u16* __restrict__ Sb, const u16* __restrict__ Vt,
              const float* __restrict__ rowsum, u16* __restrict__ AO)
{
    constexpr int MI = 4, NJ = 4;
    const int i0 = blockIdx.x;
    const int x  = i0 & 7;
    const int j0 = i0 >> 3;            // 0..31
    const int z  = x + 8 * (j0 & 1);
    const int t  = j0 >> 1;            // 0..15
    const int bx = t & 1, by = t >> 1; // 2 n-tiles x 8 m-tiles per plane

    Sb += (long long)z * M1;
    Vt += (long long)z * 262144;
    rowsum += z << 10;
    const long long zc = (long long)(z >> 2) * M1 + (z & 3) * 256;

    __shared__ u16 As[128 * 64];
    __shared__ u16 Bs[128 * 64];

    const int m0 = by * 128;
    const int n0 = bx * 128;

    const int lane = threadIdx.x & 63;
    const int w    = threadIdx.x >> 6;
    const int wm   = (w >> 1) * 64;
    const int wn   = (w & 1) * 64;
    const int srow = lane >> 2;
    const int scol = (lane & 3) * 8;

    floatx4 acc[MI][NJ];
    #pragma unroll
    for (int i = 0; i < MI; i++)
        #pragma unroll
        for (int j = 0; j < NJ; j++)
            acc[i][j] = floatx4{0.f, 0.f, 0.f, 0.f};

    for (int k0 = 0; k0 < 1024; k0 += 64) {
        #pragma unroll
        for (int r = 0; r < 4; r++) {
            const int inst = w * 4 + r;
            const int rg = inst >> 1, kb = inst & 1;
            async_cp16(Sb + (long long)(m0 + rg * 16 + srow) * 1024 + k0 + kb * 32 + scol,
                       &As[(rg * 2 + kb) * 512]);
            async_cp16(Vt + (long long)(n0 + rg * 16 + srow) * 1024 + k0 + kb * 32 + scol,
                       &Bs[(rg * 2 + kb) * 512]);
        }
        SGEMM_MMA_STEP
    }

    const int cn    = n0 + wn + (lane & 15);
    const int rbase = m0 + wm + (lane >> 4) * 4;
    #pragma unroll
    for (int i = 0; i < MI; i++)
        #pragma unroll
        for (int r = 0; r < 4; r++) {
            const int m = rbase + i * 16 + r;
            const float inv = 1.f / rowsum[m];
            #pragma unroll
            for (int j = 0; j < NJ; j++) {
                const int n = cn + j * 16;
                AO[zc + (long long)m * 1024 + n] = f2bf(acc[i][j][r] * inv);
            }
        }
}

// ---------------------------------------------------------------------------
// LayerNorm: bf16 in -> bf16 out. One block per row.
__global__ __launch_bounds__(256)
void ln_bf_k(const u16* __restrict__ in, u16* __restrict__ out,
             const float* __restrict__ g, const float* __restrict__ b)
{
    long long row = blockIdx.x;
    int tid = threadIdx.x;
    ushort4 u = ((const ushort4*)(in + (row << 10)))[tid];
    float x0 = bf2f(u.x), x1 = bf2f(u.y), x2 = bf2f(u.z), x3 = bf2f(u.w);
    float s = x0 + x1 + x2 + x3;
    s = block_sum(s);
    float mean = s * (1.f / 1024.f);
    float dx = x0 - mean, dy = x1 - mean, dz = x2 - mean, dw = x3 - mean;
    float s2 = dx * dx + dy * dy + dz * dz + dw * dw;
    s2 = block_sum(s2);
    float inv = rsqrtf(s2 * (1.f / 1024.f) + 1e-5f);
    float4 gg = ((const float4*)g)[tid];
    float4 bb = ((const float4*)b)[tid];
    ushort4 o;
    o.x = f2bf(dx * inv * gg.x + bb.x);
    o.y = f2bf(dy * inv * gg.y + bb.y);
    o.z = f2bf(dz * inv * gg.z + bb.z);
    o.w = f2bf(dw * inv * gg.w + bb.w);
    ((ushort4*)(out + (row << 10)))[tid] = o;
}

// ---------------------------------------------------------------------------
// Fused weight prep + input projection (independent front-of-graph work).
// blocks [0, 24576): castall (seg = bid>>11); blocks [24576, 28672): inproj.
struct CastArgs {
    const float* s[10];
    const float* er; const float* qb; const float* kb; const float* vb;
    u16* ert; float* qkvb;
};
__global__ __launch_bounds__(256)
void castin_k(CastArgs a, u16* __restrict__ dst,
              const float* __restrict__ src, const float* __restrict__ inw,
              u16* __restrict__ X)
{
    const int bid = blockIdx.x;
    if (bid < 24576) {
        const int sz[10] = {2097152, 1048576, 524288, 1048576, 1048576,
                            1048576, 1048576, 1048576, 2097152, 2097152};
        int seg = bid >> 11;
        int tid = (bid & 2047) * 256 + threadIdx.x;
        if (seg < 10) {
            int n = sz[seg];
            int base = 0;
            for (int i = 0; i < seg; i++) base += sz[i];
            int i4 = tid * 4;
            if (i4 >= n) return;
            float4 v = *(const float4*)(a.s[seg] + i4);
            ushort4 o;
            o.x = f2bf(v.x); o.y = f2bf(v.y); o.z = f2bf(v.z); o.w = f2bf(v.w);
            *(ushort4*)(dst + base + i4) = o;
        } else if (seg == 10) {
            if (tid < 262144) {
                int j = tid >> 8, d = tid & 255;
                a.ert[tid] = f2bf(a.er[d * 1024 + j]);
            }
        } else {
            if (tid < 1024) a.qkvb[tid] = a.qb[tid];
            else if (tid < 2048) a.qkvb[tid] = a.kb[tid - 1024];
            else if (tid < 3072) a.qkvb[tid] = a.vb[tid - 2048];
        }
    } else {
        __shared__ float tile[32][33];
        int ib = bid - 24576;
        int f0 = (ib & 31) * 32, t0 = ((ib >> 5) & 31) * 32, b = ib >> 10;
        int tx = threadIdx.x & 31, ty = threadIdx.x >> 5;
        float w0 = inw[0], w1 = inw[1];
        for (int r = ty; r < 32; r += 8) {
            int f = f0 + r, t = t0 + tx;
            float s0 = src[(((long long)b * 2 + 0) * 1025 + f) * 1024 + t];
            float s1 = src[(((long long)b * 2 + 1) * 1025 + f) * 1024 + t];
            tile[r][tx] = w0 * s0 + w1 * s1;
        }
        __syncthreads();
        for (int r = ty; r < 32; r += 8)
            X[((long long)b * 1024 + t0 + r) * 1024 + f0 + tx] = f2bf(tile[tx][r]);
    }
}

// ---------------------------------------------------------------------------
// Fused dconvF (k=11, along f, transposed out) + dconvT (k=7, along t).
// blocks [0, 16384): dconvT -> outT; blocks [16384, 20480): dconvF -> outF.
__global__ __launch_bounds__(256)
void dconvFT_k(const u16* __restrict__ in, u16* __restrict__ outT,
               const float* __restrict__ wT, u16* __restrict__ outF,
               const float* __restrict__ wF)
{
    const int bid = blockIdx.x;
    if (bid < 16384) {
        int idx = bid * 256 + threadIdx.x;
        int f = idx & 1023;
        int bt = idx >> 10;
        int t = bt & 1023;
        int b = bt >> 10;
        const float* wr = wT + f * 7;
        float acc = 0.f;
        #pragma unroll
        for (int k = 0; k < 7; k++) {
            int tt = t + k - 3;
            if (tt >= 0 && tt < 1024)
                acc += bf2f(in[(((long long)b << 10) + tt) * 1024 + f]) * wr[k];
        }
        outT[idx] = f2bf(acc);
    } else {
        __shared__ float itile[32][44];
        __shared__ float otile[32][33];
        int ib = bid - 16384;
        int f0 = (ib & 31) * 32, t0 = ((ib >> 5) & 31) * 32, b = ib >> 10;
        int tx = threadIdx.x & 31, ty = threadIdx.x >> 5;
        for (int r = ty; r < 32; r += 8)
            for (int c = tx; c < 42; c += 32) {
                int f = f0 - 5 + c;
                itile[r][c] = (f >= 0 && f < 1024)
                    ? bf2f(in[((long long)(b * 1024 + t0 + r)) * 1024 + f]) : 0.f;
            }
        __syncthreads();
        for (int r = ty; r < 32; r += 8) {
            const float* wr = wF + (t0 + r) * 11;
            float acc = 0.f;
            #pragma unroll
            for (int k = 0; k < 11; k++) acc += itile[r][tx + k] * wr[k];
            otile[tx][r] = acc;
        }
        __syncthreads();
        for (int r = ty; r < 32; r += 8)
            outF[((long long)(b * 1024 + f0 + r)) * 1024 + t0 + tx] = f2bf(otile[r][tx]);
    }
}

// dconv along t (strided), channels=f, k=7 pad 3, bf16 (B,T,F)->(B,T,F).
__global__ __launch_bounds__(256)
void dconvT_bf_k(const u16* __restrict__ in, u16* __restrict__ out,
                 const float* __restrict__ w)
{
    int idx = blockIdx.x * 256 + threadIdx.x;
    int f = idx & 1023;
    int bt = idx >> 10;
    int t = bt & 1023;
    int b = bt >> 10;
    const float* wr = w + f * 7;
    float acc = 0.f;
    #pragma unroll
    for (int k = 0; k < 7; k++) {
        int tt = t + k - 3;
        if (tt >= 0 && tt < 1024)
            acc += bf2f(in[(((long long)b << 10) + tt) * 1024 + f]) * wr[k];
    }
    out[idx] = f2bf(acc);
}

// ---------------------------------------------------------------------------
// Fused QKV post-processing: q/k dconv+pack, v dconv+transpose, rowsum zero.
// blocks [0,16384): q/k pack; [16384,20480): vconv; [20480,20544): rowsum=0.
__global__ __launch_bounds__(256)
void qkvpack_k(const u16* __restrict__ T3, const float* __restrict__ w,
               const float* __restrict__ bias,
               u16* __restrict__ Qpk, u16* __restrict__ Kpk,
               u16* __restrict__ Vt, float* __restrict__ rowsum)
{
    const int bid = blockIdx.x;
    if (bid < 16384) {
        int idx = bid * 256 + threadIdx.x;  // 4M
        int f = idx & 1023;
        int t = (idx >> 10) & 1023;
        int b = idx >> 20;
        int band = f >> 8, d = f & 255, z = (b << 2) | band;
        const float* wr = w + f * 7;
        float bq = bias[f];
        float aq = bq, ak = bq;
        #pragma unroll
        for (int k = 0; k < 7; k++) {
            int tt = t + k - 3;
            if (tt >= 0 && tt < 1024) {
                const u16* row = T3 + ((long long)(b << 10) + tt) * 3072 + f;
                float wk = wr[k];
                aq += bf2f(row[0]) * wk;
                ak += bf2f(row[1024]) * wk;
            }
        }
        long long base = (long long)z * 262144 + t * 256 + d;
        Qpk[base] = f2bf(aq);
        Kpk[base] = f2bf(ak);
    } else if (bid < 20480) {
        __shared__ float itile[38][32];
        __shared__ float otile[32][33];
        int vb = bid - 16384;
        int f0 = (vb & 31) * 32, t0 = ((vb >> 5) & 31) * 32, b = vb >> 10;
        int tx = threadIdx.x & 31, ty = threadIdx.x >> 5;
        for (int i = threadIdx.x; i < 38 * 32; i += 256) {
            int r = i >> 5, c = i & 31;
            int t = t0 - 3 + r;
            itile[r][c] = (t >= 0 && t < 1024)
                ? bf2f(T3[((long long)(b * 1024 + t)) * 3072 + 2048 + f0 + c]) : 0.f;
        }
        __syncthreads();
        for (int r = ty; r < 32; r += 8) {
            const float* wr = w + (f0 + tx) * 7;
            float acc = bias[f0 + tx];
            #pragma unroll
            for (int k = 0; k < 7; k++) acc += itile[r + k][tx] * wr[k];
            otile[tx][r] = acc;
        }
        __syncthreads();
        for (int r = ty; r < 32; r += 8)
            Vt[((long long)(b * 1024 + f0 + r)) * 1024 + t0 + tx] = f2bf(otile[r][tx]);
    } else {
        int i = (bid - 20480) * 256 + threadIdx.x;  // 16384 floats
        rowsum[i] = 0.f;
    }
}

// Output head: reads bf16 X.
__global__ __launch_bounds__(256)
void out_k(const float* __restrict__ src, const u16* __restrict__ X,
           const float* __restrict__ ow, float* __restrict__ out)
{
    __shared__ float tile[32][33];
    int b = blockIdx.z;
    int f0 = blockIdx.y * 32, t0 = blockIdx.x * 32;
    for (int r = threadIdx.y; r < 32; r += 8)
        tile[r][threadIdx.x] = bf2f(X[((long long)b * 1024 + t0 + r) * 1024 + f0 + threadIdx.x]);
    __syncthreads();
    float w00 = ow[0], w01 = ow[1], w02 = ow[2];
    float w10 = ow[3], w11 = ow[4], w12 = ow[5];
    for (int r = threadIdx.y; r < 32; r += 8) {
        int f = f0 + r, t = t0 + threadIdx.x;
        float s0 = src[(((long long)b * 2 + 0) * 1025 + f) * 1024 + t];
        float s1 = src[(((long long)b * 2 + 1) * 1025 + f) * 1024 + t];
        float xv = tile[threadIdx.x][r];
        float v0 = fminf(fmaxf(w00 * s0 + w01 * s1 + w02 * xv, 0.f), 6.f) * (1.f / 6.f);
        float v1 = fminf(fmaxf(w10 * s0 + w11 * s1 + w12 * xv, 0.f), 6.f) * (1.f / 6.f);
        out[(((long long)b * 2 + 0) * 1025 + f) * 1024 + t] = v0;
        out[(((long long)b * 2 + 1) * 1025 + f) * 1024 + t] = v1;
        if (f == 1023) {
            out[(((long long)b * 2 + 0) * 1025 + 1024) * 1024 + t] = v0;
            out[(((long long)b * 2 + 1) * 1025 + 1024) * 1024 + t] = v1;
        }
    }
}

// ---------------------------------------------------------------------------
extern "C" void kernel_launch(void* const* d_in, const int* in_sizes, int n_in,
                              void* d_out, int out_size, void* d_ws, size_t ws_size,
                              hipStream_t stream)
{
    const float* src    = (const float*)d_in[0];
    const float* in_w   = (const float*)d_in[1];
    const float* ln1_g  = (const float*)d_in[2];
    const float* ln1_b  = (const float*)d_in[3];
    const float* glu_w  = (const float*)d_in[4];
    const float* ln2_g  = (const float*)d_in[5];
    const float* ln2_b  = (const float*)d_in[6];
    const float* c1L_dw = (const float*)d_in[7];
    const float* c1L_pw = (const float*)d_in[8];
    const float* c1R_dw = (const float*)d_in[9];
    const float* c1R_pw = (const float*)d_in[10];
    const float* ln3_g  = (const float*)d_in[11];
    const float* ln3_b  = (const float*)d_in[12];
    const float* c1M_dw = (const float*)d_in[13];
    const float* c1M_pw = (const float*)d_in[14];
    const float* ln4_g  = (const float*)d_in[15];
    const float* ln4_b  = (const float*)d_in[16];
    const float* q_w    = (const float*)d_in[17];
    const float* q_b    = (const float*)d_in[18];
    const float* qc_w   = (const float*)d_in[19];
    const float* qc_b   = (const float*)d_in[20];
    const float* k_w    = (const float*)d_in[21];
    const float* k_b    = (const float*)d_in[22];
    const float* v_w    = (const float*)d_in[23];
    const float* v_b    = (const float*)d_in[24];
    const float* o_w    = (const float*)d_in[25];
    const float* o_b    = (const float*)d_in[26];
    const float* er     = (const float*)d_in[27];
    const float* ln5_g  = (const float*)d_in[28];
    const float* ln5_b  = (const float*)d_in[29];
    const float* c2_w   = (const float*)d_in[30];
    const float* c3_w   = (const float*)d_in[31];
    const float* out_w  = (const float*)d_in[32];
    float* out = (float*)d_out;

    const size_t MB = 1ull << 20;
    if (ws_size < 162 * MB) return;
    char* wsb = (char*)d_ws;
    u16* X       = (u16*)(wsb + 0);           // 8 MB bf16 residual
    u16* SB      = (u16*)(wsb + 8 * MB);      // 8 MB bf16 hL+hR
    float* rowsum= (float*)(wsb + 16 * MB);   // 64 KB (free window, no alias)
    u16* Qpk     = (u16*)(wsb + 32 * MB);     // 8 MB q-pack (z,t,256)
    u16* Kpk     = (u16*)(wsb + 40 * MB);     // 8 MB k-pack (z,t,256)
    u16* Hbf     = (u16*)(wsb + 64 * MB);     // 8 MB ln outputs
    u16* T1bf    = (u16*)(wsb + 72 * MB);     // 8 MB dconv temps
    u16* T3      = (u16*)(wsb + 72 * MB);     // 24 MB QKV (4096x3072)
    u16* AO      = (u16*)(wsb + 80 * MB);     // 8 MB AO (B,T,F)
    u16* T2bf    = (u16*)(wsb + 96 * MB);     // 8 MB dconvF out (c1L)
    u16* Vt      = (u16*)(wsb + 96 * MB);     // reuse: 8 MB V^T (b,f,t)
    u16* Sbf     = (u16*)(wsb + 104 * MB);    // 32 MB scores (16,1024,1024)
    u16* Gbf     = (u16*)(wsb + 104 * MB);    // reuse: 16 MB ffn mid
    u16* W0      = (u16*)(wsb + 136 * MB);    // bf16 weights

    u16* glu_wb  = W0;
    u16* c1L_pwb = W0 + 2097152;
    u16* c1R_pwb = W0 + 3145728;
    u16* c1M_pwb = W0 + 3670016;
    u16* qkv_wb  = W0 + 4718592;   // q,k,v contiguous (3072 x 1024)
    u16* o_wb    = W0 + 7864320;
    u16* c2_wb   = W0 + 8912896;
    u16* c3_wb   = W0 + 11010048;
    u16* ertb    = W0 + 13107200;  // 262144 (t-major er transpose, shared)
    float* qkvb  = (float*)(W0 + 13369344);  // 3072 fp32

    const dim3 blk256(256);
    const dim3 tgrid(32, 32, NB);
    const dim3 tblk(32, 8);
    const int EW = 16384;  // 4M / 256

    // --- 1. weight prep + input projection (fused, independent work) ---
    CastArgs ca;
    ca.s[0] = glu_w;  ca.s[1] = c1L_pw; ca.s[2] = c1R_pw; ca.s[3] = c1M_pw;
    ca.s[4] = q_w;    ca.s[5] = k_w;    ca.s[6] = v_w;    ca.s[7] = o_w;
    ca.s[8] = c2_w;   ca.s[9] = c3_w;
    ca.er = er; ca.qb = q_b; ca.kb = k_b; ca.vb = v_b;
    ca.ert = ertb; ca.qkvb = qkvb;
    castin_k<<<28672, blk256, 0, stream>>>(ca, W0, src, in_w, X);

    // 2-4. h = ln1(x); x += glu(h @ glu_w^T)  [fused]
    ln_bf_k<<<4096, blk256, 0, stream>>>(X, Hbf, ln1_g, ln1_b);
    glugemm_k<<<dim3(16, 32, 1), blk256, 0, stream>>>(
        Hbf, glu_wb, glu_wb + 1048576, X);
    // 5. h = ln2(x)
    ln_bf_k<<<4096, blk256, 0, stream>>>(X, Hbf, ln2_g, ln2_b);
    // 6. both depthwise convs of h (fused; independent GEMM chains follow)
    dconvFT_k<<<20480, blk256, 0, stream>>>(Hbf, T1bf, c1R_dw, T2bf, c1L_dw);
    // 7. hL = relu(c1L_pw · dconvF(h)) -> bf16 SB   [128x128 tile]
    gemm_bf<128, 128, 1, 2><<<dim3(8, 8, NB), blk256, 0, stream>>>(
        c1L_pwb, T2bf, SB, 1024, 1024, 1024, 1024, 0, M1, M1, nullptr, 1.f);
    // 8. SB[:, :512] += relu(dconvT(h) @ c1R_pw^T)  (bf16 accum)
    gemm_bf<128, 64, 1, 3><<<dim3(8, 32, 1), blk256, 0, stream>>>(
        T1bf, c1R_pwb, SB, 1024, 1024, 1024, 1024, 0, 0, 0, nullptr, 1.f);
    // 9-11. h = ln3(SB); x += dconvT(h) @ c1M_pw^T  (bf16 accum) [128x128]
    ln_bf_k<<<4096, blk256, 0, stream>>>(SB, Hbf, ln3_g, ln3_b);
    dconvT_bf_k<<<EW, blk256, 0, stream>>>(Hbf, T1bf, c1M_dw);
    gemm_bf<128, 128, 0, 3><<<dim3(8, 32, 1), blk256, 0, stream>>>(
        T1bf, c1M_pwb, X, 1024, 1024, 1024, 1024, 0, 0, 0, nullptr, 1.f);
    // 12. h = ln4(x)
    ln_bf_k<<<4096, blk256, 0, stream>>>(X, Hbf, ln4_g, ln4_b);
    // 13. fused QKV GEMM (4096x3072x1024) -> T3 bf16
    gemm_bf<128, 128, 0, 2><<<dim3(24, 32, 1), blk256, 0, stream>>>(
        Hbf, qkv_wb, T3, 1024, 1024, 1024, 3072, 0, 0, 0, qkvb, 1.f);
    // 14. qc convs: q/k pack + V transpose + rowsum zero (fused)
    qkvpack_k<<<20544, blk256, 0, stream>>>(T3, qc_w, qc_b, Qpk, Kpk, Vt, rowsum);
    // 15. S = exp((QK^T + rel-pos)/32) + rowsum; plane->XCD affinity
    sgemm_exp_k<<<1024, blk256, 0, stream>>>(Qpk, Kpk, ertb, Sbf, rowsum, 0.03125f);
    // 16. AO = (S @ V) / rowsum; plane->XCD affinity; (B,T,F); [128x128]
    aogemm_k<<<256, blk256, 0, stream>>>(Sbf, Vt, rowsum, AO);
    // 17. x += AO @ o_w^T + o_b  (bf16 accum)  [128x128]
    gemm_bf<128, 128, 0, 3><<<dim3(8, 32, 1), blk256, 0, stream>>>(
        AO, o_wb, X, 1024, 1024, 1024, 1024, 0, 0, 0, o_b, 1.f);
    // 18-19. h = ln5(x); mid = relu(h @ c2_w^T)^2
    ln_bf_k<<<4096, blk256, 0, stream>>>(X, Hbf, ln5_g, ln5_b);
    gemm_bf<128, 128, 2, 2><<<dim3(16, 32, 1), blk256, 0, stream>>>(
        Hbf, c2_wb, Gbf, 1024, 1024, 1024, 2048, 0, 0, 0, nullptr, 1.f);
    // 20. x += mid @ c3_w^T  (bf16 accum)  [128x128]
    gemm_bf<128, 128, 0, 3><<<dim3(8, 32, 1), blk256, 0, stream>>>(
        Gbf, c3_wb, X, 2048, 2048, 2048, 1024, 0, 0, 0, nullptr, 1.f);
    // 21. output head
    out_k<<<tgrid, tblk, 0, stream>>>(src, X, out_w, out);
}

// Round 3
// 564.074 us; speedup vs baseline: 1.0450x; 1.0450x over previous
//
#include <hip/hip_runtime.h>
#include <math.h>

// ---------------------------------------------------------------------------
// FrameTransformer — R11: revert R10 tile geometry (1 block/CU = latency
// disaster: MfmaUtil 13%, occ 9.6%, 46.5us/GEMM), keep R10 VALU fixes.
// Rule learned: with the 2-barrier K-loop structure, >=2 blocks/CU is
// mandatory (co-resident blocks hide each other's staging drain).
//  * c1L/c1M/o/c3/aogemm back to 128x64 (512 blocks = 2/CU).
//  * c1R: 128x64 (256 blocks = 1/CU) -> 64x64 (512 blocks = 2/CU).
//  * kept: peeled sgemm halves + __expf, glugemm __expf.
// R9 launch fusion + operand dedup + plane->XCD affinity kept.
// ---------------------------------------------------------------------------

typedef unsigned short u16;
typedef __attribute__((ext_vector_type(4))) float floatx4;
typedef __attribute__((ext_vector_type(8))) short short8;

#define NB 4
static const long long M1 = 1024LL * 1024LL;

__device__ __forceinline__ float bf2f(u16 h) {
    union { unsigned int u; float f; } v;
    v.u = ((unsigned int)h) << 16;
    return v.f;
}
__device__ __forceinline__ u16 f2bf(float x) {
    union { float f; unsigned int u; } v;
    v.f = x;
    unsigned int r = (v.u + 0x7FFFu + ((v.u >> 16) & 1u)) >> 16;
    return (u16)r;
}

__device__ __forceinline__ void async_cp16(const u16* g, u16* lds) {
    __builtin_amdgcn_global_load_lds(
        (const __attribute__((address_space(1))) unsigned int*)g,
        (__attribute__((address_space(3))) unsigned int*)lds, 16, 0, 0);
}

__device__ __forceinline__ float block_sum(float v) {
    __shared__ float sd[4];
    #pragma unroll
    for (int off = 32; off; off >>= 1) v += __shfl_down(v, off, 64);
    int lane = threadIdx.x & 63, wid = threadIdx.x >> 6;
    __syncthreads();
    if (lane == 0) sd[wid] = v;
    __syncthreads();
    return sd[0] + sd[1] + sd[2] + sd[3];
}

// ---------------------------------------------------------------------------
// bf16 NT GEMM: C[M,N] (op)= act( scale*(A·B^T + bias) )
// OUT: 0 = f32 store, 1 = f32 accum, 2 = bf16 store, 3 = bf16 accum.
// ---------------------------------------------------------------------------
template<int BM, int BN, int ACT, int OUT>
__global__ __launch_bounds__(256)
void gemm_bf(const u16* __restrict__ A, const u16* __restrict__ B,
             void* __restrict__ Cv, int K, int lda, int ldb, int ldc,
             long long sAz, long long sBz, long long sCz,
             const float* __restrict__ bias, float scale)
{
    constexpr int MI = BM / 32;
    constexpr int NJ = BN / 32;

    A += (long long)blockIdx.z * sAz;
    B += (long long)blockIdx.z * sBz;
    const long long zc = (long long)blockIdx.z * sCz;

    __shared__ u16 As[BM * 64];
    __shared__ u16 Bs[BN * 64];

    const int id = blockIdx.x + gridDim.x * blockIdx.y;
    const int bx = (id >> 3) % gridDim.x;
    const int by = (id & 7) + 8 * ((id >> 3) / gridDim.x);
    const int m0 = by * BM;
    const int n0 = bx * BN;

    const int lane = threadIdx.x & 63;
    const int w    = threadIdx.x >> 6;
    const int wm   = (w >> 1) * (BM / 2);
    const int wn   = (w & 1) * (BN / 2);
    const int srow = lane >> 2;
    const int scol = (lane & 3) * 8;

    floatx4 acc[MI][NJ];
    #pragma unroll
    for (int i = 0; i < MI; i++)
        #pragma unroll
        for (int j = 0; j < NJ; j++)
            acc[i][j] = floatx4{0.f, 0.f, 0.f, 0.f};

    for (int k0 = 0; k0 < K; k0 += 64) {
        #pragma unroll
        for (int r = 0; r < BM / 32; r++) {
            const int inst = w * (BM / 32) + r;
            const int rg = inst >> 1, kb = inst & 1;
            async_cp16(A + (long long)(m0 + rg * 16 + srow) * lda + k0 + kb * 32 + scol,
                       &As[(rg * 2 + kb) * 512]);
        }
        #pragma unroll
        for (int r = 0; r < BN / 32; r++) {
            const int inst = w * (BN / 32) + r;
            const int rg = inst >> 1, kb = inst & 1;
            async_cp16(B + (long long)(n0 + rg * 16 + srow) * ldb + k0 + kb * 32 + scol,
                       &Bs[(rg * 2 + kb) * 512]);
        }
        __syncthreads();

        #pragma unroll
        for (int s = 0; s < 2; s++) {
            short8 a[MI], b[NJ];
            const int fr = lane & 15;
            const int q  = lane >> 4;
            const int go = (fr * 4 + q) * 8;
            #pragma unroll
            for (int i = 0; i < MI; i++)
                a[i] = *(const short8*)&As[(((wm >> 4) + i) * 2 + s) * 512 + go];
            #pragma unroll
            for (int j = 0; j < NJ; j++)
                b[j] = *(const short8*)&Bs[(((wn >> 4) + j) * 2 + s) * 512 + go];
            #pragma unroll
            for (int i = 0; i < MI; i++)
                #pragma unroll
                for (int j = 0; j < NJ; j++)
                    acc[i][j] = __builtin_amdgcn_mfma_f32_16x16x32_bf16(
                        a[i], b[j], acc[i][j], 0, 0, 0);
        }
        __syncthreads();
    }

    float* Cf = (float*)Cv;
    u16*  Cb  = (u16*)Cv;
    const int cn    = n0 + wn + (lane & 15);
    const int rbase = m0 + wm + (lane >> 4) * 4;
    float bj[NJ];
    #pragma unroll
    for (int j = 0; j < NJ; j++) bj[j] = bias ? bias[cn + j * 16] : 0.f;

    #pragma unroll
    for (int i = 0; i < MI; i++) {
        #pragma unroll
        for (int r = 0; r < 4; r++) {
            const int m = rbase + i * 16 + r;
            #pragma unroll
            for (int j = 0; j < NJ; j++) {
                const int n = cn + j * 16;
                float v = (acc[i][j][r] + bj[j]) * scale;
                if (ACT == 1) v = fmaxf(v, 0.f);
                else if (ACT == 2) { v = fmaxf(v, 0.f); v = v * v; }
                const long long ci = zc + (long long)m * ldc + n;
                if (OUT == 0)      Cf[ci] = v;
                else if (OUT == 1) Cf[ci] += v;
                else if (OUT == 2) Cb[ci] = f2bf(v);
                else               Cb[ci] = f2bf(bf2f(Cb[ci]) + v);
            }
        }
    }
}

// GLU-fused GEMM: X[m,n] (bf16) += (A·B1^T)[m,n] * sigmoid((A·B2^T)[m,n])
__global__ __launch_bounds__(256)
void glugemm_k(const u16* __restrict__ A, const u16* __restrict__ B1,
               const u16* __restrict__ B2, u16* __restrict__ X)
{
    constexpr int BM = 128, BN = 64, MI = 4, NJ = 2;
    __shared__ u16 As[BM * 64];
    __shared__ u16 B1s[BN * 64];
    __shared__ u16 B2s[BN * 64];

    const int id = blockIdx.x + gridDim.x * blockIdx.y;
    const int bx = (id >> 3) % gridDim.x;
    const int by = (id & 7) + 8 * ((id >> 3) / gridDim.x);
    const int m0 = by * BM;
    const int n0 = bx * BN;

    const int lane = threadIdx.x & 63;
    const int w    = threadIdx.x >> 6;
    const int wm   = (w >> 1) * 64;
    const int wn   = (w & 1) * 32;
    const int srow = lane >> 2;
    const int scol = (lane & 3) * 8;

    floatx4 acc1[MI][NJ], acc2[MI][NJ];
    #pragma unroll
    for (int i = 0; i < MI; i++)
        #pragma unroll
        for (int j = 0; j < NJ; j++) {
            acc1[i][j] = floatx4{0.f, 0.f, 0.f, 0.f};
            acc2[i][j] = floatx4{0.f, 0.f, 0.f, 0.f};
        }

    for (int k0 = 0; k0 < 1024; k0 += 64) {
        #pragma unroll
        for (int r = 0; r < 4; r++) {
            const int inst = w * 4 + r;
            const int rg = inst >> 1, kb = inst & 1;
            async_cp16(A + (long long)(m0 + rg * 16 + srow) * 1024 + k0 + kb * 32 + scol,
                       &As[(rg * 2 + kb) * 512]);
        }
        #pragma unroll
        for (int r = 0; r < 2; r++) {
            const int inst = w * 2 + r;
            const int rg = inst >> 1, kb = inst & 1;
            async_cp16(B1 + (long long)(n0 + rg * 16 + srow) * 1024 + k0 + kb * 32 + scol,
                       &B1s[(rg * 2 + kb) * 512]);
            async_cp16(B2 + (long long)(n0 + rg * 16 + srow) * 1024 + k0 + kb * 32 + scol,
                       &B2s[(rg * 2 + kb) * 512]);
        }
        __syncthreads();

        #pragma unroll
        for (int s = 0; s < 2; s++) {
            short8 a[MI], b1[NJ], b2[NJ];
            const int fr = lane & 15;
            const int q  = lane >> 4;
            const int go = (fr * 4 + q) * 8;
            #pragma unroll
            for (int i = 0; i < MI; i++)
                a[i] = *(const short8*)&As[(((wm >> 4) + i) * 2 + s) * 512 + go];
            #pragma unroll
            for (int j = 0; j < NJ; j++) {
                b1[j] = *(const short8*)&B1s[(((wn >> 4) + j) * 2 + s) * 512 + go];
                b2[j] = *(const short8*)&B2s[(((wn >> 4) + j) * 2 + s) * 512 + go];
            }
            #pragma unroll
            for (int i = 0; i < MI; i++)
                #pragma unroll
                for (int j = 0; j < NJ; j++) {
                    acc1[i][j] = __builtin_amdgcn_mfma_f32_16x16x32_bf16(
                        a[i], b1[j], acc1[i][j], 0, 0, 0);
                    acc2[i][j] = __builtin_amdgcn_mfma_f32_16x16x32_bf16(
                        a[i], b2[j], acc2[i][j], 0, 0, 0);
                }
        }
        __syncthreads();
    }

    const int cn    = n0 + wn + (lane & 15);
    const int rbase = m0 + wm + (lane >> 4) * 4;
    #pragma unroll
    for (int i = 0; i < MI; i++)
        #pragma unroll
        for (int r = 0; r < 4; r++) {
            const int m = rbase + i * 16 + r;
            #pragma unroll
            for (int j = 0; j < NJ; j++) {
                const int n = cn + j * 16;
                float g = acc1[i][j][r] / (1.f + __expf(-acc2[i][j][r]));
                u16* xp = &X[(long long)m * 1024 + n];
                *xp = f2bf(bf2f(*xp) + g);
            }
        }
}

// Shared MMA step (reads As/Bs/MI/NJ/wm/wn/lane from enclosing scope).
#define SGEMM_MMA_STEP                                                        \
    __syncthreads();                                                          \
    _Pragma("unroll")                                                         \
    for (int s = 0; s < 2; s++) {                                             \
        short8 a[MI], b[NJ];                                                  \
        const int fr = lane & 15;                                             \
        const int q  = lane >> 4;                                             \
        const int go = (fr * 4 + q) * 8;                                      \
        _Pragma("unroll")                                                     \
        for (int i = 0; i < MI; i++)                                          \
            a[i] = *(const short8*)&As[(((wm >> 4) + i) * 2 + s) * 512 + go]; \
        _Pragma("unroll")                                                     \
        for (int j = 0; j < NJ; j++)                                          \
            b[j] = *(const short8*)&Bs[(((wn >> 4) + j) * 2 + s) * 512 + go]; \
        _Pragma("unroll")                                                     \
        for (int i = 0; i < MI; i++)                                          \
            _Pragma("unroll")                                                 \
            for (int j = 0; j < NJ; j++)                                      \
                acc[i][j] = __builtin_amdgcn_mfma_f32_16x16x32_bf16(          \
                    a[i], b[j], acc[i][j], 0, 0, 0);                          \
    }                                                                         \
    __syncthreads();

// S GEMM + exp + rowsum, plane->XCD affinity (grid 1024 1-D).
// K-loop peeled into two compile-time halves (k<256: Q·K, k>=256: Er·Q).
__global__ __launch_bounds__(256)
void sgemm_exp_k(const u16* __restrict__ Qpk, const u16* __restrict__ Kpk,
                 const u16* __restrict__ ErT,
                 u16* __restrict__ S, float* __restrict__ rowsum, float scale)
{
    constexpr int MI = 4, NJ = 4;
    const int i0 = blockIdx.x;
    const int x  = i0 & 7;
    const int j0 = i0 >> 3;            // 0..127
    const int z  = x + 8 * (j0 & 1);   // plane
    const int t  = j0 >> 1;            // 0..63
    const int bx = t & 7, by = t >> 3;

    const u16* Aq = Qpk + (long long)z * 262144;
    const u16* Bk = Kpk + (long long)z * 262144;
    S += (long long)z * M1;
    rowsum += z << 10;

    __shared__ u16 As[128 * 64];
    __shared__ u16 Bs[128 * 64];

    const int m0 = by * 128;
    const int n0 = bx * 128;

    const int lane = threadIdx.x & 63;
    const int w    = threadIdx.x >> 6;
    const int wm   = (w >> 1) * 64;
    const int wn   = (w & 1) * 64;
    const int srow = lane >> 2;
    const int scol = (lane & 3) * 8;

    floatx4 acc[MI][NJ];
    #pragma unroll
    for (int i = 0; i < MI; i++)
        #pragma unroll
        for (int j = 0; j < NJ; j++)
            acc[i][j] = floatx4{0.f, 0.f, 0.f, 0.f};

    // half 1: k in [0,256) — A from Qpk, B from Kpk (compile-time sources)
    for (int k0 = 0; k0 < 256; k0 += 64) {
        #pragma unroll
        for (int r = 0; r < 4; r++) {
            const int inst = w * 4 + r;
            const int rg = inst >> 1, kb = inst & 1;
            const int cb = k0 + kb * 32;
            async_cp16(Aq + (long long)(m0 + rg * 16 + srow) * 256 + cb + scol,
                       &As[(rg * 2 + kb) * 512]);
            async_cp16(Bk + (long long)(n0 + rg * 16 + srow) * 256 + cb + scol,
                       &Bs[(rg * 2 + kb) * 512]);
        }
        SGEMM_MMA_STEP
    }
    // half 2: k in [256,512) — A from ErT (shared, L2-hot), B from Qpk
    for (int k0 = 0; k0 < 256; k0 += 64) {
        #pragma unroll
        for (int r = 0; r < 4; r++) {
            const int inst = w * 4 + r;
            const int rg = inst >> 1, kb = inst & 1;
            const int cb = k0 + kb * 32;
            async_cp16(ErT + (long long)(m0 + rg * 16 + srow) * 256 + cb + scol,
                       &As[(rg * 2 + kb) * 512]);
            async_cp16(Aq + (long long)(n0 + rg * 16 + srow) * 256 + cb + scol,
                       &Bs[(rg * 2 + kb) * 512]);
        }
        SGEMM_MMA_STEP
    }

    const int cn    = n0 + wn + (lane & 15);
    const int rbase = m0 + wm + (lane >> 4) * 4;
    #pragma unroll
    for (int i = 0; i < MI; i++)
        #pragma unroll
        for (int r = 0; r < 4; r++) {
            const int m = rbase + i * 16 + r;
            float part = 0.f;
            #pragma unroll
            for (int j = 0; j < NJ; j++) {
                const int n = cn + j * 16;
                float e = __expf(acc[i][j][r] * scale);
                S[(long long)m * 1024 + n] = f2bf(e);
                part += e;
            }
            #pragma unroll
            for (int off = 8; off; off >>= 1) part += __shfl_xor(part, off, 64);
            if ((lane & 15) == 0) atomicAdd(&rowsum[m], part);
        }
}

// AO GEMM + rowsum divide, plane->XCD affinity (grid 512 1-D),
// 128x64 tile (2 blocks/CU), writes AO in (B,T,F) layout directly.
__global__ __launch_bounds__(256)
void aogemm_k(const u16* __restrict__ Sb, const u16* __restrict__ Vt,
              const float* __restrict__ rowsum, u16* __restrict__ AO)
{
    constexpr int MI = 4, NJ = 2;
    const int i0 = blockIdx.x;
    const int x  = i0 & 7;
    const int j0 = i0 >> 3;            // 0..63
    const int z  = x + 8 * (j0 & 1);
    const int t  = j0 >> 1;            // 0..31
    const int bx = t & 3, by = t >> 2;

    Sb += (long long)z * M1;
    Vt += (long long)z * 262144;
    rowsum += z << 10;
    const long long zc = (long long)(z >> 2) * M1 + (z & 3) * 256;

    __shared__ u16 As[128 * 64];
    __shared__ u16 Bs[64 * 64];

    const int m0 = by * 128;
    const int n0 = bx * 64;

    const int lane = threadIdx.x & 63;
    const int w    = threadIdx.x >> 6;
    const int wm   = (w >> 1) * 64;
    const int wn   = (w & 1) * 32;
    const int srow = lane >> 2;
    const int scol = (lane & 3) * 8;

    floatx4 acc[MI][NJ];
    #pragma unroll
    for (int i = 0; i < MI; i++)
        #pragma unroll
        for (int j = 0; j < NJ; j++)
            acc[i][j] = floatx4{0.f, 0.f, 0.f, 0.f};

    for (int k0 = 0; k0 < 1024; k0 += 64) {
        #pragma unroll
        for (int r = 0; r < 4; r++) {
            const int inst = w * 4 + r;
            const int rg = inst >> 1, kb = inst & 1;
            async_cp16(Sb + (long long)(m0 + rg * 16 + srow) * 1024 + k0 + kb * 32 + scol,
                       &As[(rg * 2 + kb) * 512]);
        }
        #pragma unroll
        for (int r = 0; r < 2; r++) {
            const int inst = w * 2 + r;
            const int rg = inst >> 1, kb = inst & 1;
            async_cp16(Vt + (long long)(n0 + rg * 16 + srow) * 1024 + k0 + kb * 32 + scol,
                       &Bs[(rg * 2 + kb) * 512]);
        }
        SGEMM_MMA_STEP
    }

    const int cn    = n0 + wn + (lane & 15);
    const int rbase = m0 + wm + (lane >> 4) * 4;
    #pragma unroll
    for (int i = 0; i < MI; i++)
        #pragma unroll
        for (int r = 0; r < 4; r++) {
            const int m = rbase + i * 16 + r;
            const float inv = 1.f / rowsum[m];
            #pragma unroll
            for (int j = 0; j < NJ; j++) {
                const int n = cn + j * 16;
                AO[zc + (long long)m * 1024 + n] = f2bf(acc[i][j][r] * inv);
            }
        }
}

// ---------------------------------------------------------------------------
// LayerNorm: bf16 in -> bf16 out. One block per row.
__global__ __launch_bounds__(256)
void ln_bf_k(const u16* __restrict__ in, u16* __restrict__ out,
             const float* __restrict__ g, const float* __restrict__ b)
{
    long long row = blockIdx.x;
    int tid = threadIdx.x;
    ushort4 u = ((const ushort4*)(in + (row << 10)))[tid];
    float x0 = bf2f(u.x), x1 = bf2f(u.y), x2 = bf2f(u.z), x3 = bf2f(u.w);
    float s = x0 + x1 + x2 + x3;
    s = block_sum(s);
    float mean = s * (1.f / 1024.f);
    float dx = x0 - mean, dy = x1 - mean, dz = x2 - mean, dw = x3 - mean;
    float s2 = dx * dx + dy * dy + dz * dz + dw * dw;
    s2 = block_sum(s2);
    float inv = rsqrtf(s2 * (1.f / 1024.f) + 1e-5f);
    float4 gg = ((const float4*)g)[tid];
    float4 bb = ((const float4*)b)[tid];
    ushort4 o;
    o.x = f2bf(dx * inv * gg.x + bb.x);
    o.y = f2bf(dy * inv * gg.y + bb.y);
    o.z = f2bf(dz * inv * gg.z + bb.z);
    o.w = f2bf(dw * inv * gg.w + bb.w);
    ((ushort4*)(out + (row << 10)))[tid] = o;
}

// ---------------------------------------------------------------------------
// Fused weight prep + input projection (independent front-of-graph work).
// blocks [0, 24576): castall (seg = bid>>11); blocks [24576, 28672): inproj.
struct CastArgs {
    const float* s[10];
    const float* er; const float* qb; const float* kb; const float* vb;
    u16* ert; float* qkvb;
};
__global__ __launch_bounds__(256)
void castin_k(CastArgs a, u16* __restrict__ dst,
              const float* __restrict__ src, const float* __restrict__ inw,
              u16* __restrict__ X)
{
    const int bid = blockIdx.x;
    if (bid < 24576) {
        const int sz[10] = {2097152, 1048576, 524288, 1048576, 1048576,
                            1048576, 1048576, 1048576, 2097152, 2097152};
        int seg = bid >> 11;
        int tid = (bid & 2047) * 256 + threadIdx.x;
        if (seg < 10) {
            int n = sz[seg];
            int base = 0;
            for (int i = 0; i < seg; i++) base += sz[i];
            int i4 = tid * 4;
            if (i4 >= n) return;
            float4 v = *(const float4*)(a.s[seg] + i4);
            ushort4 o;
            o.x = f2bf(v.x); o.y = f2bf(v.y); o.z = f2bf(v.z); o.w = f2bf(v.w);
            *(ushort4*)(dst + base + i4) = o;
        } else if (seg == 10) {
            if (tid < 262144) {
                int j = tid >> 8, d = tid & 255;
                a.ert[tid] = f2bf(a.er[d * 1024 + j]);
            }
        } else {
            if (tid < 1024) a.qkvb[tid] = a.qb[tid];
            else if (tid < 2048) a.qkvb[tid] = a.kb[tid - 1024];
            else if (tid < 3072) a.qkvb[tid] = a.vb[tid - 2048];
        }
    } else {
        __shared__ float tile[32][33];
        int ib = bid - 24576;
        int f0 = (ib & 31) * 32, t0 = ((ib >> 5) & 31) * 32, b = ib >> 10;
        int tx = threadIdx.x & 31, ty = threadIdx.x >> 5;
        float w0 = inw[0], w1 = inw[1];
        for (int r = ty; r < 32; r += 8) {
            int f = f0 + r, t = t0 + tx;
            float s0 = src[(((long long)b * 2 + 0) * 1025 + f) * 1024 + t];
            float s1 = src[(((long long)b * 2 + 1) * 1025 + f) * 1024 + t];
            tile[r][tx] = w0 * s0 + w1 * s1;
        }
        __syncthreads();
        for (int r = ty; r < 32; r += 8)
            X[((long long)b * 1024 + t0 + r) * 1024 + f0 + tx] = f2bf(tile[tx][r]);
    }
}

// ---------------------------------------------------------------------------
// Fused dconvF (k=11, along f, transposed out) + dconvT (k=7, along t).
// blocks [0, 16384): dconvT -> outT; blocks [16384, 20480): dconvF -> outF.
__global__ __launch_bounds__(256)
void dconvFT_k(const u16* __restrict__ in, u16* __restrict__ outT,
               const float* __restrict__ wT, u16* __restrict__ outF,
               const float* __restrict__ wF)
{
    const int bid = blockIdx.x;
    if (bid < 16384) {
        int idx = bid * 256 + threadIdx.x;
        int f = idx & 1023;
        int bt = idx >> 10;
        int t = bt & 1023;
        int b = bt >> 10;
        const float* wr = wT + f * 7;
        float acc = 0.f;
        #pragma unroll
        for (int k = 0; k < 7; k++) {
            int tt = t + k - 3;
            if (tt >= 0 && tt < 1024)
                acc += bf2f(in[(((long long)b << 10) + tt) * 1024 + f]) * wr[k];
        }
        outT[idx] = f2bf(acc);
    } else {
        __shared__ float itile[32][44];
        __shared__ float otile[32][33];
        int ib = bid - 16384;
        int f0 = (ib & 31) * 32, t0 = ((ib >> 5) & 31) * 32, b = ib >> 10;
        int tx = threadIdx.x & 31, ty = threadIdx.x >> 5;
        for (int r = ty; r < 32; r += 8)
            for (int c = tx; c < 42; c += 32) {
                int f = f0 - 5 + c;
                itile[r][c] = (f >= 0 && f < 1024)
                    ? bf2f(in[((long long)(b * 1024 + t0 + r)) * 1024 + f]) : 0.f;
            }
        __syncthreads();
        for (int r = ty; r < 32; r += 8) {
            const float* wr = wF + (t0 + r) * 11;
            float acc = 0.f;
            #pragma unroll
            for (int k = 0; k < 11; k++) acc += itile[r][tx + k] * wr[k];
            otile[tx][r] = acc;
        }
        __syncthreads();
        for (int r = ty; r < 32; r += 8)
            outF[((long long)(b * 1024 + f0 + r)) * 1024 + t0 + tx] = f2bf(otile[r][tx]);
    }
}

// dconv along t (strided), channels=f, k=7 pad 3, bf16 (B,T,F)->(B,T,F).
__global__ __launch_bounds__(256)
void dconvT_bf_k(const u16* __restrict__ in, u16* __restrict__ out,
                 const float* __restrict__ w)
{
    int idx = blockIdx.x * 256 + threadIdx.x;
    int f = idx & 1023;
    int bt = idx >> 10;
    int t = bt & 1023;
    int b = bt >> 10;
    const float* wr = w + f * 7;
    float acc = 0.f;
    #pragma unroll
    for (int k = 0; k < 7; k++) {
        int tt = t + k - 3;
        if (tt >= 0 && tt < 1024)
            acc += bf2f(in[(((long long)b << 10) + tt) * 1024 + f]) * wr[k];
    }
    out[idx] = f2bf(acc);
}

// ---------------------------------------------------------------------------
// Fused QKV post-processing: q/k dconv+pack, v dconv+transpose, rowsum zero.
// blocks [0,16384): q/k pack; [16384,20480): vconv; [20480,20544): rowsum=0.
__global__ __launch_bounds__(256)
void qkvpack_k(const u16* __restrict__ T3, const float* __restrict__ w,
               const float* __restrict__ bias,
               u16* __restrict__ Qpk, u16* __restrict__ Kpk,
               u16* __restrict__ Vt, float* __restrict__ rowsum)
{
    const int bid = blockIdx.x;
    if (bid < 16384) {
        int idx = bid * 256 + threadIdx.x;  // 4M
        int f = idx & 1023;
        int t = (idx >> 10) & 1023;
        int b = idx >> 20;
        int band = f >> 8, d = f & 255, z = (b << 2) | band;
        const float* wr = w + f * 7;
        float bq = bias[f];
        float aq = bq, ak = bq;
        #pragma unroll
        for (int k = 0; k < 7; k++) {
            int tt = t + k - 3;
            if (tt >= 0 && tt < 1024) {
                const u16* row = T3 + ((long long)(b << 10) + tt) * 3072 + f;
                float wk = wr[k];
                aq += bf2f(row[0]) * wk;
                ak += bf2f(row[1024]) * wk;
            }
        }
        long long base = (long long)z * 262144 + t * 256 + d;
        Qpk[base] = f2bf(aq);
        Kpk[base] = f2bf(ak);
    } else if (bid < 20480) {
        __shared__ float itile[38][32];
        __shared__ float otile[32][33];
        int vb = bid - 16384;
        int f0 = (vb & 31) * 32, t0 = ((vb >> 5) & 31) * 32, b = vb >> 10;
        int tx = threadIdx.x & 31, ty = threadIdx.x >> 5;
        for (int i = threadIdx.x; i < 38 * 32; i += 256) {
            int r = i >> 5, c = i & 31;
            int t = t0 - 3 + r;
            itile[r][c] = (t >= 0 && t < 1024)
                ? bf2f(T3[((long long)(b * 1024 + t)) * 3072 + 2048 + f0 + c]) : 0.f;
        }
        __syncthreads();
        for (int r = ty; r < 32; r += 8) {
            const float* wr = w + (f0 + tx) * 7;
            float acc = bias[f0 + tx];
            #pragma unroll
            for (int k = 0; k < 7; k++) acc += itile[r + k][tx] * wr[k];
            otile[tx][r] = acc;
        }
        __syncthreads();
        for (int r = ty; r < 32; r += 8)
            Vt[((long long)(b * 1024 + f0 + r)) * 1024 + t0 + tx] = f2bf(otile[r][tx]);
    } else {
        int i = (bid - 20480) * 256 + threadIdx.x;  // 16384 floats
        rowsum[i] = 0.f;
    }
}

// Output head: reads bf16 X.
__global__ __launch_bounds__(256)
void out_k(const float* __restrict__ src, const u16* __restrict__ X,
           const float* __restrict__ ow, float* __restrict__ out)
{
    __shared__ float tile[32][33];
    int b = blockIdx.z;
    int f0 = blockIdx.y * 32, t0 = blockIdx.x * 32;
    for (int r = threadIdx.y; r < 32; r += 8)
        tile[r][threadIdx.x] = bf2f(X[((long long)b * 1024 + t0 + r) * 1024 + f0 + threadIdx.x]);
    __syncthreads();
    float w00 = ow[0], w01 = ow[1], w02 = ow[2];
    float w10 = ow[3], w11 = ow[4], w12 = ow[5];
    for (int r = threadIdx.y; r < 32; r += 8) {
        int f = f0 + r, t = t0 + threadIdx.x;
        float s0 = src[(((long long)b * 2 + 0) * 1025 + f) * 1024 + t];
        float s1 = src[(((long long)b * 2 + 1) * 1025 + f) * 1024 + t];
        float xv = tile[threadIdx.x][r];
        float v0 = fminf(fmaxf(w00 * s0 + w01 * s1 + w02 * xv, 0.f), 6.f) * (1.f / 6.f);
        float v1 = fminf(fmaxf(w10 * s0 + w11 * s1 + w12 * xv, 0.f), 6.f) * (1.f / 6.f);
        out[(((long long)b * 2 + 0) * 1025 + f) * 1024 + t] = v0;
        out[(((long long)b * 2 + 1) * 1025 + f) * 1024 + t] = v1;
        if (f == 1023) {
            out[(((long long)b * 2 + 0) * 1025 + 1024) * 1024 + t] = v0;
            out[(((long long)b * 2 + 1) * 1025 + 1024) * 1024 + t] = v1;
        }
    }
}

// ---------------------------------------------------------------------------
extern "C" void kernel_launch(void* const* d_in, const int* in_sizes, int n_in,
                              void* d_out, int out_size, void* d_ws, size_t ws_size,
                              hipStream_t stream)
{
    const float* src    = (const float*)d_in[0];
    const float* in_w   = (const float*)d_in[1];
    const float* ln1_g  = (const float*)d_in[2];
    const float* ln1_b  = (const float*)d_in[3];
    const float* glu_w  = (const float*)d_in[4];
    const float* ln2_g  = (const float*)d_in[5];
    const float* ln2_b  = (const float*)d_in[6];
    const float* c1L_dw = (const float*)d_in[7];
    const float* c1L_pw = (const float*)d_in[8];
    const float* c1R_dw = (const float*)d_in[9];
    const float* c1R_pw = (const float*)d_in[10];
    const float* ln3_g  = (const float*)d_in[11];
    const float* ln3_b  = (const float*)d_in[12];
    const float* c1M_dw = (const float*)d_in[13];
    const float* c1M_pw = (const float*)d_in[14];
    const float* ln4_g  = (const float*)d_in[15];
    const float* ln4_b  = (const float*)d_in[16];
    const float* q_w    = (const float*)d_in[17];
    const float* q_b    = (const float*)d_in[18];
    const float* qc_w   = (const float*)d_in[19];
    const float* qc_b   = (const float*)d_in[20];
    const float* k_w    = (const float*)d_in[21];
    const float* k_b    = (const float*)d_in[22];
    const float* v_w    = (const float*)d_in[23];
    const float* v_b    = (const float*)d_in[24];
    const float* o_w    = (const float*)d_in[25];
    const float* o_b    = (const float*)d_in[26];
    const float* er     = (const float*)d_in[27];
    const float* ln5_g  = (const float*)d_in[28];
    const float* ln5_b  = (const float*)d_in[29];
    const float* c2_w   = (const float*)d_in[30];
    const float* c3_w   = (const float*)d_in[31];
    const float* out_w  = (const float*)d_in[32];
    float* out = (float*)d_out;

    const size_t MB = 1ull << 20;
    if (ws_size < 162 * MB) return;
    char* wsb = (char*)d_ws;
    u16* X       = (u16*)(wsb + 0);           // 8 MB bf16 residual
    u16* SB      = (u16*)(wsb + 8 * MB);      // 8 MB bf16 hL+hR
    float* rowsum= (float*)(wsb + 16 * MB);   // 64 KB (free window, no alias)
    u16* Qpk     = (u16*)(wsb + 32 * MB);     // 8 MB q-pack (z,t,256)
    u16* Kpk     = (u16*)(wsb + 40 * MB);     // 8 MB k-pack (z,t,256)
    u16* Hbf     = (u16*)(wsb + 64 * MB);     // 8 MB ln outputs
    u16* T1bf    = (u16*)(wsb + 72 * MB);     // 8 MB dconv temps
    u16* T3      = (u16*)(wsb + 72 * MB);     // 24 MB QKV (4096x3072)
    u16* AO      = (u16*)(wsb + 80 * MB);     // 8 MB AO (B,T,F)
    u16* T2bf    = (u16*)(wsb + 96 * MB);     // 8 MB dconvF out (c1L)
    u16* Vt      = (u16*)(wsb + 96 * MB);     // reuse: 8 MB V^T (b,f,t)
    u16* Sbf     = (u16*)(wsb + 104 * MB);    // 32 MB scores (16,1024,1024)
    u16* Gbf     = (u16*)(wsb + 104 * MB);    // reuse: 16 MB ffn mid
    u16* W0      = (u16*)(wsb + 136 * MB);    // bf16 weights

    u16* glu_wb  = W0;
    u16* c1L_pwb = W0 + 2097152;
    u16* c1R_pwb = W0 + 3145728;
    u16* c1M_pwb = W0 + 3670016;
    u16* qkv_wb  = W0 + 4718592;   // q,k,v contiguous (3072 x 1024)
    u16* o_wb    = W0 + 7864320;
    u16* c2_wb   = W0 + 8912896;
    u16* c3_wb   = W0 + 11010048;
    u16* ertb    = W0 + 13107200;  // 262144 (t-major er transpose, shared)
    float* qkvb  = (float*)(W0 + 13369344);  // 3072 fp32

    const dim3 blk256(256);
    const dim3 tgrid(32, 32, NB);
    const dim3 tblk(32, 8);
    const int EW = 16384;  // 4M / 256

    // --- 1. weight prep + input projection (fused, independent work) ---
    CastArgs ca;
    ca.s[0] = glu_w;  ca.s[1] = c1L_pw; ca.s[2] = c1R_pw; ca.s[3] = c1M_pw;
    ca.s[4] = q_w;    ca.s[5] = k_w;    ca.s[6] = v_w;    ca.s[7] = o_w;
    ca.s[8] = c2_w;   ca.s[9] = c3_w;
    ca.er = er; ca.qb = q_b; ca.kb = k_b; ca.vb = v_b;
    ca.ert = ertb; ca.qkvb = qkvb;
    castin_k<<<28672, blk256, 0, stream>>>(ca, W0, src, in_w, X);

    // 2-4. h = ln1(x); x += glu(h @ glu_w^T)  [fused]
    ln_bf_k<<<4096, blk256, 0, stream>>>(X, Hbf, ln1_g, ln1_b);
    glugemm_k<<<dim3(16, 32, 1), blk256, 0, stream>>>(
        Hbf, glu_wb, glu_wb + 1048576, X);
    // 5. h = ln2(x)
    ln_bf_k<<<4096, blk256, 0, stream>>>(X, Hbf, ln2_g, ln2_b);
    // 6. both depthwise convs of h (fused; independent GEMM chains follow)
    dconvFT_k<<<20480, blk256, 0, stream>>>(Hbf, T1bf, c1R_dw, T2bf, c1L_dw);
    // 7. hL = relu(c1L_pw · dconvF(h)) -> bf16 SB   [128x64, 2 blk/CU]
    gemm_bf<128, 64, 1, 2><<<dim3(16, 8, NB), blk256, 0, stream>>>(
        c1L_pwb, T2bf, SB, 1024, 1024, 1024, 1024, 0, M1, M1, nullptr, 1.f);
    // 8. SB[:, :512] += relu(dconvT(h) @ c1R_pw^T)  [64x64, 2 blk/CU]
    gemm_bf<64, 64, 1, 3><<<dim3(8, 64, 1), blk256, 0, stream>>>(
        T1bf, c1R_pwb, SB, 1024, 1024, 1024, 1024, 0, 0, 0, nullptr, 1.f);
    // 9-11. h = ln3(SB); x += dconvT(h) @ c1M_pw^T  [128x64, 2 blk/CU]
    ln_bf_k<<<4096, blk256, 0, stream>>>(SB, Hbf, ln3_g, ln3_b);
    dconvT_bf_k<<<EW, blk256, 0, stream>>>(Hbf, T1bf, c1M_dw);
    gemm_bf<128, 64, 0, 3><<<dim3(16, 32, 1), blk256, 0, stream>>>(
        T1bf, c1M_pwb, X, 1024, 1024, 1024, 1024, 0, 0, 0, nullptr, 1.f);
    // 12. h = ln4(x)
    ln_bf_k<<<4096, blk256, 0, stream>>>(X, Hbf, ln4_g, ln4_b);
    // 13. fused QKV GEMM (4096x3072x1024) -> T3 bf16  [128x128, 3 blk/CU]
    gemm_bf<128, 128, 0, 2><<<dim3(24, 32, 1), blk256, 0, stream>>>(
        Hbf, qkv_wb, T3, 1024, 1024, 1024, 3072, 0, 0, 0, qkvb, 1.f);
    // 14. qc convs: q/k pack + V transpose + rowsum zero (fused)
    qkvpack_k<<<20544, blk256, 0, stream>>>(T3, qc_w, qc_b, Qpk, Kpk, Vt, rowsum);
    // 15. S = exp((QK^T + rel-pos)/32) + rowsum; plane->XCD affinity
    sgemm_exp_k<<<1024, blk256, 0, stream>>>(Qpk, Kpk, ertb, Sbf, rowsum, 0.03125f);
    // 16. AO = (S @ V) / rowsum; plane->XCD affinity; [128x64, 2 blk/CU]
    aogemm_k<<<512, blk256, 0, stream>>>(Sbf, Vt, rowsum, AO);
    // 17. x += AO @ o_w^T + o_b  [128x64, 2 blk/CU]
    gemm_bf<128, 64, 0, 3><<<dim3(16, 32, 1), blk256, 0, stream>>>(
        AO, o_wb, X, 1024, 1024, 1024, 1024, 0, 0, 0, o_b, 1.f);
    // 18-19. h = ln5(x); mid = relu(h @ c2_w^T)^2  [128x128, 2 blk/CU]
    ln_bf_k<<<4096, blk256, 0, stream>>>(X, Hbf, ln5_g, ln5_b);
    gemm_bf<128, 128, 2, 2><<<dim3(16, 32, 1), blk256, 0, stream>>>(
        Hbf, c2_wb, Gbf, 1024, 1024, 1024, 2048, 0, 0, 0, nullptr, 1.f);
    // 20. x += mid @ c3_w^T  [128x64, 2 blk/CU]
    gemm_bf<128, 64, 0, 3><<<dim3(16, 32, 1), blk256, 0, stream>>>(
        Gbf, c3_wb, X, 2048, 2048, 2048, 1024, 0, 0, 0, nullptr, 1.f);
    // 21. output head
    out_k<<<tgrid, tblk, 0, stream>>>(src, X, out_w, out);
}

// Round 5
// 510.622 us; speedup vs baseline: 1.1544x; 1.1047x over previous
//
#include <hip/hip_runtime.h>
#include <math.h>

// ---------------------------------------------------------------------------
// FrameTransformer — R12 (resubmit; prior run hit container infra failure).
// Vectorize strided-tap depthwise convs (short8, 16B/lane) + transposed
// [k][1024] f32 weight tables built in weight-prep.
// dconvFT_k was 40us @ 12% HBM / 28% VALU = scalar-load instruction-bound;
// same pattern in dconvT_bf_k and qkvpack q/k branch.
// R11 GEMM geometry (>=2 blocks/CU rule) + R10 VALU fixes + R9 fusion kept.
// ---------------------------------------------------------------------------

typedef unsigned short u16;
typedef __attribute__((ext_vector_type(4))) float floatx4;
typedef __attribute__((ext_vector_type(8))) short short8;

#define NB 4
static const long long M1 = 1024LL * 1024LL;

__device__ __forceinline__ float bf2f(u16 h) {
    union { unsigned int u; float f; } v;
    v.u = ((unsigned int)h) << 16;
    return v.f;
}
__device__ __forceinline__ u16 f2bf(float x) {
    union { float f; unsigned int u; } v;
    v.f = x;
    unsigned int r = (v.u + 0x7FFFu + ((v.u >> 16) & 1u)) >> 16;
    return (u16)r;
}

__device__ __forceinline__ void async_cp16(const u16* g, u16* lds) {
    __builtin_amdgcn_global_load_lds(
        (const __attribute__((address_space(1))) unsigned int*)g,
        (__attribute__((address_space(3))) unsigned int*)lds, 16, 0, 0);
}

__device__ __forceinline__ float block_sum(float v) {
    __shared__ float sd[4];
    #pragma unroll
    for (int off = 32; off; off >>= 1) v += __shfl_down(v, off, 64);
    int lane = threadIdx.x & 63, wid = threadIdx.x >> 6;
    __syncthreads();
    if (lane == 0) sd[wid] = v;
    __syncthreads();
    return sd[0] + sd[1] + sd[2] + sd[3];
}

// ---------------------------------------------------------------------------
// bf16 NT GEMM: C[M,N] (op)= act( scale*(A·B^T + bias) )
// OUT: 0 = f32 store, 1 = f32 accum, 2 = bf16 store, 3 = bf16 accum.
// ---------------------------------------------------------------------------
template<int BM, int BN, int ACT, int OUT>
__global__ __launch_bounds__(256)
void gemm_bf(const u16* __restrict__ A, const u16* __restrict__ B,
             void* __restrict__ Cv, int K, int lda, int ldb, int ldc,
             long long sAz, long long sBz, long long sCz,
             const float* __restrict__ bias, float scale)
{
    constexpr int MI = BM / 32;
    constexpr int NJ = BN / 32;

    A += (long long)blockIdx.z * sAz;
    B += (long long)blockIdx.z * sBz;
    const long long zc = (long long)blockIdx.z * sCz;

    __shared__ u16 As[BM * 64];
    __shared__ u16 Bs[BN * 64];

    const int id = blockIdx.x + gridDim.x * blockIdx.y;
    const int bx = (id >> 3) % gridDim.x;
    const int by = (id & 7) + 8 * ((id >> 3) / gridDim.x);
    const int m0 = by * BM;
    const int n0 = bx * BN;

    const int lane = threadIdx.x & 63;
    const int w    = threadIdx.x >> 6;
    const int wm   = (w >> 1) * (BM / 2);
    const int wn   = (w & 1) * (BN / 2);
    const int srow = lane >> 2;
    const int scol = (lane & 3) * 8;

    floatx4 acc[MI][NJ];
    #pragma unroll
    for (int i = 0; i < MI; i++)
        #pragma unroll
        for (int j = 0; j < NJ; j++)
            acc[i][j] = floatx4{0.f, 0.f, 0.f, 0.f};

    for (int k0 = 0; k0 < K; k0 += 64) {
        #pragma unroll
        for (int r = 0; r < BM / 32; r++) {
            const int inst = w * (BM / 32) + r;
            const int rg = inst >> 1, kb = inst & 1;
            async_cp16(A + (long long)(m0 + rg * 16 + srow) * lda + k0 + kb * 32 + scol,
                       &As[(rg * 2 + kb) * 512]);
        }
        #pragma unroll
        for (int r = 0; r < BN / 32; r++) {
            const int inst = w * (BN / 32) + r;
            const int rg = inst >> 1, kb = inst & 1;
            async_cp16(B + (long long)(n0 + rg * 16 + srow) * ldb + k0 + kb * 32 + scol,
                       &Bs[(rg * 2 + kb) * 512]);
        }
        __syncthreads();

        #pragma unroll
        for (int s = 0; s < 2; s++) {
            short8 a[MI], b[NJ];
            const int fr = lane & 15;
            const int q  = lane >> 4;
            const int go = (fr * 4 + q) * 8;
            #pragma unroll
            for (int i = 0; i < MI; i++)
                a[i] = *(const short8*)&As[(((wm >> 4) + i) * 2 + s) * 512 + go];
            #pragma unroll
            for (int j = 0; j < NJ; j++)
                b[j] = *(const short8*)&Bs[(((wn >> 4) + j) * 2 + s) * 512 + go];
            #pragma unroll
            for (int i = 0; i < MI; i++)
                #pragma unroll
                for (int j = 0; j < NJ; j++)
                    acc[i][j] = __builtin_amdgcn_mfma_f32_16x16x32_bf16(
                        a[i], b[j], acc[i][j], 0, 0, 0);
        }
        __syncthreads();
    }

    float* Cf = (float*)Cv;
    u16*  Cb  = (u16*)Cv;
    const int cn    = n0 + wn + (lane & 15);
    const int rbase = m0 + wm + (lane >> 4) * 4;
    float bj[NJ];
    #pragma unroll
    for (int j = 0; j < NJ; j++) bj[j] = bias ? bias[cn + j * 16] : 0.f;

    #pragma unroll
    for (int i = 0; i < MI; i++) {
        #pragma unroll
        for (int r = 0; r < 4; r++) {
            const int m = rbase + i * 16 + r;
            #pragma unroll
            for (int j = 0; j < NJ; j++) {
                const int n = cn + j * 16;
                float v = (acc[i][j][r] + bj[j]) * scale;
                if (ACT == 1) v = fmaxf(v, 0.f);
                else if (ACT == 2) { v = fmaxf(v, 0.f); v = v * v; }
                const long long ci = zc + (long long)m * ldc + n;
                if (OUT == 0)      Cf[ci] = v;
                else if (OUT == 1) Cf[ci] += v;
                else if (OUT == 2) Cb[ci] = f2bf(v);
                else               Cb[ci] = f2bf(bf2f(Cb[ci]) + v);
            }
        }
    }
}

// GLU-fused GEMM: X[m,n] (bf16) += (A·B1^T)[m,n] * sigmoid((A·B2^T)[m,n])
__global__ __launch_bounds__(256)
void glugemm_k(const u16* __restrict__ A, const u16* __restrict__ B1,
               const u16* __restrict__ B2, u16* __restrict__ X)
{
    constexpr int BM = 128, BN = 64, MI = 4, NJ = 2;
    __shared__ u16 As[BM * 64];
    __shared__ u16 B1s[BN * 64];
    __shared__ u16 B2s[BN * 64];

    const int id = blockIdx.x + gridDim.x * blockIdx.y;
    const int bx = (id >> 3) % gridDim.x;
    const int by = (id & 7) + 8 * ((id >> 3) / gridDim.x);
    const int m0 = by * BM;
    const int n0 = bx * BN;

    const int lane = threadIdx.x & 63;
    const int w    = threadIdx.x >> 6;
    const int wm   = (w >> 1) * 64;
    const int wn   = (w & 1) * 32;
    const int srow = lane >> 2;
    const int scol = (lane & 3) * 8;

    floatx4 acc1[MI][NJ], acc2[MI][NJ];
    #pragma unroll
    for (int i = 0; i < MI; i++)
        #pragma unroll
        for (int j = 0; j < NJ; j++) {
            acc1[i][j] = floatx4{0.f, 0.f, 0.f, 0.f};
            acc2[i][j] = floatx4{0.f, 0.f, 0.f, 0.f};
        }

    for (int k0 = 0; k0 < 1024; k0 += 64) {
        #pragma unroll
        for (int r = 0; r < 4; r++) {
            const int inst = w * 4 + r;
            const int rg = inst >> 1, kb = inst & 1;
            async_cp16(A + (long long)(m0 + rg * 16 + srow) * 1024 + k0 + kb * 32 + scol,
                       &As[(rg * 2 + kb) * 512]);
        }
        #pragma unroll
        for (int r = 0; r < 2; r++) {
            const int inst = w * 2 + r;
            const int rg = inst >> 1, kb = inst & 1;
            async_cp16(B1 + (long long)(n0 + rg * 16 + srow) * 1024 + k0 + kb * 32 + scol,
                       &B1s[(rg * 2 + kb) * 512]);
            async_cp16(B2 + (long long)(n0 + rg * 16 + srow) * 1024 + k0 + kb * 32 + scol,
                       &B2s[(rg * 2 + kb) * 512]);
        }
        __syncthreads();

        #pragma unroll
        for (int s = 0; s < 2; s++) {
            short8 a[MI], b1[NJ], b2[NJ];
            const int fr = lane & 15;
            const int q  = lane >> 4;
            const int go = (fr * 4 + q) * 8;
            #pragma unroll
            for (int i = 0; i < MI; i++)
                a[i] = *(const short8*)&As[(((wm >> 4) + i) * 2 + s) * 512 + go];
            #pragma unroll
            for (int j = 0; j < NJ; j++) {
                b1[j] = *(const short8*)&B1s[(((wn >> 4) + j) * 2 + s) * 512 + go];
                b2[j] = *(const short8*)&B2s[(((wn >> 4) + j) * 2 + s) * 512 + go];
            }
            #pragma unroll
            for (int i = 0; i < MI; i++)
                #pragma unroll
                for (int j = 0; j < NJ; j++) {
                    acc1[i][j] = __builtin_amdgcn_mfma_f32_16x16x32_bf16(
                        a[i], b1[j], acc1[i][j], 0, 0, 0);
                    acc2[i][j] = __builtin_amdgcn_mfma_f32_16x16x32_bf16(
                        a[i], b2[j], acc2[i][j], 0, 0, 0);
                }
        }
        __syncthreads();
    }

    const int cn    = n0 + wn + (lane & 15);
    const int rbase = m0 + wm + (lane >> 4) * 4;
    #pragma unroll
    for (int i = 0; i < MI; i++)
        #pragma unroll
        for (int r = 0; r < 4; r++) {
            const int m = rbase + i * 16 + r;
            #pragma unroll
            for (int j = 0; j < NJ; j++) {
                const int n = cn + j * 16;
                float g = acc1[i][j][r] / (1.f + __expf(-acc2[i][j][r]));
                u16* xp = &X[(long long)m * 1024 + n];
                *xp = f2bf(bf2f(*xp) + g);
            }
        }
}

// Shared MMA step (reads As/Bs/MI/NJ/wm/wn/lane from enclosing scope).
#define SGEMM_MMA_STEP                                                        \
    __syncthreads();                                                          \
    _Pragma("unroll")                                                         \
    for (int s = 0; s < 2; s++) {                                             \
        short8 a[MI], b[NJ];                                                  \
        const int fr = lane & 15;                                             \
        const int q  = lane >> 4;                                             \
        const int go = (fr * 4 + q) * 8;                                      \
        _Pragma("unroll")                                                     \
        for (int i = 0; i < MI; i++)                                          \
            a[i] = *(const short8*)&As[(((wm >> 4) + i) * 2 + s) * 512 + go]; \
        _Pragma("unroll")                                                     \
        for (int j = 0; j < NJ; j++)                                          \
            b[j] = *(const short8*)&Bs[(((wn >> 4) + j) * 2 + s) * 512 + go]; \
        _Pragma("unroll")                                                     \
        for (int i = 0; i < MI; i++)                                          \
            _Pragma("unroll")                                                 \
            for (int j = 0; j < NJ; j++)                                      \
                acc[i][j] = __builtin_amdgcn_mfma_f32_16x16x32_bf16(          \
                    a[i], b[j], acc[i][j], 0, 0, 0);                          \
    }                                                                         \
    __syncthreads();

// S GEMM + exp + rowsum, plane->XCD affinity (grid 1024 1-D).
// K-loop peeled into two compile-time halves (k<256: Q·K, k>=256: Er·Q).
__global__ __launch_bounds__(256)
void sgemm_exp_k(const u16* __restrict__ Qpk, const u16* __restrict__ Kpk,
                 const u16* __restrict__ ErT,
                 u16* __restrict__ S, float* __restrict__ rowsum, float scale)
{
    constexpr int MI = 4, NJ = 4;
    const int i0 = blockIdx.x;
    const int x  = i0 & 7;
    const int j0 = i0 >> 3;            // 0..127
    const int z  = x + 8 * (j0 & 1);   // plane
    const int t  = j0 >> 1;            // 0..63
    const int bx = t & 7, by = t >> 3;

    const u16* Aq = Qpk + (long long)z * 262144;
    const u16* Bk = Kpk + (long long)z * 262144;
    S += (long long)z * M1;
    rowsum += z << 10;

    __shared__ u16 As[128 * 64];
    __shared__ u16 Bs[128 * 64];

    const int m0 = by * 128;
    const int n0 = bx * 128;

    const int lane = threadIdx.x & 63;
    const int w    = threadIdx.x >> 6;
    const int wm   = (w >> 1) * 64;
    const int wn   = (w & 1) * 64;
    const int srow = lane >> 2;
    const int scol = (lane & 3) * 8;

    floatx4 acc[MI][NJ];
    #pragma unroll
    for (int i = 0; i < MI; i++)
        #pragma unroll
        for (int j = 0; j < NJ; j++)
            acc[i][j] = floatx4{0.f, 0.f, 0.f, 0.f};

    // half 1: k in [0,256) — A from Qpk, B from Kpk (compile-time sources)
    for (int k0 = 0; k0 < 256; k0 += 64) {
        #pragma unroll
        for (int r = 0; r < 4; r++) {
            const int inst = w * 4 + r;
            const int rg = inst >> 1, kb = inst & 1;
            const int cb = k0 + kb * 32;
            async_cp16(Aq + (long long)(m0 + rg * 16 + srow) * 256 + cb + scol,
                       &As[(rg * 2 + kb) * 512]);
            async_cp16(Bk + (long long)(n0 + rg * 16 + srow) * 256 + cb + scol,
                       &Bs[(rg * 2 + kb) * 512]);
        }
        SGEMM_MMA_STEP
    }
    // half 2: k in [256,512) — A from ErT (shared, L2-hot), B from Qpk
    for (int k0 = 0; k0 < 256; k0 += 64) {
        #pragma unroll
        for (int r = 0; r < 4; r++) {
            const int inst = w * 4 + r;
            const int rg = inst >> 1, kb = inst & 1;
            const int cb = k0 + kb * 32;
            async_cp16(ErT + (long long)(m0 + rg * 16 + srow) * 256 + cb + scol,
                       &As[(rg * 2 + kb) * 512]);
            async_cp16(Aq + (long long)(n0 + rg * 16 + srow) * 256 + cb + scol,
                       &Bs[(rg * 2 + kb) * 512]);
        }
        SGEMM_MMA_STEP
    }

    const int cn    = n0 + wn + (lane & 15);
    const int rbase = m0 + wm + (lane >> 4) * 4;
    #pragma unroll
    for (int i = 0; i < MI; i++)
        #pragma unroll
        for (int r = 0; r < 4; r++) {
            const int m = rbase + i * 16 + r;
            float part = 0.f;
            #pragma unroll
            for (int j = 0; j < NJ; j++) {
                const int n = cn + j * 16;
                float e = __expf(acc[i][j][r] * scale);
                S[(long long)m * 1024 + n] = f2bf(e);
                part += e;
            }
            #pragma unroll
            for (int off = 8; off; off >>= 1) part += __shfl_xor(part, off, 64);
            if ((lane & 15) == 0) atomicAdd(&rowsum[m], part);
        }
}

// AO GEMM + rowsum divide, plane->XCD affinity (grid 512 1-D),
// 128x64 tile (2 blocks/CU), writes AO in (B,T,F) layout directly.
__global__ __launch_bounds__(256)
void aogemm_k(const u16* __restrict__ Sb, const u16* __restrict__ Vt,
              const float* __restrict__ rowsum, u16* __restrict__ AO)
{
    constexpr int MI = 4, NJ = 2;
    const int i0 = blockIdx.x;
    const int x  = i0 & 7;
    const int j0 = i0 >> 3;            // 0..63
    const int z  = x + 8 * (j0 & 1);
    const int t  = j0 >> 1;            // 0..31
    const int bx = t & 3, by = t >> 2;

    Sb += (long long)z * M1;
    Vt += (long long)z * 262144;
    rowsum += z << 10;
    const long long zc = (long long)(z >> 2) * M1 + (z & 3) * 256;

    __shared__ u16 As[128 * 64];
    __shared__ u16 Bs[64 * 64];

    const int m0 = by * 128;
    const int n0 = bx * 64;

    const int lane = threadIdx.x & 63;
    const int w    = threadIdx.x >> 6;
    const int wm   = (w >> 1) * 64;
    const int wn   = (w & 1) * 32;
    const int srow = lane >> 2;
    const int scol = (lane & 3) * 8;

    floatx4 acc[MI][NJ];
    #pragma unroll
    for (int i = 0; i < MI; i++)
        #pragma unroll
        for (int j = 0; j < NJ; j++)
            acc[i][j] = floatx4{0.f, 0.f, 0.f, 0.f};

    for (int k0 = 0; k0 < 1024; k0 += 64) {
        #pragma unroll
        for (int r = 0; r < 4; r++) {
            const int inst = w * 4 + r;
            const int rg = inst >> 1, kb = inst & 1;
            async_cp16(Sb + (long long)(m0 + rg * 16 + srow) * 1024 + k0 + kb * 32 + scol,
                       &As[(rg * 2 + kb) * 512]);
        }
        #pragma unroll
        for (int r = 0; r < 2; r++) {
            const int inst = w * 2 + r;
            const int rg = inst >> 1, kb = inst & 1;
            async_cp16(Vt + (long long)(n0 + rg * 16 + srow) * 1024 + k0 + kb * 32 + scol,
                       &Bs[(rg * 2 + kb) * 512]);
        }
        SGEMM_MMA_STEP
    }

    const int cn    = n0 + wn + (lane & 15);
    const int rbase = m0 + wm + (lane >> 4) * 4;
    #pragma unroll
    for (int i = 0; i < MI; i++)
        #pragma unroll
        for (int r = 0; r < 4; r++) {
            const int m = rbase + i * 16 + r;
            const float inv = 1.f / rowsum[m];
            #pragma unroll
            for (int j = 0; j < NJ; j++) {
                const int n = cn + j * 16;
                AO[zc + (long long)m * 1024 + n] = f2bf(acc[i][j][r] * inv);
            }
        }
}

// ---------------------------------------------------------------------------
// LayerNorm: bf16 in -> bf16 out. One block per row.
__global__ __launch_bounds__(256)
void ln_bf_k(const u16* __restrict__ in, u16* __restrict__ out,
             const float* __restrict__ g, const float* __restrict__ b)
{
    long long row = blockIdx.x;
    int tid = threadIdx.x;
    ushort4 u = ((const ushort4*)(in + (row << 10)))[tid];
    float x0 = bf2f(u.x), x1 = bf2f(u.y), x2 = bf2f(u.z), x3 = bf2f(u.w);
    float s = x0 + x1 + x2 + x3;
    s = block_sum(s);
    float mean = s * (1.f / 1024.f);
    float dx = x0 - mean, dy = x1 - mean, dz = x2 - mean, dw = x3 - mean;
    float s2 = dx * dx + dy * dy + dz * dz + dw * dw;
    s2 = block_sum(s2);
    float inv = rsqrtf(s2 * (1.f / 1024.f) + 1e-5f);
    float4 gg = ((const float4*)g)[tid];
    float4 bb = ((const float4*)b)[tid];
    ushort4 o;
    o.x = f2bf(dx * inv * gg.x + bb.x);
    o.y = f2bf(dy * inv * gg.y + bb.y);
    o.z = f2bf(dz * inv * gg.z + bb.z);
    o.w = f2bf(dw * inv * gg.w + bb.w);
    ((ushort4*)(out + (row << 10)))[tid] = o;
}

// ---------------------------------------------------------------------------
// Vectorized depthwise conv along t (k=7, pad 3), 8 f per thread.
// wtr: transposed weights [k][1024] f32. gidx in [0, 524288).
__device__ __forceinline__ void dconv7_vec8(
    const u16* __restrict__ in, u16* __restrict__ out,
    const float* __restrict__ wtr, int gidx)
{
    const int f8 = (gidx & 127) * 8;
    const int bt = gidx >> 7;
    const int t  = bt & 1023;
    const long long rowbase = (long long)(bt - t) * 1024;  // b*1024*1024
    float acc[8] = {0.f, 0.f, 0.f, 0.f, 0.f, 0.f, 0.f, 0.f};
    #pragma unroll
    for (int k = 0; k < 7; k++) {
        int tt = t + k - 3;
        if (tt >= 0 && tt < 1024) {
            short8 v = *(const short8*)&in[rowbase + (long long)tt * 1024 + f8];
            float4 wa = *(const float4*)&wtr[k * 1024 + f8];
            float4 wb = *(const float4*)&wtr[k * 1024 + f8 + 4];
            acc[0] += bf2f((u16)v[0]) * wa.x;
            acc[1] += bf2f((u16)v[1]) * wa.y;
            acc[2] += bf2f((u16)v[2]) * wa.z;
            acc[3] += bf2f((u16)v[3]) * wa.w;
            acc[4] += bf2f((u16)v[4]) * wb.x;
            acc[5] += bf2f((u16)v[5]) * wb.y;
            acc[6] += bf2f((u16)v[6]) * wb.z;
            acc[7] += bf2f((u16)v[7]) * wb.w;
        }
    }
    short8 o;
    #pragma unroll
    for (int i = 0; i < 8; i++) o[i] = (short)f2bf(acc[i]);
    *(short8*)&out[(long long)bt * 1024 + f8] = o;
}

// ---------------------------------------------------------------------------
// Fused weight prep + input projection (independent front-of-graph work).
// blocks [0, 24576): castall (seg = bid>>11); blocks [24576, 28672): inproj.
struct CastArgs {
    const float* s[10];
    const float* er; const float* qb; const float* kb; const float* vb;
    const float* dwR; const float* dwM; const float* dwQ;   // k=7 dconv weights
    u16* ert; float* qkvb; float* wtr;                      // wtr: 3x[7][1024]
};
__global__ __launch_bounds__(256)
void castin_k(CastArgs a, u16* __restrict__ dst,
              const float* __restrict__ src, const float* __restrict__ inw,
              u16* __restrict__ X)
{
    const int bid = blockIdx.x;
    if (bid < 24576) {
        const int sz[10] = {2097152, 1048576, 524288, 1048576, 1048576,
                            1048576, 1048576, 1048576, 2097152, 2097152};
        int seg = bid >> 11;
        int tid = (bid & 2047) * 256 + threadIdx.x;
        if (seg < 10) {
            int n = sz[seg];
            int base = 0;
            for (int i = 0; i < seg; i++) base += sz[i];
            int i4 = tid * 4;
            if (i4 >= n) return;
            float4 v = *(const float4*)(a.s[seg] + i4);
            ushort4 o;
            o.x = f2bf(v.x); o.y = f2bf(v.y); o.z = f2bf(v.z); o.w = f2bf(v.w);
            *(ushort4*)(dst + base + i4) = o;
        } else if (seg == 10) {
            if (tid < 262144) {
                int j = tid >> 8, d = tid & 255;
                a.ert[tid] = f2bf(a.er[d * 1024 + j]);
            }
        } else {
            if (tid < 1024) a.qkvb[tid] = a.qb[tid];
            else if (tid < 2048) a.qkvb[tid] = a.kb[tid - 1024];
            else if (tid < 3072) a.qkvb[tid] = a.vb[tid - 2048];
            else if (tid < 3072 + 21504) {
                int i = tid - 3072;
                int tbl = i / 7168, r = i - tbl * 7168;
                int k = r >> 10, f = r & 1023;
                const float* s = (tbl == 0) ? a.dwR : (tbl == 1) ? a.dwM : a.dwQ;
                a.wtr[tbl * 7168 + k * 1024 + f] = s[f * 7 + k];
            }
        }
    } else {
        __shared__ float tile[32][33];
        int ib = bid - 24576;
        int f0 = (ib & 31) * 32, t0 = ((ib >> 5) & 31) * 32, b = ib >> 10;
        int tx = threadIdx.x & 31, ty = threadIdx.x >> 5;
        float w0 = inw[0], w1 = inw[1];
        for (int r = ty; r < 32; r += 8) {
            int f = f0 + r, t = t0 + tx;
            float s0 = src[(((long long)b * 2 + 0) * 1025 + f) * 1024 + t];
            float s1 = src[(((long long)b * 2 + 1) * 1025 + f) * 1024 + t];
            tile[r][tx] = w0 * s0 + w1 * s1;
        }
        __syncthreads();
        for (int r = ty; r < 32; r += 8)
            X[((long long)b * 1024 + t0 + r) * 1024 + f0 + tx] = f2bf(tile[tx][r]);
    }
}

// ---------------------------------------------------------------------------
// Fused dconvF (k=11, along f, transposed out, LDS tiles) + vectorized
// dconvT (k=7, along t, short8).
// blocks [0, 2048): dconvT -> outT; blocks [2048, 6144): dconvF -> outF.
__global__ __launch_bounds__(256)
void dconvFT_k(const u16* __restrict__ in, u16* __restrict__ outT,
               const float* __restrict__ wtrT, u16* __restrict__ outF,
               const float* __restrict__ wF)
{
    const int bid = blockIdx.x;
    if (bid < 2048) {
        dconv7_vec8(in, outT, wtrT, bid * 256 + threadIdx.x);
    } else {
        __shared__ float itile[32][44];
        __shared__ float otile[32][33];
        int ib = bid - 2048;
        int f0 = (ib & 31) * 32, t0 = ((ib >> 5) & 31) * 32, b = ib >> 10;
        int tx = threadIdx.x & 31, ty = threadIdx.x >> 5;
        for (int r = ty; r < 32; r += 8)
            for (int c = tx; c < 42; c += 32) {
                int f = f0 - 5 + c;
                itile[r][c] = (f >= 0 && f < 1024)
                    ? bf2f(in[((long long)(b * 1024 + t0 + r)) * 1024 + f]) : 0.f;
            }
        __syncthreads();
        for (int r = ty; r < 32; r += 8) {
            const float* wr = wF + (t0 + r) * 11;
            float acc = 0.f;
            #pragma unroll
            for (int k = 0; k < 11; k++) acc += itile[r][tx + k] * wr[k];
            otile[tx][r] = acc;
        }
        __syncthreads();
        for (int r = ty; r < 32; r += 8)
            outF[((long long)(b * 1024 + f0 + r)) * 1024 + t0 + tx] = f2bf(otile[r][tx]);
    }
}

// Vectorized dconv along t (k=7 pad 3), bf16 (B,T,F)->(B,T,F). grid 2048.
__global__ __launch_bounds__(256)
void dconvT_bf_k(const u16* __restrict__ in, u16* __restrict__ out,
                 const float* __restrict__ wtr)
{
    dconv7_vec8(in, out, wtr, blockIdx.x * 256 + threadIdx.x);
}

// ---------------------------------------------------------------------------
// Fused QKV post-processing: vectorized q/k dconv+pack (short8, 2 planes),
// v dconv+transpose (LDS tiles), rowsum zero.
// blocks [0,2048): q/k pack; [2048,6144): vconv; [6144,6208): rowsum=0.
__global__ __launch_bounds__(256)
void qkvpack_k(const u16* __restrict__ T3, const float* __restrict__ w,
               const float* __restrict__ wtrQ, const float* __restrict__ bias,
               u16* __restrict__ Qpk, u16* __restrict__ Kpk,
               u16* __restrict__ Vt, float* __restrict__ rowsum)
{
    const int bid = blockIdx.x;
    if (bid < 2048) {
        const int gidx = bid * 256 + threadIdx.x;   // 0..524287
        const int f8 = (gidx & 127) * 8;
        const int t  = (gidx >> 7) & 1023;
        const int b  = gidx >> 17;
        float4 b0 = *(const float4*)&bias[f8];
        float4 b1 = *(const float4*)&bias[f8 + 4];
        float aq[8] = {b0.x, b0.y, b0.z, b0.w, b1.x, b1.y, b1.z, b1.w};
        float ak[8] = {b0.x, b0.y, b0.z, b0.w, b1.x, b1.y, b1.z, b1.w};
        #pragma unroll
        for (int k = 0; k < 7; k++) {
            int tt = t + k - 3;
            if (tt >= 0 && tt < 1024) {
                const u16* row = T3 + ((long long)((b << 10) + tt)) * 3072 + f8;
                short8 vq = *(const short8*)&row[0];
                short8 vk = *(const short8*)&row[1024];
                float4 wa = *(const float4*)&wtrQ[k * 1024 + f8];
                float4 wb = *(const float4*)&wtrQ[k * 1024 + f8 + 4];
                aq[0] += bf2f((u16)vq[0]) * wa.x;  ak[0] += bf2f((u16)vk[0]) * wa.x;
                aq[1] += bf2f((u16)vq[1]) * wa.y;  ak[1] += bf2f((u16)vk[1]) * wa.y;
                aq[2] += bf2f((u16)vq[2]) * wa.z;  ak[2] += bf2f((u16)vk[2]) * wa.z;
                aq[3] += bf2f((u16)vq[3]) * wa.w;  ak[3] += bf2f((u16)vk[3]) * wa.w;
                aq[4] += bf2f((u16)vq[4]) * wb.x;  ak[4] += bf2f((u16)vk[4]) * wb.x;
                aq[5] += bf2f((u16)vq[5]) * wb.y;  ak[5] += bf2f((u16)vk[5]) * wb.y;
                aq[6] += bf2f((u16)vq[6]) * wb.z;  ak[6] += bf2f((u16)vk[6]) * wb.z;
                aq[7] += bf2f((u16)vq[7]) * wb.w;  ak[7] += bf2f((u16)vk[7]) * wb.w;
            }
        }
        const int band = f8 >> 8, d = f8 & 255, z = (b << 2) | band;
        const long long base = (long long)z * 262144 + t * 256 + d;
        short8 oq, ok;
        #pragma unroll
        for (int i = 0; i < 8; i++) {
            oq[i] = (short)f2bf(aq[i]);
            ok[i] = (short)f2bf(ak[i]);
        }
        *(short8*)&Qpk[base] = oq;
        *(short8*)&Kpk[base] = ok;
    } else if (bid < 6144) {
        __shared__ float itile[38][32];
        __shared__ float otile[32][33];
        int vb = bid - 2048;
        int f0 = (vb & 31) * 32, t0 = ((vb >> 5) & 31) * 32, b = vb >> 10;
        int tx = threadIdx.x & 31, ty = threadIdx.x >> 5;
        for (int i = threadIdx.x; i < 38 * 32; i += 256) {
            int r = i >> 5, c = i & 31;
            int t = t0 - 3 + r;
            itile[r][c] = (t >= 0 && t < 1024)
                ? bf2f(T3[((long long)(b * 1024 + t)) * 3072 + 2048 + f0 + c]) : 0.f;
        }
        __syncthreads();
        for (int r = ty; r < 32; r += 8) {
            const float* wr = w + (f0 + tx) * 7;
            float acc = bias[f0 + tx];
            #pragma unroll
            for (int k = 0; k < 7; k++) acc += itile[r + k][tx] * wr[k];
            otile[tx][r] = acc;
        }
        __syncthreads();
        for (int r = ty; r < 32; r += 8)
            Vt[((long long)(b * 1024 + f0 + r)) * 1024 + t0 + tx] = f2bf(otile[r][tx]);
    } else {
        int i = (bid - 6144) * 256 + threadIdx.x;  // 16384 floats
        rowsum[i] = 0.f;
    }
}

// Output head: reads bf16 X.
__global__ __launch_bounds__(256)
void out_k(const float* __restrict__ src, const u16* __restrict__ X,
           const float* __restrict__ ow, float* __restrict__ out)
{
    __shared__ float tile[32][33];
    int b = blockIdx.z;
    int f0 = blockIdx.y * 32, t0 = blockIdx.x * 32;
    for (int r = threadIdx.y; r < 32; r += 8)
        tile[r][threadIdx.x] = bf2f(X[((long long)b * 1024 + t0 + r) * 1024 + f0 + threadIdx.x]);
    __syncthreads();
    float w00 = ow[0], w01 = ow[1], w02 = ow[2];
    float w10 = ow[3], w11 = ow[4], w12 = ow[5];
    for (int r = threadIdx.y; r < 32; r += 8) {
        int f = f0 + r, t = t0 + threadIdx.x;
        float s0 = src[(((long long)b * 2 + 0) * 1025 + f) * 1024 + t];
        float s1 = src[(((long long)b * 2 + 1) * 1025 + f) * 1024 + t];
        float xv = tile[threadIdx.x][r];
        float v0 = fminf(fmaxf(w00 * s0 + w01 * s1 + w02 * xv, 0.f), 6.f) * (1.f / 6.f);
        float v1 = fminf(fmaxf(w10 * s0 + w11 * s1 + w12 * xv, 0.f), 6.f) * (1.f / 6.f);
        out[(((long long)b * 2 + 0) * 1025 + f) * 1024 + t] = v0;
        out[(((long long)b * 2 + 1) * 1025 + f) * 1024 + t] = v1;
        if (f == 1023) {
            out[(((long long)b * 2 + 0) * 1025 + 1024) * 1024 + t] = v0;
            out[(((long long)b * 2 + 1) * 1025 + 1024) * 1024 + t] = v1;
        }
    }
}

// ---------------------------------------------------------------------------
extern "C" void kernel_launch(void* const* d_in, const int* in_sizes, int n_in,
                              void* d_out, int out_size, void* d_ws, size_t ws_size,
                              hipStream_t stream)
{
    const float* src    = (const float*)d_in[0];
    const float* in_w   = (const float*)d_in[1];
    const float* ln1_g  = (const float*)d_in[2];
    const float* ln1_b  = (const float*)d_in[3];
    const float* glu_w  = (const float*)d_in[4];
    const float* ln2_g  = (const float*)d_in[5];
    const float* ln2_b  = (const float*)d_in[6];
    const float* c1L_dw = (const float*)d_in[7];
    const float* c1L_pw = (const float*)d_in[8];
    const float* c1R_dw = (const float*)d_in[9];
    const float* c1R_pw = (const float*)d_in[10];
    const float* ln3_g  = (const float*)d_in[11];
    const float* ln3_b  = (const float*)d_in[12];
    const float* c1M_dw = (const float*)d_in[13];
    const float* c1M_pw = (const float*)d_in[14];
    const float* ln4_g  = (const float*)d_in[15];
    const float* ln4_b  = (const float*)d_in[16];
    const float* q_w    = (const float*)d_in[17];
    const float* q_b    = (const float*)d_in[18];
    const float* qc_w   = (const float*)d_in[19];
    const float* qc_b   = (const float*)d_in[20];
    const float* k_w    = (const float*)d_in[21];
    const float* k_b    = (const float*)d_in[22];
    const float* v_w    = (const float*)d_in[23];
    const float* v_b    = (const float*)d_in[24];
    const float* o_w    = (const float*)d_in[25];
    const float* o_b    = (const float*)d_in[26];
    const float* er     = (const float*)d_in[27];
    const float* ln5_g  = (const float*)d_in[28];
    const float* ln5_b  = (const float*)d_in[29];
    const float* c2_w   = (const float*)d_in[30];
    const float* c3_w   = (const float*)d_in[31];
    const float* out_w  = (const float*)d_in[32];
    float* out = (float*)d_out;

    const size_t MB = 1ull << 20;
    if (ws_size < 162 * MB) return;
    char* wsb = (char*)d_ws;
    u16* X       = (u16*)(wsb + 0);           // 8 MB bf16 residual
    u16* SB      = (u16*)(wsb + 8 * MB);      // 8 MB bf16 hL+hR
    float* rowsum= (float*)(wsb + 16 * MB);   // 64 KB (free window, no alias)
    u16* Qpk     = (u16*)(wsb + 32 * MB);     // 8 MB q-pack (z,t,256)
    u16* Kpk     = (u16*)(wsb + 40 * MB);     // 8 MB k-pack (z,t,256)
    u16* Hbf     = (u16*)(wsb + 64 * MB);     // 8 MB ln outputs
    u16* T1bf    = (u16*)(wsb + 72 * MB);     // 8 MB dconv temps
    u16* T3      = (u16*)(wsb + 72 * MB);     // 24 MB QKV (4096x3072)
    u16* AO      = (u16*)(wsb + 80 * MB);     // 8 MB AO (B,T,F)
    u16* T2bf    = (u16*)(wsb + 96 * MB);     // 8 MB dconvF out (c1L)
    u16* Vt      = (u16*)(wsb + 96 * MB);     // reuse: 8 MB V^T (b,f,t)
    u16* Sbf     = (u16*)(wsb + 104 * MB);    // 32 MB scores (16,1024,1024)
    u16* Gbf     = (u16*)(wsb + 104 * MB);    // reuse: 16 MB ffn mid
    u16* W0      = (u16*)(wsb + 136 * MB);    // bf16 weights

    u16* glu_wb  = W0;
    u16* c1L_pwb = W0 + 2097152;
    u16* c1R_pwb = W0 + 3145728;
    u16* c1M_pwb = W0 + 3670016;
    u16* qkv_wb  = W0 + 4718592;   // q,k,v contiguous (3072 x 1024)
    u16* o_wb    = W0 + 7864320;
    u16* c2_wb   = W0 + 8912896;
    u16* c3_wb   = W0 + 11010048;
    u16* ertb    = W0 + 13107200;  // 262144 (t-major er transpose, shared)
    float* qkvb  = (float*)(W0 + 13369344);  // 3072 fp32
    float* wtrb  = qkvb + 3072;    // 3 x 7168 fp32 transposed dconv weights
    float* wtrR  = wtrb;           // c1R_dw  [7][1024]
    float* wtrM  = wtrb + 7168;    // c1M_dw  [7][1024]
    float* wtrQ  = wtrb + 14336;   // qc_w    [7][1024]

    const dim3 blk256(256);
    const dim3 tgrid(32, 32, NB);
    const dim3 tblk(32, 8);

    // --- 1. weight prep + input projection (fused, independent work) ---
    CastArgs ca;
    ca.s[0] = glu_w;  ca.s[1] = c1L_pw; ca.s[2] = c1R_pw; ca.s[3] = c1M_pw;
    ca.s[4] = q_w;    ca.s[5] = k_w;    ca.s[6] = v_w;    ca.s[7] = o_w;
    ca.s[8] = c2_w;   ca.s[9] = c3_w;
    ca.er = er; ca.qb = q_b; ca.kb = k_b; ca.vb = v_b;
    ca.dwR = c1R_dw; ca.dwM = c1M_dw; ca.dwQ = qc_w;
    ca.ert = ertb; ca.qkvb = qkvb; ca.wtr = wtrb;
    castin_k<<<28672, blk256, 0, stream>>>(ca, W0, src, in_w, X);

    // 2-4. h = ln1(x); x += glu(h @ glu_w^T)  [fused]
    ln_bf_k<<<4096, blk256, 0, stream>>>(X, Hbf, ln1_g, ln1_b);
    glugemm_k<<<dim3(16, 32, 1), blk256, 0, stream>>>(
        Hbf, glu_wb, glu_wb + 1048576, X);
    // 5. h = ln2(x)
    ln_bf_k<<<4096, blk256, 0, stream>>>(X, Hbf, ln2_g, ln2_b);
    // 6. both depthwise convs of h (fused; dconvT vectorized short8)
    dconvFT_k<<<6144, blk256, 0, stream>>>(Hbf, T1bf, wtrR, T2bf, c1L_dw);
    // 7. hL = relu(c1L_pw · dconvF(h)) -> bf16 SB   [128x64, 2 blk/CU]
    gemm_bf<128, 64, 1, 2><<<dim3(16, 8, NB), blk256, 0, stream>>>(
        c1L_pwb, T2bf, SB, 1024, 1024, 1024, 1024, 0, M1, M1, nullptr, 1.f);
    // 8. SB[:, :512] += relu(dconvT(h) @ c1R_pw^T)  [64x64, 2 blk/CU]
    gemm_bf<64, 64, 1, 3><<<dim3(8, 64, 1), blk256, 0, stream>>>(
        T1bf, c1R_pwb, SB, 1024, 1024, 1024, 1024, 0, 0, 0, nullptr, 1.f);
    // 9-11. h = ln3(SB); x += dconvT(h) @ c1M_pw^T  [128x64, 2 blk/CU]
    ln_bf_k<<<4096, blk256, 0, stream>>>(SB, Hbf, ln3_g, ln3_b);
    dconvT_bf_k<<<2048, blk256, 0, stream>>>(Hbf, T1bf, wtrM);
    gemm_bf<128, 64, 0, 3><<<dim3(16, 32, 1), blk256, 0, stream>>>(
        T1bf, c1M_pwb, X, 1024, 1024, 1024, 1024, 0, 0, 0, nullptr, 1.f);
    // 12. h = ln4(x)
    ln_bf_k<<<4096, blk256, 0, stream>>>(X, Hbf, ln4_g, ln4_b);
    // 13. fused QKV GEMM (4096x3072x1024) -> T3 bf16  [128x128, 3 blk/CU]
    gemm_bf<128, 128, 0, 2><<<dim3(24, 32, 1), blk256, 0, stream>>>(
        Hbf, qkv_wb, T3, 1024, 1024, 1024, 3072, 0, 0, 0, qkvb, 1.f);
    // 14. qc convs: vectorized q/k pack + V transpose + rowsum zero (fused)
    qkvpack_k<<<6208, blk256, 0, stream>>>(T3, qc_w, wtrQ, qc_b, Qpk, Kpk, Vt, rowsum);
    // 15. S = exp((QK^T + rel-pos)/32) + rowsum; plane->XCD affinity
    sgemm_exp_k<<<1024, blk256, 0, stream>>>(Qpk, Kpk, ertb, Sbf, rowsum, 0.03125f);
    // 16. AO = (S @ V) / rowsum; plane->XCD affinity; [128x64, 2 blk/CU]
    aogemm_k<<<512, blk256, 0, stream>>>(Sbf, Vt, rowsum, AO);
    // 17. x += AO @ o_w^T + o_b  [128x64, 2 blk/CU]
    gemm_bf<128, 64, 0, 3><<<dim3(16, 32, 1), blk256, 0, stream>>>(
        AO, o_wb, X, 1024, 1024, 1024, 1024, 0, 0, 0, o_b, 1.f);
    // 18-19. h = ln5(x); mid = relu(h @ c2_w^T)^2  [128x128, 2 blk/CU]
    ln_bf_k<<<4096, blk256, 0, stream>>>(X, Hbf, ln5_g, ln5_b);
    gemm_bf<128, 128, 2, 2><<<dim3(16, 32, 1), blk256, 0, stream>>>(
        Hbf, c2_wb, Gbf, 1024, 1024, 1024, 2048, 0, 0, 0, nullptr, 1.f);
    // 20. x += mid @ c3_w^T  [128x64, 2 blk/CU]
    gemm_bf<128, 64, 0, 3><<<dim3(16, 32, 1), blk256, 0, stream>>>(
        Gbf, c3_wb, X, 2048, 2048, 2048, 1024, 0, 0, 0, nullptr, 1.f);
    // 21. output head
    out_k<<<tgrid, tblk, 0, stream>>>(src, X, out_w, out);
}

// Round 6
// 504.024 us; speedup vs baseline: 1.1695x; 1.0131x over previous
//
#include <hip/hip_runtime.h>
#include <math.h>

// ---------------------------------------------------------------------------
// FrameTransformer — R13: XCD-chunked swizzle for tap-windowed kernels +
// c1L/c1R merged dispatch (split outputs, ln3-add).
//  * dconvT paths + qkvpack q/k: bid chunk-swizzle (bid%8)*256+bid/8 so each
//    XCD's L2 keeps its own t-slab (7-tap overlap was cross-XCD re-fetch:
//    dconvFT FETCH 21MB vs 8MB ideal in R3).
//  * c1L+c1R: one 1024-block dispatch -> SBL/SBR (no RMW, no serialization);
//    ln_add_bf_k sums them (exact same math, one fewer bf16 rounding).
// R12 short8 dconvs + R11 GEMM geometry + R10 VALU fixes + R9 fusion kept.
// ---------------------------------------------------------------------------

typedef unsigned short u16;
typedef __attribute__((ext_vector_type(4))) float floatx4;
typedef __attribute__((ext_vector_type(8))) short short8;

#define NB 4
static const long long M1 = 1024LL * 1024LL;

__device__ __forceinline__ float bf2f(u16 h) {
    union { unsigned int u; float f; } v;
    v.u = ((unsigned int)h) << 16;
    return v.f;
}
__device__ __forceinline__ u16 f2bf(float x) {
    union { float f; unsigned int u; } v;
    v.f = x;
    unsigned int r = (v.u + 0x7FFFu + ((v.u >> 16) & 1u)) >> 16;
    return (u16)r;
}

__device__ __forceinline__ void async_cp16(const u16* g, u16* lds) {
    __builtin_amdgcn_global_load_lds(
        (const __attribute__((address_space(1))) unsigned int*)g,
        (__attribute__((address_space(3))) unsigned int*)lds, 16, 0, 0);
}

__device__ __forceinline__ float block_sum(float v) {
    __shared__ float sd[4];
    #pragma unroll
    for (int off = 32; off; off >>= 1) v += __shfl_down(v, off, 64);
    int lane = threadIdx.x & 63, wid = threadIdx.x >> 6;
    __syncthreads();
    if (lane == 0) sd[wid] = v;
    __syncthreads();
    return sd[0] + sd[1] + sd[2] + sd[3];
}

// ---------------------------------------------------------------------------
// bf16 NT GEMM: C[M,N] (op)= act( scale*(A·B^T + bias) )
// OUT: 0 = f32 store, 1 = f32 accum, 2 = bf16 store, 3 = bf16 accum.
// ---------------------------------------------------------------------------
template<int BM, int BN, int ACT, int OUT>
__global__ __launch_bounds__(256)
void gemm_bf(const u16* __restrict__ A, const u16* __restrict__ B,
             void* __restrict__ Cv, int K, int lda, int ldb, int ldc,
             long long sAz, long long sBz, long long sCz,
             const float* __restrict__ bias, float scale)
{
    constexpr int MI = BM / 32;
    constexpr int NJ = BN / 32;

    A += (long long)blockIdx.z * sAz;
    B += (long long)blockIdx.z * sBz;
    const long long zc = (long long)blockIdx.z * sCz;

    __shared__ u16 As[BM * 64];
    __shared__ u16 Bs[BN * 64];

    const int id = blockIdx.x + gridDim.x * blockIdx.y;
    const int bx = (id >> 3) % gridDim.x;
    const int by = (id & 7) + 8 * ((id >> 3) / gridDim.x);
    const int m0 = by * BM;
    const int n0 = bx * BN;

    const int lane = threadIdx.x & 63;
    const int w    = threadIdx.x >> 6;
    const int wm   = (w >> 1) * (BM / 2);
    const int wn   = (w & 1) * (BN / 2);
    const int srow = lane >> 2;
    const int scol = (lane & 3) * 8;

    floatx4 acc[MI][NJ];
    #pragma unroll
    for (int i = 0; i < MI; i++)
        #pragma unroll
        for (int j = 0; j < NJ; j++)
            acc[i][j] = floatx4{0.f, 0.f, 0.f, 0.f};

    for (int k0 = 0; k0 < K; k0 += 64) {
        #pragma unroll
        for (int r = 0; r < BM / 32; r++) {
            const int inst = w * (BM / 32) + r;
            const int rg = inst >> 1, kb = inst & 1;
            async_cp16(A + (long long)(m0 + rg * 16 + srow) * lda + k0 + kb * 32 + scol,
                       &As[(rg * 2 + kb) * 512]);
        }
        #pragma unroll
        for (int r = 0; r < BN / 32; r++) {
            const int inst = w * (BN / 32) + r;
            const int rg = inst >> 1, kb = inst & 1;
            async_cp16(B + (long long)(n0 + rg * 16 + srow) * ldb + k0 + kb * 32 + scol,
                       &Bs[(rg * 2 + kb) * 512]);
        }
        __syncthreads();

        #pragma unroll
        for (int s = 0; s < 2; s++) {
            short8 a[MI], b[NJ];
            const int fr = lane & 15;
            const int q  = lane >> 4;
            const int go = (fr * 4 + q) * 8;
            #pragma unroll
            for (int i = 0; i < MI; i++)
                a[i] = *(const short8*)&As[(((wm >> 4) + i) * 2 + s) * 512 + go];
            #pragma unroll
            for (int j = 0; j < NJ; j++)
                b[j] = *(const short8*)&Bs[(((wn >> 4) + j) * 2 + s) * 512 + go];
            #pragma unroll
            for (int i = 0; i < MI; i++)
                #pragma unroll
                for (int j = 0; j < NJ; j++)
                    acc[i][j] = __builtin_amdgcn_mfma_f32_16x16x32_bf16(
                        a[i], b[j], acc[i][j], 0, 0, 0);
        }
        __syncthreads();
    }

    float* Cf = (float*)Cv;
    u16*  Cb  = (u16*)Cv;
    const int cn    = n0 + wn + (lane & 15);
    const int rbase = m0 + wm + (lane >> 4) * 4;
    float bj[NJ];
    #pragma unroll
    for (int j = 0; j < NJ; j++) bj[j] = bias ? bias[cn + j * 16] : 0.f;

    #pragma unroll
    for (int i = 0; i < MI; i++) {
        #pragma unroll
        for (int r = 0; r < 4; r++) {
            const int m = rbase + i * 16 + r;
            #pragma unroll
            for (int j = 0; j < NJ; j++) {
                const int n = cn + j * 16;
                float v = (acc[i][j][r] + bj[j]) * scale;
                if (ACT == 1) v = fmaxf(v, 0.f);
                else if (ACT == 2) { v = fmaxf(v, 0.f); v = v * v; }
                const long long ci = zc + (long long)m * ldc + n;
                if (OUT == 0)      Cf[ci] = v;
                else if (OUT == 1) Cf[ci] += v;
                else if (OUT == 2) Cb[ci] = f2bf(v);
                else               Cb[ci] = f2bf(bf2f(Cb[ci]) + v);
            }
        }
    }
}

// GLU-fused GEMM: X[m,n] (bf16) += (A·B1^T)[m,n] * sigmoid((A·B2^T)[m,n])
__global__ __launch_bounds__(256)
void glugemm_k(const u16* __restrict__ A, const u16* __restrict__ B1,
               const u16* __restrict__ B2, u16* __restrict__ X)
{
    constexpr int BM = 128, BN = 64, MI = 4, NJ = 2;
    __shared__ u16 As[BM * 64];
    __shared__ u16 B1s[BN * 64];
    __shared__ u16 B2s[BN * 64];

    const int id = blockIdx.x + gridDim.x * blockIdx.y;
    const int bx = (id >> 3) % gridDim.x;
    const int by = (id & 7) + 8 * ((id >> 3) / gridDim.x);
    const int m0 = by * BM;
    const int n0 = bx * BN;

    const int lane = threadIdx.x & 63;
    const int w    = threadIdx.x >> 6;
    const int wm   = (w >> 1) * 64;
    const int wn   = (w & 1) * 32;
    const int srow = lane >> 2;
    const int scol = (lane & 3) * 8;

    floatx4 acc1[MI][NJ], acc2[MI][NJ];
    #pragma unroll
    for (int i = 0; i < MI; i++)
        #pragma unroll
        for (int j = 0; j < NJ; j++) {
            acc1[i][j] = floatx4{0.f, 0.f, 0.f, 0.f};
            acc2[i][j] = floatx4{0.f, 0.f, 0.f, 0.f};
        }

    for (int k0 = 0; k0 < 1024; k0 += 64) {
        #pragma unroll
        for (int r = 0; r < 4; r++) {
            const int inst = w * 4 + r;
            const int rg = inst >> 1, kb = inst & 1;
            async_cp16(A + (long long)(m0 + rg * 16 + srow) * 1024 + k0 + kb * 32 + scol,
                       &As[(rg * 2 + kb) * 512]);
        }
        #pragma unroll
        for (int r = 0; r < 2; r++) {
            const int inst = w * 2 + r;
            const int rg = inst >> 1, kb = inst & 1;
            async_cp16(B1 + (long long)(n0 + rg * 16 + srow) * 1024 + k0 + kb * 32 + scol,
                       &B1s[(rg * 2 + kb) * 512]);
            async_cp16(B2 + (long long)(n0 + rg * 16 + srow) * 1024 + k0 + kb * 32 + scol,
                       &B2s[(rg * 2 + kb) * 512]);
        }
        __syncthreads();

        #pragma unroll
        for (int s = 0; s < 2; s++) {
            short8 a[MI], b1[NJ], b2[NJ];
            const int fr = lane & 15;
            const int q  = lane >> 4;
            const int go = (fr * 4 + q) * 8;
            #pragma unroll
            for (int i = 0; i < MI; i++)
                a[i] = *(const short8*)&As[(((wm >> 4) + i) * 2 + s) * 512 + go];
            #pragma unroll
            for (int j = 0; j < NJ; j++) {
                b1[j] = *(const short8*)&B1s[(((wn >> 4) + j) * 2 + s) * 512 + go];
                b2[j] = *(const short8*)&B2s[(((wn >> 4) + j) * 2 + s) * 512 + go];
            }
            #pragma unroll
            for (int i = 0; i < MI; i++)
                #pragma unroll
                for (int j = 0; j < NJ; j++) {
                    acc1[i][j] = __builtin_amdgcn_mfma_f32_16x16x32_bf16(
                        a[i], b1[j], acc1[i][j], 0, 0, 0);
                    acc2[i][j] = __builtin_amdgcn_mfma_f32_16x16x32_bf16(
                        a[i], b2[j], acc2[i][j], 0, 0, 0);
                }
        }
        __syncthreads();
    }

    const int cn    = n0 + wn + (lane & 15);
    const int rbase = m0 + wm + (lane >> 4) * 4;
    #pragma unroll
    for (int i = 0; i < MI; i++)
        #pragma unroll
        for (int r = 0; r < 4; r++) {
            const int m = rbase + i * 16 + r;
            #pragma unroll
            for (int j = 0; j < NJ; j++) {
                const int n = cn + j * 16;
                float g = acc1[i][j][r] / (1.f + __expf(-acc2[i][j][r]));
                u16* xp = &X[(long long)m * 1024 + n];
                *xp = f2bf(bf2f(*xp) + g);
            }
        }
}

// Shared MMA step (reads As/Bs/MI/NJ/wm/wn/lane from enclosing scope).
#define SGEMM_MMA_STEP                                                        \
    __syncthreads();                                                          \
    _Pragma("unroll")                                                         \
    for (int s = 0; s < 2; s++) {                                             \
        short8 a[MI], b[NJ];                                                  \
        const int fr = lane & 15;                                             \
        const int q  = lane >> 4;                                             \
        const int go = (fr * 4 + q) * 8;                                      \
        _Pragma("unroll")                                                     \
        for (int i = 0; i < MI; i++)                                          \
            a[i] = *(const short8*)&As[(((wm >> 4) + i) * 2 + s) * 512 + go]; \
        _Pragma("unroll")                                                     \
        for (int j = 0; j < NJ; j++)                                          \
            b[j] = *(const short8*)&Bs[(((wn >> 4) + j) * 2 + s) * 512 + go]; \
        _Pragma("unroll")                                                     \
        for (int i = 0; i < MI; i++)                                          \
            _Pragma("unroll")                                                 \
            for (int j = 0; j < NJ; j++)                                      \
                acc[i][j] = __builtin_amdgcn_mfma_f32_16x16x32_bf16(          \
                    a[i], b[j], acc[i][j], 0, 0, 0);                          \
    }                                                                         \
    __syncthreads();

// Merged c1L + c1R GEMMs (independent outputs; 1024 blocks = 4/CU).
// bid<512:  SBL[z][m][n] = relu(PW[m,:]·T2[z][n,:])   BM=128 BN=64 K=1024
// bid>=512: SBR[m][n]    = relu(T1[m,:]·RW[n,:])      BM=64  BN=64 K=1024
__global__ __launch_bounds__(256)
void c1lr_k(const u16* __restrict__ PW, const u16* __restrict__ T2,
            const u16* __restrict__ T1, const u16* __restrict__ RW,
            u16* __restrict__ SBL, u16* __restrict__ SBR)
{
    __shared__ u16 As[128 * 64];
    __shared__ u16 Bs[64 * 64];
    const int lane = threadIdx.x & 63;
    const int w    = threadIdx.x >> 6;
    const int srow = lane >> 2;
    const int scol = (lane & 3) * 8;

    if (blockIdx.x < 512) {
        constexpr int MI = 4, NJ = 2;
        const int z  = blockIdx.x >> 7;
        const int id = blockIdx.x & 127;
        const int bx = id >> 3, by = id & 7;
        const int m0 = by * 128, n0 = bx * 64;
        const u16* B = T2 + (long long)z * M1;
        const int wm = (w >> 1) * 64;
        const int wn = (w & 1) * 32;

        floatx4 acc[MI][NJ];
        #pragma unroll
        for (int i = 0; i < MI; i++)
            #pragma unroll
            for (int j = 0; j < NJ; j++)
                acc[i][j] = floatx4{0.f, 0.f, 0.f, 0.f};

        for (int k0 = 0; k0 < 1024; k0 += 64) {
            #pragma unroll
            for (int r = 0; r < 4; r++) {
                const int inst = w * 4 + r;
                const int rg = inst >> 1, kb = inst & 1;
                async_cp16(PW + (long long)(m0 + rg * 16 + srow) * 1024 + k0 + kb * 32 + scol,
                           &As[(rg * 2 + kb) * 512]);
            }
            #pragma unroll
            for (int r = 0; r < 2; r++) {
                const int inst = w * 2 + r;
                const int rg = inst >> 1, kb = inst & 1;
                async_cp16(B + (long long)(n0 + rg * 16 + srow) * 1024 + k0 + kb * 32 + scol,
                           &Bs[(rg * 2 + kb) * 512]);
            }
            SGEMM_MMA_STEP
        }

        const int cn    = n0 + wn + (lane & 15);
        const int rbase = m0 + wm + (lane >> 4) * 4;
        #pragma unroll
        for (int i = 0; i < MI; i++)
            #pragma unroll
            for (int r = 0; r < 4; r++) {
                const int m = rbase + i * 16 + r;
                #pragma unroll
                for (int j = 0; j < NJ; j++) {
                    const int n = cn + j * 16;
                    SBL[(long long)z * M1 + (long long)m * 1024 + n] =
                        f2bf(fmaxf(acc[i][j][r], 0.f));
                }
            }
    } else {
        constexpr int MI = 2, NJ = 2;
        const int id = blockIdx.x - 512;
        const int bx = (id >> 3) & 7;
        const int by = (id & 7) + 8 * (id >> 6);
        const int m0 = by * 64, n0 = bx * 64;
        const int wm = (w >> 1) * 32;
        const int wn = (w & 1) * 32;

        floatx4 acc[MI][NJ];
        #pragma unroll
        for (int i = 0; i < MI; i++)
            #pragma unroll
            for (int j = 0; j < NJ; j++)
                acc[i][j] = floatx4{0.f, 0.f, 0.f, 0.f};

        for (int k0 = 0; k0 < 1024; k0 += 64) {
            #pragma unroll
            for (int r = 0; r < 2; r++) {
                const int inst = w * 2 + r;
                const int rg = inst >> 1, kb = inst & 1;
                async_cp16(T1 + (long long)(m0 + rg * 16 + srow) * 1024 + k0 + kb * 32 + scol,
                           &As[(rg * 2 + kb) * 512]);
                async_cp16(RW + (long long)(n0 + rg * 16 + srow) * 1024 + k0 + kb * 32 + scol,
                           &Bs[(rg * 2 + kb) * 512]);
            }
            SGEMM_MMA_STEP
        }

        const int cn    = n0 + wn + (lane & 15);
        const int rbase = m0 + wm + (lane >> 4) * 4;
        #pragma unroll
        for (int i = 0; i < MI; i++)
            #pragma unroll
            for (int r = 0; r < 4; r++) {
                const int m = rbase + i * 16 + r;
                #pragma unroll
                for (int j = 0; j < NJ; j++) {
                    const int n = cn + j * 16;
                    SBR[(long long)m * 512 + n] = f2bf(fmaxf(acc[i][j][r], 0.f));
                }
            }
    }
}

// S GEMM + exp + rowsum, plane->XCD affinity (grid 1024 1-D).
// K-loop peeled into two compile-time halves (k<256: Q·K, k>=256: Er·Q).
__global__ __launch_bounds__(256)
void sgemm_exp_k(const u16* __restrict__ Qpk, const u16* __restrict__ Kpk,
                 const u16* __restrict__ ErT,
                 u16* __restrict__ S, float* __restrict__ rowsum, float scale)
{
    constexpr int MI = 4, NJ = 4;
    const int i0 = blockIdx.x;
    const int x  = i0 & 7;
    const int j0 = i0 >> 3;            // 0..127
    const int z  = x + 8 * (j0 & 1);   // plane
    const int t  = j0 >> 1;            // 0..63
    const int bx = t & 7, by = t >> 3;

    const u16* Aq = Qpk + (long long)z * 262144;
    const u16* Bk = Kpk + (long long)z * 262144;
    S += (long long)z * M1;
    rowsum += z << 10;

    __shared__ u16 As[128 * 64];
    __shared__ u16 Bs[128 * 64];

    const int m0 = by * 128;
    const int n0 = bx * 128;

    const int lane = threadIdx.x & 63;
    const int w    = threadIdx.x >> 6;
    const int wm   = (w >> 1) * 64;
    const int wn   = (w & 1) * 64;
    const int srow = lane >> 2;
    const int scol = (lane & 3) * 8;

    floatx4 acc[MI][NJ];
    #pragma unroll
    for (int i = 0; i < MI; i++)
        #pragma unroll
        for (int j = 0; j < NJ; j++)
            acc[i][j] = floatx4{0.f, 0.f, 0.f, 0.f};

    // half 1: k in [0,256) — A from Qpk, B from Kpk (compile-time sources)
    for (int k0 = 0; k0 < 256; k0 += 64) {
        #pragma unroll
        for (int r = 0; r < 4; r++) {
            const int inst = w * 4 + r;
            const int rg = inst >> 1, kb = inst & 1;
            const int cb = k0 + kb * 32;
            async_cp16(Aq + (long long)(m0 + rg * 16 + srow) * 256 + cb + scol,
                       &As[(rg * 2 + kb) * 512]);
            async_cp16(Bk + (long long)(n0 + rg * 16 + srow) * 256 + cb + scol,
                       &Bs[(rg * 2 + kb) * 512]);
        }
        SGEMM_MMA_STEP
    }
    // half 2: k in [256,512) — A from ErT (shared, L2-hot), B from Qpk
    for (int k0 = 0; k0 < 256; k0 += 64) {
        #pragma unroll
        for (int r = 0; r < 4; r++) {
            const int inst = w * 4 + r;
            const int rg = inst >> 1, kb = inst & 1;
            const int cb = k0 + kb * 32;
            async_cp16(ErT + (long long)(m0 + rg * 16 + srow) * 256 + cb + scol,
                       &As[(rg * 2 + kb) * 512]);
            async_cp16(Aq + (long long)(n0 + rg * 16 + srow) * 256 + cb + scol,
                       &Bs[(rg * 2 + kb) * 512]);
        }
        SGEMM_MMA_STEP
    }

    const int cn    = n0 + wn + (lane & 15);
    const int rbase = m0 + wm + (lane >> 4) * 4;
    #pragma unroll
    for (int i = 0; i < MI; i++)
        #pragma unroll
        for (int r = 0; r < 4; r++) {
            const int m = rbase + i * 16 + r;
            float part = 0.f;
            #pragma unroll
            for (int j = 0; j < NJ; j++) {
                const int n = cn + j * 16;
                float e = __expf(acc[i][j][r] * scale);
                S[(long long)m * 1024 + n] = f2bf(e);
                part += e;
            }
            #pragma unroll
            for (int off = 8; off; off >>= 1) part += __shfl_xor(part, off, 64);
            if ((lane & 15) == 0) atomicAdd(&rowsum[m], part);
        }
}

// AO GEMM + rowsum divide, plane->XCD affinity (grid 512 1-D),
// 128x64 tile (2 blocks/CU), writes AO in (B,T,F) layout directly.
__global__ __launch_bounds__(256)
void aogemm_k(const u16* __restrict__ Sb, const u16* __restrict__ Vt,
              const float* __restrict__ rowsum, u16* __restrict__ AO)
{
    constexpr int MI = 4, NJ = 2;
    const int i0 = blockIdx.x;
    const int x  = i0 & 7;
    const int j0 = i0 >> 3;            // 0..63
    const int z  = x + 8 * (j0 & 1);
    const int t  = j0 >> 1;            // 0..31
    const int bx = t & 3, by = t >> 2;

    Sb += (long long)z * M1;
    Vt += (long long)z * 262144;
    rowsum += z << 10;
    const long long zc = (long long)(z >> 2) * M1 + (z & 3) * 256;

    __shared__ u16 As[128 * 64];
    __shared__ u16 Bs[64 * 64];

    const int m0 = by * 128;
    const int n0 = bx * 64;

    const int lane = threadIdx.x & 63;
    const int w    = threadIdx.x >> 6;
    const int wm   = (w >> 1) * 64;
    const int wn   = (w & 1) * 32;
    const int srow = lane >> 2;
    const int scol = (lane & 3) * 8;

    floatx4 acc[MI][NJ];
    #pragma unroll
    for (int i = 0; i < MI; i++)
        #pragma unroll
        for (int j = 0; j < NJ; j++)
            acc[i][j] = floatx4{0.f, 0.f, 0.f, 0.f};

    for (int k0 = 0; k0 < 1024; k0 += 64) {
        #pragma unroll
        for (int r = 0; r < 4; r++) {
            const int inst = w * 4 + r;
            const int rg = inst >> 1, kb = inst & 1;
            async_cp16(Sb + (long long)(m0 + rg * 16 + srow) * 1024 + k0 + kb * 32 + scol,
                       &As[(rg * 2 + kb) * 512]);
        }
        #pragma unroll
        for (int r = 0; r < 2; r++) {
            const int inst = w * 2 + r;
            const int rg = inst >> 1, kb = inst & 1;
            async_cp16(Vt + (long long)(n0 + rg * 16 + srow) * 1024 + k0 + kb * 32 + scol,
                       &Bs[(rg * 2 + kb) * 512]);
        }
        SGEMM_MMA_STEP
    }

    const int cn    = n0 + wn + (lane & 15);
    const int rbase = m0 + wm + (lane >> 4) * 4;
    #pragma unroll
    for (int i = 0; i < MI; i++)
        #pragma unroll
        for (int r = 0; r < 4; r++) {
            const int m = rbase + i * 16 + r;
            const float inv = 1.f / rowsum[m];
            #pragma unroll
            for (int j = 0; j < NJ; j++) {
                const int n = cn + j * 16;
                AO[zc + (long long)m * 1024 + n] = f2bf(acc[i][j][r] * inv);
            }
        }
}

// ---------------------------------------------------------------------------
// LayerNorm: bf16 in -> bf16 out. One block per row.
__global__ __launch_bounds__(256)
void ln_bf_k(const u16* __restrict__ in, u16* __restrict__ out,
             const float* __restrict__ g, const float* __restrict__ b)
{
    long long row = blockIdx.x;
    int tid = threadIdx.x;
    ushort4 u = ((const ushort4*)(in + (row << 10)))[tid];
    float x0 = bf2f(u.x), x1 = bf2f(u.y), x2 = bf2f(u.z), x3 = bf2f(u.w);
    float s = x0 + x1 + x2 + x3;
    s = block_sum(s);
    float mean = s * (1.f / 1024.f);
    float dx = x0 - mean, dy = x1 - mean, dz = x2 - mean, dw = x3 - mean;
    float s2 = dx * dx + dy * dy + dz * dz + dw * dw;
    s2 = block_sum(s2);
    float inv = rsqrtf(s2 * (1.f / 1024.f) + 1e-5f);
    float4 gg = ((const float4*)g)[tid];
    float4 bb = ((const float4*)b)[tid];
    ushort4 o;
    o.x = f2bf(dx * inv * gg.x + bb.x);
    o.y = f2bf(dy * inv * gg.y + bb.y);
    o.z = f2bf(dz * inv * gg.z + bb.z);
    o.w = f2bf(dw * inv * gg.w + bb.w);
    ((ushort4*)(out + (row << 10)))[tid] = o;
}

// LayerNorm over (SBL + [SBR | 0]): SBR covers cols [0,512).
__global__ __launch_bounds__(256)
void ln_add_bf_k(const u16* __restrict__ inL, const u16* __restrict__ inR,
                 u16* __restrict__ out,
                 const float* __restrict__ g, const float* __restrict__ b)
{
    long long row = blockIdx.x;
    int tid = threadIdx.x;
    ushort4 u = ((const ushort4*)(inL + (row << 10)))[tid];
    float x0 = bf2f(u.x), x1 = bf2f(u.y), x2 = bf2f(u.z), x3 = bf2f(u.w);
    if (tid < 128) {
        ushort4 v = ((const ushort4*)(inR + (row << 9)))[tid];
        x0 += bf2f(v.x); x1 += bf2f(v.y); x2 += bf2f(v.z); x3 += bf2f(v.w);
    }
    float s = x0 + x1 + x2 + x3;
    s = block_sum(s);
    float mean = s * (1.f / 1024.f);
    float dx = x0 - mean, dy = x1 - mean, dz = x2 - mean, dw = x3 - mean;
    float s2 = dx * dx + dy * dy + dz * dz + dw * dw;
    s2 = block_sum(s2);
    float inv = rsqrtf(s2 * (1.f / 1024.f) + 1e-5f);
    float4 gg = ((const float4*)g)[tid];
    float4 bb = ((const float4*)b)[tid];
    ushort4 o;
    o.x = f2bf(dx * inv * gg.x + bb.x);
    o.y = f2bf(dy * inv * gg.y + bb.y);
    o.z = f2bf(dz * inv * gg.z + bb.z);
    o.w = f2bf(dw * inv * gg.w + bb.w);
    ((ushort4*)(out + (row << 10)))[tid] = o;
}

// ---------------------------------------------------------------------------
// Vectorized depthwise conv along t (k=7, pad 3), 8 f per thread.
// wtr: transposed weights [k][1024] f32. gidx in [0, 524288).
__device__ __forceinline__ void dconv7_vec8(
    const u16* __restrict__ in, u16* __restrict__ out,
    const float* __restrict__ wtr, int gidx)
{
    const int f8 = (gidx & 127) * 8;
    const int bt = gidx >> 7;
    const int t  = bt & 1023;
    const long long rowbase = (long long)(bt - t) * 1024;  // b*1024*1024
    float acc[8] = {0.f, 0.f, 0.f, 0.f, 0.f, 0.f, 0.f, 0.f};
    #pragma unroll
    for (int k = 0; k < 7; k++) {
        int tt = t + k - 3;
        if (tt >= 0 && tt < 1024) {
            short8 v = *(const short8*)&in[rowbase + (long long)tt * 1024 + f8];
            float4 wa = *(const float4*)&wtr[k * 1024 + f8];
            float4 wb = *(const float4*)&wtr[k * 1024 + f8 + 4];
            acc[0] += bf2f((u16)v[0]) * wa.x;
            acc[1] += bf2f((u16)v[1]) * wa.y;
            acc[2] += bf2f((u16)v[2]) * wa.z;
            acc[3] += bf2f((u16)v[3]) * wa.w;
            acc[4] += bf2f((u16)v[4]) * wb.x;
            acc[5] += bf2f((u16)v[5]) * wb.y;
            acc[6] += bf2f((u16)v[6]) * wb.z;
            acc[7] += bf2f((u16)v[7]) * wb.w;
        }
    }
    short8 o;
    #pragma unroll
    for (int i = 0; i < 8; i++) o[i] = (short)f2bf(acc[i]);
    *(short8*)&out[(long long)bt * 1024 + f8] = o;
}

// XCD chunk swizzle for 2048-block tap-windowed kernels: each XCD gets a
// contiguous t-slab so the 7-tap overlap is L2-local (2048 = 8 * 256).
__device__ __forceinline__ int xcd_chunk2048(int bid) {
    return (bid & 7) * 256 + (bid >> 3);
}

// ---------------------------------------------------------------------------
// Fused weight prep + input projection (independent front-of-graph work).
// blocks [0, 24576): castall (seg = bid>>11); blocks [24576, 28672): inproj.
struct CastArgs {
    const float* s[10];
    const float* er; const float* qb; const float* kb; const float* vb;
    const float* dwR; const float* dwM; const float* dwQ;   // k=7 dconv weights
    u16* ert; float* qkvb; float* wtr;                      // wtr: 3x[7][1024]
};
__global__ __launch_bounds__(256)
void castin_k(CastArgs a, u16* __restrict__ dst,
              const float* __restrict__ src, const float* __restrict__ inw,
              u16* __restrict__ X)
{
    const int bid = blockIdx.x;
    if (bid < 24576) {
        const int sz[10] = {2097152, 1048576, 524288, 1048576, 1048576,
                            1048576, 1048576, 1048576, 2097152, 2097152};
        int seg = bid >> 11;
        int tid = (bid & 2047) * 256 + threadIdx.x;
        if (seg < 10) {
            int n = sz[seg];
            int base = 0;
            for (int i = 0; i < seg; i++) base += sz[i];
            int i4 = tid * 4;
            if (i4 >= n) return;
            float4 v = *(const float4*)(a.s[seg] + i4);
            ushort4 o;
            o.x = f2bf(v.x); o.y = f2bf(v.y); o.z = f2bf(v.z); o.w = f2bf(v.w);
            *(ushort4*)(dst + base + i4) = o;
        } else if (seg == 10) {
            if (tid < 262144) {
                int j = tid >> 8, d = tid & 255;
                a.ert[tid] = f2bf(a.er[d * 1024 + j]);
            }
        } else {
            if (tid < 1024) a.qkvb[tid] = a.qb[tid];
            else if (tid < 2048) a.qkvb[tid] = a.kb[tid - 1024];
            else if (tid < 3072) a.qkvb[tid] = a.vb[tid - 2048];
            else if (tid < 3072 + 21504) {
                int i = tid - 3072;
                int tbl = i / 7168, r = i - tbl * 7168;
                int k = r >> 10, f = r & 1023;
                const float* s = (tbl == 0) ? a.dwR : (tbl == 1) ? a.dwM : a.dwQ;
                a.wtr[tbl * 7168 + k * 1024 + f] = s[f * 7 + k];
            }
        }
    } else {
        __shared__ float tile[32][33];
        int ib = bid - 24576;
        int f0 = (ib & 31) * 32, t0 = ((ib >> 5) & 31) * 32, b = ib >> 10;
        int tx = threadIdx.x & 31, ty = threadIdx.x >> 5;
        float w0 = inw[0], w1 = inw[1];
        for (int r = ty; r < 32; r += 8) {
            int f = f0 + r, t = t0 + tx;
            float s0 = src[(((long long)b * 2 + 0) * 1025 + f) * 1024 + t];
            float s1 = src[(((long long)b * 2 + 1) * 1025 + f) * 1024 + t];
            tile[r][tx] = w0 * s0 + w1 * s1;
        }
        __syncthreads();
        for (int r = ty; r < 32; r += 8)
            X[((long long)b * 1024 + t0 + r) * 1024 + f0 + tx] = f2bf(tile[tx][r]);
    }
}

// ---------------------------------------------------------------------------
// Fused dconvF (k=11, along f, transposed out, LDS tiles) + vectorized
// dconvT (k=7, along t, short8, XCD-chunked).
// blocks [0, 2048): dconvT -> outT; blocks [2048, 6144): dconvF -> outF.
__global__ __launch_bounds__(256)
void dconvFT_k(const u16* __restrict__ in, u16* __restrict__ outT,
               const float* __restrict__ wtrT, u16* __restrict__ outF,
               const float* __restrict__ wF)
{
    const int bid = blockIdx.x;
    if (bid < 2048) {
        dconv7_vec8(in, outT, wtrT, xcd_chunk2048(bid) * 256 + threadIdx.x);
    } else {
        __shared__ float itile[32][44];
        __shared__ float otile[32][33];
        int ib = bid - 2048;
        int f0 = (ib & 31) * 32, t0 = ((ib >> 5) & 31) * 32, b = ib >> 10;
        int tx = threadIdx.x & 31, ty = threadIdx.x >> 5;
        for (int r = ty; r < 32; r += 8)
            for (int c = tx; c < 42; c += 32) {
                int f = f0 - 5 + c;
                itile[r][c] = (f >= 0 && f < 1024)
                    ? bf2f(in[((long long)(b * 1024 + t0 + r)) * 1024 + f]) : 0.f;
            }
        __syncthreads();
        for (int r = ty; r < 32; r += 8) {
            const float* wr = wF + (t0 + r) * 11;
            float acc = 0.f;
            #pragma unroll
            for (int k = 0; k < 11; k++) acc += itile[r][tx + k] * wr[k];
            otile[tx][r] = acc;
        }
        __syncthreads();
        for (int r = ty; r < 32; r += 8)
            outF[((long long)(b * 1024 + f0 + r)) * 1024 + t0 + tx] = f2bf(otile[r][tx]);
    }
}

// Vectorized dconv along t (k=7 pad 3), bf16, XCD-chunked. grid 2048.
__global__ __launch_bounds__(256)
void dconvT_bf_k(const u16* __restrict__ in, u16* __restrict__ out,
                 const float* __restrict__ wtr)
{
    dconv7_vec8(in, out, wtr, xcd_chunk2048(blockIdx.x) * 256 + threadIdx.x);
}

// ---------------------------------------------------------------------------
// Fused QKV post-processing: vectorized q/k dconv+pack (short8, XCD-chunked),
// v dconv+transpose (LDS tiles), rowsum zero.
// blocks [0,2048): q/k pack; [2048,6144): vconv; [6144,6208): rowsum=0.
__global__ __launch_bounds__(256)
void qkvpack_k(const u16* __restrict__ T3, const float* __restrict__ w,
               const float* __restrict__ wtrQ, const float* __restrict__ bias,
               u16* __restrict__ Qpk, u16* __restrict__ Kpk,
               u16* __restrict__ Vt, float* __restrict__ rowsum)
{
    const int bid = blockIdx.x;
    if (bid < 2048) {
        const int gidx = xcd_chunk2048(bid) * 256 + threadIdx.x;   // 0..524287
        const int f8 = (gidx & 127) * 8;
        const int t  = (gidx >> 7) & 1023;
        const int b  = gidx >> 17;
        float4 b0 = *(const float4*)&bias[f8];
        float4 b1 = *(const float4*)&bias[f8 + 4];
        float aq[8] = {b0.x, b0.y, b0.z, b0.w, b1.x, b1.y, b1.z, b1.w};
        float ak[8] = {b0.x, b0.y, b0.z, b0.w, b1.x, b1.y, b1.z, b1.w};
        #pragma unroll
        for (int k = 0; k < 7; k++) {
            int tt = t + k - 3;
            if (tt >= 0 && tt < 1024) {
                const u16* row = T3 + ((long long)((b << 10) + tt)) * 3072 + f8;
                short8 vq = *(const short8*)&row[0];
                short8 vk = *(const short8*)&row[1024];
                float4 wa = *(const float4*)&wtrQ[k * 1024 + f8];
                float4 wb = *(const float4*)&wtrQ[k * 1024 + f8 + 4];
                aq[0] += bf2f((u16)vq[0]) * wa.x;  ak[0] += bf2f((u16)vk[0]) * wa.x;
                aq[1] += bf2f((u16)vq[1]) * wa.y;  ak[1] += bf2f((u16)vk[1]) * wa.y;
                aq[2] += bf2f((u16)vq[2]) * wa.z;  ak[2] += bf2f((u16)vk[2]) * wa.z;
                aq[3] += bf2f((u16)vq[3]) * wa.w;  ak[3] += bf2f((u16)vk[3]) * wa.w;
                aq[4] += bf2f((u16)vq[4]) * wb.x;  ak[4] += bf2f((u16)vk[4]) * wb.x;
                aq[5] += bf2f((u16)vq[5]) * wb.y;  ak[5] += bf2f((u16)vk[5]) * wb.y;
                aq[6] += bf2f((u16)vq[6]) * wb.z;  ak[6] += bf2f((u16)vk[6]) * wb.z;
                aq[7] += bf2f((u16)vq[7]) * wb.w;  ak[7] += bf2f((u16)vk[7]) * wb.w;
            }
        }
        const int band = f8 >> 8, d = f8 & 255, z = (b << 2) | band;
        const long long base = (long long)z * 262144 + t * 256 + d;
        short8 oq, ok;
        #pragma unroll
        for (int i = 0; i < 8; i++) {
            oq[i] = (short)f2bf(aq[i]);
            ok[i] = (short)f2bf(ak[i]);
        }
        *(short8*)&Qpk[base] = oq;
        *(short8*)&Kpk[base] = ok;
    } else if (bid < 6144) {
        __shared__ float itile[38][32];
        __shared__ float otile[32][33];
        int vb = bid - 2048;
        int f0 = (vb & 31) * 32, t0 = ((vb >> 5) & 31) * 32, b = vb >> 10;
        int tx = threadIdx.x & 31, ty = threadIdx.x >> 5;
        for (int i = threadIdx.x; i < 38 * 32; i += 256) {
            int r = i >> 5, c = i & 31;
            int t = t0 - 3 + r;
            itile[r][c] = (t >= 0 && t < 1024)
                ? bf2f(T3[((long long)(b * 1024 + t)) * 3072 + 2048 + f0 + c]) : 0.f;
        }
        __syncthreads();
        for (int r = ty; r < 32; r += 8) {
            const float* wr = w + (f0 + tx) * 7;
            float acc = bias[f0 + tx];
            #pragma unroll
            for (int k = 0; k < 7; k++) acc += itile[r + k][tx] * wr[k];
            otile[tx][r] = acc;
        }
        __syncthreads();
        for (int r = ty; r < 32; r += 8)
            Vt[((long long)(b * 1024 + f0 + r)) * 1024 + t0 + tx] = f2bf(otile[r][tx]);
    } else {
        int i = (bid - 6144) * 256 + threadIdx.x;  // 16384 floats
        rowsum[i] = 0.f;
    }
}

// Output head: reads bf16 X.
__global__ __launch_bounds__(256)
void out_k(const float* __restrict__ src, const u16* __restrict__ X,
           const float* __restrict__ ow, float* __restrict__ out)
{
    __shared__ float tile[32][33];
    int b = blockIdx.z;
    int f0 = blockIdx.y * 32, t0 = blockIdx.x * 32;
    for (int r = threadIdx.y; r < 32; r += 8)
        tile[r][threadIdx.x] = bf2f(X[((long long)b * 1024 + t0 + r) * 1024 + f0 + threadIdx.x]);
    __syncthreads();
    float w00 = ow[0], w01 = ow[1], w02 = ow[2];
    float w10 = ow[3], w11 = ow[4], w12 = ow[5];
    for (int r = threadIdx.y; r < 32; r += 8) {
        int f = f0 + r, t = t0 + threadIdx.x;
        float s0 = src[(((long long)b * 2 + 0) * 1025 + f) * 1024 + t];
        float s1 = src[(((long long)b * 2 + 1) * 1025 + f) * 1024 + t];
        float xv = tile[threadIdx.x][r];
        float v0 = fminf(fmaxf(w00 * s0 + w01 * s1 + w02 * xv, 0.f), 6.f) * (1.f / 6.f);
        float v1 = fminf(fmaxf(w10 * s0 + w11 * s1 + w12 * xv, 0.f), 6.f) * (1.f / 6.f);
        out[(((long long)b * 2 + 0) * 1025 + f) * 1024 + t] = v0;
        out[(((long long)b * 2 + 1) * 1025 + f) * 1024 + t] = v1;
        if (f == 1023) {
            out[(((long long)b * 2 + 0) * 1025 + 1024) * 1024 + t] = v0;
            out[(((long long)b * 2 + 1) * 1025 + 1024) * 1024 + t] = v1;
        }
    }
}

// ---------------------------------------------------------------------------
extern "C" void kernel_launch(void* const* d_in, const int* in_sizes, int n_in,
                              void* d_out, int out_size, void* d_ws, size_t ws_size,
                              hipStream_t stream)
{
    const float* src    = (const float*)d_in[0];
    const float* in_w   = (const float*)d_in[1];
    const float* ln1_g  = (const float*)d_in[2];
    const float* ln1_b  = (const float*)d_in[3];
    const float* glu_w  = (const float*)d_in[4];
    const float* ln2_g  = (const float*)d_in[5];
    const float* ln2_b  = (const float*)d_in[6];
    const float* c1L_dw = (const float*)d_in[7];
    const float* c1L_pw = (const float*)d_in[8];
    const float* c1R_dw = (const float*)d_in[9];
    const float* c1R_pw = (const float*)d_in[10];
    const float* ln3_g  = (const float*)d_in[11];
    const float* ln3_b  = (const float*)d_in[12];
    const float* c1M_dw = (const float*)d_in[13];
    const float* c1M_pw = (const float*)d_in[14];
    const float* ln4_g  = (const float*)d_in[15];
    const float* ln4_b  = (const float*)d_in[16];
    const float* q_w    = (const float*)d_in[17];
    const float* q_b    = (const float*)d_in[18];
    const float* qc_w   = (const float*)d_in[19];
    const float* qc_b   = (const float*)d_in[20];
    const float* k_w    = (const float*)d_in[21];
    const float* k_b    = (const float*)d_in[22];
    const float* v_w    = (const float*)d_in[23];
    const float* v_b    = (const float*)d_in[24];
    const float* o_w    = (const float*)d_in[25];
    const float* o_b    = (const float*)d_in[26];
    const float* er     = (const float*)d_in[27];
    const float* ln5_g  = (const float*)d_in[28];
    const float* ln5_b  = (const float*)d_in[29];
    const float* c2_w   = (const float*)d_in[30];
    const float* c3_w   = (const float*)d_in[31];
    const float* out_w  = (const float*)d_in[32];
    float* out = (float*)d_out;

    const size_t MB = 1ull << 20;
    if (ws_size < 162 * MB) return;
    char* wsb = (char*)d_ws;
    u16* X       = (u16*)(wsb + 0);           // 8 MB bf16 residual
    u16* SB      = (u16*)(wsb + 8 * MB);      // 8 MB bf16 hL (SBL)
    float* rowsum= (float*)(wsb + 16 * MB);   // 64 KB (free window, no alias)
    u16* SBR     = (u16*)(wsb + 24 * MB);     // 4 MB bf16 hR (4096x512)
    u16* Qpk     = (u16*)(wsb + 32 * MB);     // 8 MB q-pack (z,t,256)
    u16* Kpk     = (u16*)(wsb + 40 * MB);     // 8 MB k-pack (z,t,256)
    u16* Hbf     = (u16*)(wsb + 64 * MB);     // 8 MB ln outputs
    u16* T1bf    = (u16*)(wsb + 72 * MB);     // 8 MB dconv temps
    u16* T3      = (u16*)(wsb + 72 * MB);     // 24 MB QKV (4096x3072)
    u16* AO      = (u16*)(wsb + 80 * MB);     // 8 MB AO (B,T,F)
    u16* T2bf    = (u16*)(wsb + 96 * MB);     // 8 MB dconvF out (c1L)
    u16* Vt      = (u16*)(wsb + 96 * MB);     // reuse: 8 MB V^T (b,f,t)
    u16* Sbf     = (u16*)(wsb + 104 * MB);    // 32 MB scores (16,1024,1024)
    u16* Gbf     = (u16*)(wsb + 104 * MB);    // reuse: 16 MB ffn mid
    u16* W0      = (u16*)(wsb + 136 * MB);    // bf16 weights

    u16* glu_wb  = W0;
    u16* c1L_pwb = W0 + 2097152;
    u16* c1R_pwb = W0 + 3145728;
    u16* c1M_pwb = W0 + 3670016;
    u16* qkv_wb  = W0 + 4718592;   // q,k,v contiguous (3072 x 1024)
    u16* o_wb    = W0 + 7864320;
    u16* c2_wb   = W0 + 8912896;
    u16* c3_wb   = W0 + 11010048;
    u16* ertb    = W0 + 13107200;  // 262144 (t-major er transpose, shared)
    float* qkvb  = (float*)(W0 + 13369344);  // 3072 fp32
    float* wtrb  = qkvb + 3072;    // 3 x 7168 fp32 transposed dconv weights
    float* wtrR  = wtrb;           // c1R_dw  [7][1024]
    float* wtrM  = wtrb + 7168;    // c1M_dw  [7][1024]
    float* wtrQ  = wtrb + 14336;   // qc_w    [7][1024]

    const dim3 blk256(256);
    const dim3 tgrid(32, 32, NB);
    const dim3 tblk(32, 8);

    // --- 1. weight prep + input projection (fused, independent work) ---
    CastArgs ca;
    ca.s[0] = glu_w;  ca.s[1] = c1L_pw; ca.s[2] = c1R_pw; ca.s[3] = c1M_pw;
    ca.s[4] = q_w;    ca.s[5] = k_w;    ca.s[6] = v_w;    ca.s[7] = o_w;
    ca.s[8] = c2_w;   ca.s[9] = c3_w;
    ca.er = er; ca.qb = q_b; ca.kb = k_b; ca.vb = v_b;
    ca.dwR = c1R_dw; ca.dwM = c1M_dw; ca.dwQ = qc_w;
    ca.ert = ertb; ca.qkvb = qkvb; ca.wtr = wtrb;
    castin_k<<<28672, blk256, 0, stream>>>(ca, W0, src, in_w, X);

    // 2-4. h = ln1(x); x += glu(h @ glu_w^T)  [fused]
    ln_bf_k<<<4096, blk256, 0, stream>>>(X, Hbf, ln1_g, ln1_b);
    glugemm_k<<<dim3(16, 32, 1), blk256, 0, stream>>>(
        Hbf, glu_wb, glu_wb + 1048576, X);
    // 5. h = ln2(x)
    ln_bf_k<<<4096, blk256, 0, stream>>>(X, Hbf, ln2_g, ln2_b);
    // 6. both depthwise convs of h (fused; dconvT vectorized + XCD-chunked)
    dconvFT_k<<<6144, blk256, 0, stream>>>(Hbf, T1bf, wtrR, T2bf, c1L_dw);
    // 7. merged c1L+c1R -> SBL, SBR (independent, 1024 blocks = 4/CU)
    c1lr_k<<<1024, blk256, 0, stream>>>(c1L_pwb, T2bf, T1bf, c1R_pwb, SB, SBR);
    // 8. h = ln3(SBL + [SBR|0])
    ln_add_bf_k<<<4096, blk256, 0, stream>>>(SB, SBR, Hbf, ln3_g, ln3_b);
    // 9-10. x += dconvT(h) @ c1M_pw^T  [128x64, 2 blk/CU]
    dconvT_bf_k<<<2048, blk256, 0, stream>>>(Hbf, T1bf, wtrM);
    gemm_bf<128, 64, 0, 3><<<dim3(16, 32, 1), blk256, 0, stream>>>(
        T1bf, c1M_pwb, X, 1024, 1024, 1024, 1024, 0, 0, 0, nullptr, 1.f);
    // 11. h = ln4(x)
    ln_bf_k<<<4096, blk256, 0, stream>>>(X, Hbf, ln4_g, ln4_b);
    // 12. fused QKV GEMM (4096x3072x1024) -> T3 bf16  [128x128, 3 blk/CU]
    gemm_bf<128, 128, 0, 2><<<dim3(24, 32, 1), blk256, 0, stream>>>(
        Hbf, qkv_wb, T3, 1024, 1024, 1024, 3072, 0, 0, 0, qkvb, 1.f);
    // 13. qc convs: q/k pack (XCD-chunked) + V transpose + rowsum zero
    qkvpack_k<<<6208, blk256, 0, stream>>>(T3, qc_w, wtrQ, qc_b, Qpk, Kpk, Vt, rowsum);
    // 14. S = exp((QK^T + rel-pos)/32) + rowsum; plane->XCD affinity
    sgemm_exp_k<<<1024, blk256, 0, stream>>>(Qpk, Kpk, ertb, Sbf, rowsum, 0.03125f);
    // 15. AO = (S @ V) / rowsum; plane->XCD affinity; [128x64, 2 blk/CU]
    aogemm_k<<<512, blk256, 0, stream>>>(Sbf, Vt, rowsum, AO);
    // 16. x += AO @ o_w^T + o_b  [128x64, 2 blk/CU]
    gemm_bf<128, 64, 0, 3><<<dim3(16, 32, 1), blk256, 0, stream>>>(
        AO, o_wb, X, 1024, 1024, 1024, 1024, 0, 0, 0, o_b, 1.f);
    // 17-18. h = ln5(x); mid = relu(h @ c2_w^T)^2  [128x128, 2 blk/CU]
    ln_bf_k<<<4096, blk256, 0, stream>>>(X, Hbf, ln5_g, ln5_b);
    gemm_bf<128, 128, 2, 2><<<dim3(16, 32, 1), blk256, 0, stream>>>(
        Hbf, c2_wb, Gbf, 1024, 1024, 1024, 2048, 0, 0, 0, nullptr, 1.f);
    // 19. x += mid @ c3_w^T  [128x64, 2 blk/CU]
    gemm_bf<128, 64, 0, 3><<<dim3(16, 32, 1), blk256, 0, stream>>>(
        Gbf, c3_wb, X, 2048, 2048, 2048, 1024, 0, 0, 0, nullptr, 1.f);
    // 20. output head
    out_k<<<tgrid, tblk, 0, stream>>>(src, X, out_w, out);
}

// Round 8
// 489.817 us; speedup vs baseline: 1.2034x; 1.0290x over previous
//
#include <hip/hip_runtime.h>
#include <math.h>

// ---------------------------------------------------------------------------
// FrameTransformer — R15: BK=128 (halved barrier pairs) on grid-limited
// 128x64 GEMMs; R14 swizzle REVERTED (re-derivation: each ds_read_b128 reads
// its 1KB block exhaustively -> any bijective permutation is bank-neutral;
// the 2.1M conflict counter is intrinsic 1KB/instr serialization).
// BK=128 applied ONLY where occupancy can't drop: c1M/o/c3 + aogemm
// (LDS 24->48KB, grid 512 = 2 blk/CU <= 3 LDS-cap). QKV/c2/sgemm/glu/c1lr
// keep BK=64 (would lose blocks/CU — m132 failure mode).
// R13 merge/swizzles + R12 short8 dconvs + R11 geometry + R10/R9 kept.
// ---------------------------------------------------------------------------

typedef unsigned short u16;
typedef __attribute__((ext_vector_type(4))) float floatx4;
typedef __attribute__((ext_vector_type(8))) short short8;

#define NB 4
static const long long M1 = 1024LL * 1024LL;

__device__ __forceinline__ float bf2f(u16 h) {
    union { unsigned int u; float f; } v;
    v.u = ((unsigned int)h) << 16;
    return v.f;
}
__device__ __forceinline__ u16 f2bf(float x) {
    union { float f; unsigned int u; } v;
    v.f = x;
    unsigned int r = (v.u + 0x7FFFu + ((v.u >> 16) & 1u)) >> 16;
    return (u16)r;
}

__device__ __forceinline__ void async_cp16(const u16* g, u16* lds) {
    __builtin_amdgcn_global_load_lds(
        (const __attribute__((address_space(1))) unsigned int*)g,
        (__attribute__((address_space(3))) unsigned int*)lds, 16, 0, 0);
}

__device__ __forceinline__ float block_sum(float v) {
    __shared__ float sd[4];
    #pragma unroll
    for (int off = 32; off; off >>= 1) v += __shfl_down(v, off, 64);
    int lane = threadIdx.x & 63, wid = threadIdx.x >> 6;
    __syncthreads();
    if (lane == 0) sd[wid] = v;
    __syncthreads();
    return sd[0] + sd[1] + sd[2] + sd[3];
}

// ---------------------------------------------------------------------------
// bf16 NT GEMM: C[M,N] (op)= act( scale*(A·B^T + bias) )
// OUT: 0 = f32 store, 1 = f32 accum, 2 = bf16 store, 3 = bf16 accum.
// BK: K-elements staged per barrier pair (64 or 128).
// ---------------------------------------------------------------------------
template<int BM, int BN, int BK, int ACT, int OUT>
__global__ __launch_bounds__(256)
void gemm_bf(const u16* __restrict__ A, const u16* __restrict__ B,
             void* __restrict__ Cv, int K, int lda, int ldb, int ldc,
             long long sAz, long long sBz, long long sCz,
             const float* __restrict__ bias, float scale)
{
    constexpr int MI = BM / 32;
    constexpr int NJ = BN / 32;
    constexpr int KB = BK / 32;               // 32-col sub-blocks per K-step
    constexpr int AST = (BM / 16) * KB / 4;   // A staging instrs per wave
    constexpr int BST = (BN / 16) * KB / 4;   // B staging instrs per wave

    A += (long long)blockIdx.z * sAz;
    B += (long long)blockIdx.z * sBz;
    const long long zc = (long long)blockIdx.z * sCz;

    __shared__ u16 As[BM * BK];
    __shared__ u16 Bs[BN * BK];

    const int id = blockIdx.x + gridDim.x * blockIdx.y;
    const int bx = (id >> 3) % gridDim.x;
    const int by = (id & 7) + 8 * ((id >> 3) / gridDim.x);
    const int m0 = by * BM;
    const int n0 = bx * BN;

    const int lane = threadIdx.x & 63;
    const int w    = threadIdx.x >> 6;
    const int wm   = (w >> 1) * (BM / 2);
    const int wn   = (w & 1) * (BN / 2);
    const int srow = lane >> 2;
    const int scol = (lane & 3) * 8;

    floatx4 acc[MI][NJ];
    #pragma unroll
    for (int i = 0; i < MI; i++)
        #pragma unroll
        for (int j = 0; j < NJ; j++)
            acc[i][j] = floatx4{0.f, 0.f, 0.f, 0.f};

    for (int k0 = 0; k0 < K; k0 += BK) {
        #pragma unroll
        for (int r = 0; r < AST; r++) {
            const int inst = w * AST + r;
            const int rg = inst / KB, kb = inst % KB;
            async_cp16(A + (long long)(m0 + rg * 16 + srow) * lda + k0 + kb * 32 + scol,
                       &As[(rg * KB + kb) * 512]);
        }
        #pragma unroll
        for (int r = 0; r < BST; r++) {
            const int inst = w * BST + r;
            const int rg = inst / KB, kb = inst % KB;
            async_cp16(B + (long long)(n0 + rg * 16 + srow) * ldb + k0 + kb * 32 + scol,
                       &Bs[(rg * KB + kb) * 512]);
        }
        __syncthreads();

        #pragma unroll
        for (int s = 0; s < KB; s++) {
            short8 a[MI], b[NJ];
            const int fr = lane & 15;
            const int q  = lane >> 4;
            const int go = (fr * 4 + q) * 8;
            #pragma unroll
            for (int i = 0; i < MI; i++)
                a[i] = *(const short8*)&As[(((wm >> 4) + i) * KB + s) * 512 + go];
            #pragma unroll
            for (int j = 0; j < NJ; j++)
                b[j] = *(const short8*)&Bs[(((wn >> 4) + j) * KB + s) * 512 + go];
            #pragma unroll
            for (int i = 0; i < MI; i++)
                #pragma unroll
                for (int j = 0; j < NJ; j++)
                    acc[i][j] = __builtin_amdgcn_mfma_f32_16x16x32_bf16(
                        a[i], b[j], acc[i][j], 0, 0, 0);
        }
        __syncthreads();
    }

    float* Cf = (float*)Cv;
    u16*  Cb  = (u16*)Cv;
    const int cn    = n0 + wn + (lane & 15);
    const int rbase = m0 + wm + (lane >> 4) * 4;
    float bj[NJ];
    #pragma unroll
    for (int j = 0; j < NJ; j++) bj[j] = bias ? bias[cn + j * 16] : 0.f;

    #pragma unroll
    for (int i = 0; i < MI; i++) {
        #pragma unroll
        for (int r = 0; r < 4; r++) {
            const int m = rbase + i * 16 + r;
            #pragma unroll
            for (int j = 0; j < NJ; j++) {
                const int n = cn + j * 16;
                float v = (acc[i][j][r] + bj[j]) * scale;
                if (ACT == 1) v = fmaxf(v, 0.f);
                else if (ACT == 2) { v = fmaxf(v, 0.f); v = v * v; }
                const long long ci = zc + (long long)m * ldc + n;
                if (OUT == 0)      Cf[ci] = v;
                else if (OUT == 1) Cf[ci] += v;
                else if (OUT == 2) Cb[ci] = f2bf(v);
                else               Cb[ci] = f2bf(bf2f(Cb[ci]) + v);
            }
        }
    }
}

// GLU-fused GEMM: X[m,n] (bf16) += (A·B1^T)[m,n] * sigmoid((A·B2^T)[m,n])
__global__ __launch_bounds__(256)
void glugemm_k(const u16* __restrict__ A, const u16* __restrict__ B1,
               const u16* __restrict__ B2, u16* __restrict__ X)
{
    constexpr int BM = 128, BN = 64, MI = 4, NJ = 2;
    __shared__ u16 As[BM * 64];
    __shared__ u16 B1s[BN * 64];
    __shared__ u16 B2s[BN * 64];

    const int id = blockIdx.x + gridDim.x * blockIdx.y;
    const int bx = (id >> 3) % gridDim.x;
    const int by = (id & 7) + 8 * ((id >> 3) / gridDim.x);
    const int m0 = by * BM;
    const int n0 = bx * BN;

    const int lane = threadIdx.x & 63;
    const int w    = threadIdx.x >> 6;
    const int wm   = (w >> 1) * 64;
    const int wn   = (w & 1) * 32;
    const int srow = lane >> 2;
    const int scol = (lane & 3) * 8;

    floatx4 acc1[MI][NJ], acc2[MI][NJ];
    #pragma unroll
    for (int i = 0; i < MI; i++)
        #pragma unroll
        for (int j = 0; j < NJ; j++) {
            acc1[i][j] = floatx4{0.f, 0.f, 0.f, 0.f};
            acc2[i][j] = floatx4{0.f, 0.f, 0.f, 0.f};
        }

    for (int k0 = 0; k0 < 1024; k0 += 64) {
        #pragma unroll
        for (int r = 0; r < 4; r++) {
            const int inst = w * 4 + r;
            const int rg = inst >> 1, kb = inst & 1;
            async_cp16(A + (long long)(m0 + rg * 16 + srow) * 1024 + k0 + kb * 32 + scol,
                       &As[(rg * 2 + kb) * 512]);
        }
        #pragma unroll
        for (int r = 0; r < 2; r++) {
            const int inst = w * 2 + r;
            const int rg = inst >> 1, kb = inst & 1;
            async_cp16(B1 + (long long)(n0 + rg * 16 + srow) * 1024 + k0 + kb * 32 + scol,
                       &B1s[(rg * 2 + kb) * 512]);
            async_cp16(B2 + (long long)(n0 + rg * 16 + srow) * 1024 + k0 + kb * 32 + scol,
                       &B2s[(rg * 2 + kb) * 512]);
        }
        __syncthreads();

        #pragma unroll
        for (int s = 0; s < 2; s++) {
            short8 a[MI], b1[NJ], b2[NJ];
            const int fr = lane & 15;
            const int q  = lane >> 4;
            const int go = (fr * 4 + q) * 8;
            #pragma unroll
            for (int i = 0; i < MI; i++)
                a[i] = *(const short8*)&As[(((wm >> 4) + i) * 2 + s) * 512 + go];
            #pragma unroll
            for (int j = 0; j < NJ; j++) {
                b1[j] = *(const short8*)&B1s[(((wn >> 4) + j) * 2 + s) * 512 + go];
                b2[j] = *(const short8*)&B2s[(((wn >> 4) + j) * 2 + s) * 512 + go];
            }
            #pragma unroll
            for (int i = 0; i < MI; i++)
                #pragma unroll
                for (int j = 0; j < NJ; j++) {
                    acc1[i][j] = __builtin_amdgcn_mfma_f32_16x16x32_bf16(
                        a[i], b1[j], acc1[i][j], 0, 0, 0);
                    acc2[i][j] = __builtin_amdgcn_mfma_f32_16x16x32_bf16(
                        a[i], b2[j], acc2[i][j], 0, 0, 0);
                }
        }
        __syncthreads();
    }

    const int cn    = n0 + wn + (lane & 15);
    const int rbase = m0 + wm + (lane >> 4) * 4;
    #pragma unroll
    for (int i = 0; i < MI; i++)
        #pragma unroll
        for (int r = 0; r < 4; r++) {
            const int m = rbase + i * 16 + r;
            #pragma unroll
            for (int j = 0; j < NJ; j++) {
                const int n = cn + j * 16;
                float g = acc1[i][j][r] / (1.f + __expf(-acc2[i][j][r]));
                u16* xp = &X[(long long)m * 1024 + n];
                *xp = f2bf(bf2f(*xp) + g);
            }
        }
}

// Shared MMA step; KB = 32-col sub-blocks per K-step.
#define SGEMM_MMA_STEP(KB)                                                    \
    __syncthreads();                                                          \
    _Pragma("unroll")                                                         \
    for (int s = 0; s < (KB); s++) {                                          \
        short8 a[MI], b[NJ];                                                  \
        const int fr = lane & 15;                                             \
        const int q  = lane >> 4;                                             \
        const int go = (fr * 4 + q) * 8;                                      \
        _Pragma("unroll")                                                     \
        for (int i = 0; i < MI; i++)                                          \
            a[i] = *(const short8*)&As[(((wm >> 4) + i) * (KB) + s) * 512 + go]; \
        _Pragma("unroll")                                                     \
        for (int j = 0; j < NJ; j++)                                          \
            b[j] = *(const short8*)&Bs[(((wn >> 4) + j) * (KB) + s) * 512 + go]; \
        _Pragma("unroll")                                                     \
        for (int i = 0; i < MI; i++)                                          \
            _Pragma("unroll")                                                 \
            for (int j = 0; j < NJ; j++)                                      \
                acc[i][j] = __builtin_amdgcn_mfma_f32_16x16x32_bf16(          \
                    a[i], b[j], acc[i][j], 0, 0, 0);                          \
    }                                                                         \
    __syncthreads();

// Merged c1L + c1R GEMMs (independent outputs; 1024 blocks = 4/CU, BK=64).
__global__ __launch_bounds__(256)
void c1lr_k(const u16* __restrict__ PW, const u16* __restrict__ T2,
            const u16* __restrict__ T1, const u16* __restrict__ RW,
            u16* __restrict__ SBL, u16* __restrict__ SBR)
{
    __shared__ u16 As[128 * 64];
    __shared__ u16 Bs[64 * 64];
    const int lane = threadIdx.x & 63;
    const int w    = threadIdx.x >> 6;
    const int srow = lane >> 2;
    const int scol = (lane & 3) * 8;

    if (blockIdx.x < 512) {
        constexpr int MI = 4, NJ = 2;
        const int z  = blockIdx.x >> 7;
        const int id = blockIdx.x & 127;
        const int bx = id >> 3, by = id & 7;
        const int m0 = by * 128, n0 = bx * 64;
        const u16* B = T2 + (long long)z * M1;
        const int wm = (w >> 1) * 64;
        const int wn = (w & 1) * 32;

        floatx4 acc[MI][NJ];
        #pragma unroll
        for (int i = 0; i < MI; i++)
            #pragma unroll
            for (int j = 0; j < NJ; j++)
                acc[i][j] = floatx4{0.f, 0.f, 0.f, 0.f};

        for (int k0 = 0; k0 < 1024; k0 += 64) {
            #pragma unroll
            for (int r = 0; r < 4; r++) {
                const int inst = w * 4 + r;
                const int rg = inst >> 1, kb = inst & 1;
                async_cp16(PW + (long long)(m0 + rg * 16 + srow) * 1024 + k0 + kb * 32 + scol,
                           &As[(rg * 2 + kb) * 512]);
            }
            #pragma unroll
            for (int r = 0; r < 2; r++) {
                const int inst = w * 2 + r;
                const int rg = inst >> 1, kb = inst & 1;
                async_cp16(B + (long long)(n0 + rg * 16 + srow) * 1024 + k0 + kb * 32 + scol,
                           &Bs[(rg * 2 + kb) * 512]);
            }
            SGEMM_MMA_STEP(2)
        }

        const int cn    = n0 + wn + (lane & 15);
        const int rbase = m0 + wm + (lane >> 4) * 4;
        #pragma unroll
        for (int i = 0; i < MI; i++)
            #pragma unroll
            for (int r = 0; r < 4; r++) {
                const int m = rbase + i * 16 + r;
                #pragma unroll
                for (int j = 0; j < NJ; j++) {
                    const int n = cn + j * 16;
                    SBL[(long long)z * M1 + (long long)m * 1024 + n] =
                        f2bf(fmaxf(acc[i][j][r], 0.f));
                }
            }
    } else {
        constexpr int MI = 2, NJ = 2;
        const int id = blockIdx.x - 512;
        const int bx = (id >> 3) & 7;
        const int by = (id & 7) + 8 * (id >> 6);
        const int m0 = by * 64, n0 = bx * 64;
        const int wm = (w >> 1) * 32;
        const int wn = (w & 1) * 32;

        floatx4 acc[MI][NJ];
        #pragma unroll
        for (int i = 0; i < MI; i++)
            #pragma unroll
            for (int j = 0; j < NJ; j++)
                acc[i][j] = floatx4{0.f, 0.f, 0.f, 0.f};

        for (int k0 = 0; k0 < 1024; k0 += 64) {
            #pragma unroll
            for (int r = 0; r < 2; r++) {
                const int inst = w * 2 + r;
                const int rg = inst >> 1, kb = inst & 1;
                async_cp16(T1 + (long long)(m0 + rg * 16 + srow) * 1024 + k0 + kb * 32 + scol,
                           &As[(rg * 2 + kb) * 512]);
                async_cp16(RW + (long long)(n0 + rg * 16 + srow) * 1024 + k0 + kb * 32 + scol,
                           &Bs[(rg * 2 + kb) * 512]);
            }
            SGEMM_MMA_STEP(2)
        }

        const int cn    = n0 + wn + (lane & 15);
        const int rbase = m0 + wm + (lane >> 4) * 4;
        #pragma unroll
        for (int i = 0; i < MI; i++)
            #pragma unroll
            for (int r = 0; r < 4; r++) {
                const int m = rbase + i * 16 + r;
                #pragma unroll
                for (int j = 0; j < NJ; j++) {
                    const int n = cn + j * 16;
                    SBR[(long long)m * 512 + n] = f2bf(fmaxf(acc[i][j][r], 0.f));
                }
            }
    }
}

// S GEMM + exp + rowsum, plane->XCD affinity (grid 1024 1-D, BK=64).
__global__ __launch_bounds__(256)
void sgemm_exp_k(const u16* __restrict__ Qpk, const u16* __restrict__ Kpk,
                 const u16* __restrict__ ErT,
                 u16* __restrict__ S, float* __restrict__ rowsum, float scale)
{
    constexpr int MI = 4, NJ = 4;
    const int i0 = blockIdx.x;
    const int x  = i0 & 7;
    const int j0 = i0 >> 3;            // 0..127
    const int z  = x + 8 * (j0 & 1);   // plane
    const int t  = j0 >> 1;            // 0..63
    const int bx = t & 7, by = t >> 3;

    const u16* Aq = Qpk + (long long)z * 262144;
    const u16* Bk = Kpk + (long long)z * 262144;
    S += (long long)z * M1;
    rowsum += z << 10;

    __shared__ u16 As[128 * 64];
    __shared__ u16 Bs[128 * 64];

    const int m0 = by * 128;
    const int n0 = bx * 128;

    const int lane = threadIdx.x & 63;
    const int w    = threadIdx.x >> 6;
    const int wm   = (w >> 1) * 64;
    const int wn   = (w & 1) * 64;
    const int srow = lane >> 2;
    const int scol = (lane & 3) * 8;

    floatx4 acc[MI][NJ];
    #pragma unroll
    for (int i = 0; i < MI; i++)
        #pragma unroll
        for (int j = 0; j < NJ; j++)
            acc[i][j] = floatx4{0.f, 0.f, 0.f, 0.f};

    // half 1: k in [0,256) — A from Qpk, B from Kpk
    for (int k0 = 0; k0 < 256; k0 += 64) {
        #pragma unroll
        for (int r = 0; r < 4; r++) {
            const int inst = w * 4 + r;
            const int rg = inst >> 1, kb = inst & 1;
            const int cb = k0 + kb * 32;
            async_cp16(Aq + (long long)(m0 + rg * 16 + srow) * 256 + cb + scol,
                       &As[(rg * 2 + kb) * 512]);
            async_cp16(Bk + (long long)(n0 + rg * 16 + srow) * 256 + cb + scol,
                       &Bs[(rg * 2 + kb) * 512]);
        }
        SGEMM_MMA_STEP(2)
    }
    // half 2: k in [256,512) — A from ErT (shared, L2-hot), B from Qpk
    for (int k0 = 0; k0 < 256; k0 += 64) {
        #pragma unroll
        for (int r = 0; r < 4; r++) {
            const int inst = w * 4 + r;
            const int rg = inst >> 1, kb = inst & 1;
            const int cb = k0 + kb * 32;
            async_cp16(ErT + (long long)(m0 + rg * 16 + srow) * 256 + cb + scol,
                       &As[(rg * 2 + kb) * 512]);
            async_cp16(Aq + (long long)(n0 + rg * 16 + srow) * 256 + cb + scol,
                       &Bs[(rg * 2 + kb) * 512]);
        }
        SGEMM_MMA_STEP(2)
    }

    const int cn    = n0 + wn + (lane & 15);
    const int rbase = m0 + wm + (lane >> 4) * 4;
    #pragma unroll
    for (int i = 0; i < MI; i++)
        #pragma unroll
        for (int r = 0; r < 4; r++) {
            const int m = rbase + i * 16 + r;
            float part = 0.f;
            #pragma unroll
            for (int j = 0; j < NJ; j++) {
                const int n = cn + j * 16;
                float e = __expf(acc[i][j][r] * scale);
                S[(long long)m * 1024 + n] = f2bf(e);
                part += e;
            }
            #pragma unroll
            for (int off = 8; off; off >>= 1) part += __shfl_xor(part, off, 64);
            if ((lane & 15) == 0) atomicAdd(&rowsum[m], part);
        }
}

// AO GEMM + rowsum divide, plane->XCD affinity (grid 512 1-D), BK=128
// (8 barrier pairs instead of 16; LDS 48KB, 2 blk/CU grid-limited anyway).
__global__ __launch_bounds__(256)
void aogemm_k(const u16* __restrict__ Sb, const u16* __restrict__ Vt,
              const float* __restrict__ rowsum, u16* __restrict__ AO)
{
    constexpr int MI = 4, NJ = 2;
    const int i0 = blockIdx.x;
    const int x  = i0 & 7;
    const int j0 = i0 >> 3;            // 0..63
    const int z  = x + 8 * (j0 & 1);
    const int t  = j0 >> 1;            // 0..31
    const int bx = t & 3, by = t >> 2;

    Sb += (long long)z * M1;
    Vt += (long long)z * 262144;
    rowsum += z << 10;
    const long long zc = (long long)(z >> 2) * M1 + (z & 3) * 256;

    __shared__ u16 As[128 * 128];
    __shared__ u16 Bs[64 * 128];

    const int m0 = by * 128;
    const int n0 = bx * 64;

    const int lane = threadIdx.x & 63;
    const int w    = threadIdx.x >> 6;
    const int wm   = (w >> 1) * 64;
    const int wn   = (w & 1) * 32;
    const int srow = lane >> 2;
    const int scol = (lane & 3) * 8;

    floatx4 acc[MI][NJ];
    #pragma unroll
    for (int i = 0; i < MI; i++)
        #pragma unroll
        for (int j = 0; j < NJ; j++)
            acc[i][j] = floatx4{0.f, 0.f, 0.f, 0.f};

    for (int k0 = 0; k0 < 1024; k0 += 128) {
        #pragma unroll
        for (int r = 0; r < 8; r++) {
            const int inst = w * 8 + r;
            const int rg = inst >> 2, kb = inst & 3;
            async_cp16(Sb + (long long)(m0 + rg * 16 + srow) * 1024 + k0 + kb * 32 + scol,
                       &As[(rg * 4 + kb) * 512]);
        }
        #pragma unroll
        for (int r = 0; r < 4; r++) {
            const int inst = w * 4 + r;
            const int rg = inst >> 2, kb = inst & 3;
            async_cp16(Vt + (long long)(n0 + rg * 16 + srow) * 1024 + k0 + kb * 32 + scol,
                       &Bs[(rg * 4 + kb) * 512]);
        }
        SGEMM_MMA_STEP(4)
    }

    const int cn    = n0 + wn + (lane & 15);
    const int rbase = m0 + wm + (lane >> 4) * 4;
    #pragma unroll
    for (int i = 0; i < MI; i++)
        #pragma unroll
        for (int r = 0; r < 4; r++) {
            const int m = rbase + i * 16 + r;
            const float inv = 1.f / rowsum[m];
            #pragma unroll
            for (int j = 0; j < NJ; j++) {
                const int n = cn + j * 16;
                AO[zc + (long long)m * 1024 + n] = f2bf(acc[i][j][r] * inv);
            }
        }
}

// ---------------------------------------------------------------------------
// LayerNorm: bf16 in -> bf16 out. One block per row.
__global__ __launch_bounds__(256)
void ln_bf_k(const u16* __restrict__ in, u16* __restrict__ out,
             const float* __restrict__ g, const float* __restrict__ b)
{
    long long row = blockIdx.x;
    int tid = threadIdx.x;
    ushort4 u = ((const ushort4*)(in + (row << 10)))[tid];
    float x0 = bf2f(u.x), x1 = bf2f(u.y), x2 = bf2f(u.z), x3 = bf2f(u.w);
    float s = x0 + x1 + x2 + x3;
    s = block_sum(s);
    float mean = s * (1.f / 1024.f);
    float dx = x0 - mean, dy = x1 - mean, dz = x2 - mean, dw = x3 - mean;
    float s2 = dx * dx + dy * dy + dz * dz + dw * dw;
    s2 = block_sum(s2);
    float inv = rsqrtf(s2 * (1.f / 1024.f) + 1e-5f);
    float4 gg = ((const float4*)g)[tid];
    float4 bb = ((const float4*)b)[tid];
    ushort4 o;
    o.x = f2bf(dx * inv * gg.x + bb.x);
    o.y = f2bf(dy * inv * gg.y + bb.y);
    o.z = f2bf(dz * inv * gg.z + bb.z);
    o.w = f2bf(dw * inv * gg.w + bb.w);
    ((ushort4*)(out + (row << 10)))[tid] = o;
}

// LayerNorm over (SBL + [SBR | 0]): SBR covers cols [0,512).
__global__ __launch_bounds__(256)
void ln_add_bf_k(const u16* __restrict__ inL, const u16* __restrict__ inR,
                 u16* __restrict__ out,
                 const float* __restrict__ g, const float* __restrict__ b)
{
    long long row = blockIdx.x;
    int tid = threadIdx.x;
    ushort4 u = ((const ushort4*)(inL + (row << 10)))[tid];
    float x0 = bf2f(u.x), x1 = bf2f(u.y), x2 = bf2f(u.z), x3 = bf2f(u.w);
    if (tid < 128) {
        ushort4 v = ((const ushort4*)(inR + (row << 9)))[tid];
        x0 += bf2f(v.x); x1 += bf2f(v.y); x2 += bf2f(v.z); x3 += bf2f(v.w);
    }
    float s = x0 + x1 + x2 + x3;
    s = block_sum(s);
    float mean = s * (1.f / 1024.f);
    float dx = x0 - mean, dy = x1 - mean, dz = x2 - mean, dw = x3 - mean;
    float s2 = dx * dx + dy * dy + dz * dz + dw * dw;
    s2 = block_sum(s2);
    float inv = rsqrtf(s2 * (1.f / 1024.f) + 1e-5f);
    float4 gg = ((const float4*)g)[tid];
    float4 bb = ((const float4*)b)[tid];
    ushort4 o;
    o.x = f2bf(dx * inv * gg.x + bb.x);
    o.y = f2bf(dy * inv * gg.y + bb.y);
    o.z = f2bf(dz * inv * gg.z + bb.z);
    o.w = f2bf(dw * inv * gg.w + bb.w);
    ((ushort4*)(out + (row << 10)))[tid] = o;
}

// ---------------------------------------------------------------------------
// Vectorized depthwise conv along t (k=7, pad 3), 8 f per thread.
__device__ __forceinline__ void dconv7_vec8(
    const u16* __restrict__ in, u16* __restrict__ out,
    const float* __restrict__ wtr, int gidx)
{
    const int f8 = (gidx & 127) * 8;
    const int bt = gidx >> 7;
    const int t  = bt & 1023;
    const long long rowbase = (long long)(bt - t) * 1024;  // b*1024*1024
    float acc[8] = {0.f, 0.f, 0.f, 0.f, 0.f, 0.f, 0.f, 0.f};
    #pragma unroll
    for (int k = 0; k < 7; k++) {
        int tt = t + k - 3;
        if (tt >= 0 && tt < 1024) {
            short8 v = *(const short8*)&in[rowbase + (long long)tt * 1024 + f8];
            float4 wa = *(const float4*)&wtr[k * 1024 + f8];
            float4 wb = *(const float4*)&wtr[k * 1024 + f8 + 4];
            acc[0] += bf2f((u16)v[0]) * wa.x;
            acc[1] += bf2f((u16)v[1]) * wa.y;
            acc[2] += bf2f((u16)v[2]) * wa.z;
            acc[3] += bf2f((u16)v[3]) * wa.w;
            acc[4] += bf2f((u16)v[4]) * wb.x;
            acc[5] += bf2f((u16)v[5]) * wb.y;
            acc[6] += bf2f((u16)v[6]) * wb.z;
            acc[7] += bf2f((u16)v[7]) * wb.w;
        }
    }
    short8 o;
    #pragma unroll
    for (int i = 0; i < 8; i++) o[i] = (short)f2bf(acc[i]);
    *(short8*)&out[(long long)bt * 1024 + f8] = o;
}

// XCD chunk swizzle for 2048-block tap-windowed kernels (2048 = 8 * 256).
__device__ __forceinline__ int xcd_chunk2048(int bid) {
    return (bid & 7) * 256 + (bid >> 3);
}

// ---------------------------------------------------------------------------
// Fused weight prep + input projection.
struct CastArgs {
    const float* s[10];
    const float* er; const float* qb; const float* kb; const float* vb;
    const float* dwR; const float* dwM; const float* dwQ;   // k=7 dconv weights
    u16* ert; float* qkvb; float* wtr;                      // wtr: 3x[7][1024]
};
__global__ __launch_bounds__(256)
void castin_k(CastArgs a, u16* __restrict__ dst,
              const float* __restrict__ src, const float* __restrict__ inw,
              u16* __restrict__ X)
{
    const int bid = blockIdx.x;
    if (bid < 24576) {
        const int sz[10] = {2097152, 1048576, 524288, 1048576, 1048576,
                            1048576, 1048576, 1048576, 2097152, 2097152};
        int seg = bid >> 11;
        int tid = (bid & 2047) * 256 + threadIdx.x;
        if (seg < 10) {
            int n = sz[seg];
            int base = 0;
            for (int i = 0; i < seg; i++) base += sz[i];
            int i4 = tid * 4;
            if (i4 >= n) return;
            float4 v = *(const float4*)(a.s[seg] + i4);
            ushort4 o;
            o.x = f2bf(v.x); o.y = f2bf(v.y); o.z = f2bf(v.z); o.w = f2bf(v.w);
            *(ushort4*)(dst + base + i4) = o;
        } else if (seg == 10) {
            if (tid < 262144) {
                int j = tid >> 8, d = tid & 255;
                a.ert[tid] = f2bf(a.er[d * 1024 + j]);
            }
        } else {
            if (tid < 1024) a.qkvb[tid] = a.qb[tid];
            else if (tid < 2048) a.qkvb[tid] = a.kb[tid - 1024];
            else if (tid < 3072) a.qkvb[tid] = a.vb[tid - 2048];
            else if (tid < 3072 + 21504) {
                int i = tid - 3072;
                int tbl = i / 7168, r = i - tbl * 7168;
                int k = r >> 10, f = r & 1023;
                const float* s = (tbl == 0) ? a.dwR : (tbl == 1) ? a.dwM : a.dwQ;
                a.wtr[tbl * 7168 + k * 1024 + f] = s[f * 7 + k];
            }
        }
    } else {
        __shared__ float tile[32][33];
        int ib = bid - 24576;
        int f0 = (ib & 31) * 32, t0 = ((ib >> 5) & 31) * 32, b = ib >> 10;
        int tx = threadIdx.x & 31, ty = threadIdx.x >> 5;
        float w0 = inw[0], w1 = inw[1];
        for (int r = ty; r < 32; r += 8) {
            int f = f0 + r, t = t0 + tx;
            float s0 = src[(((long long)b * 2 + 0) * 1025 + f) * 1024 + t];
            float s1 = src[(((long long)b * 2 + 1) * 1025 + f) * 1024 + t];
            tile[r][tx] = w0 * s0 + w1 * s1;
        }
        __syncthreads();
        for (int r = ty; r < 32; r += 8)
            X[((long long)b * 1024 + t0 + r) * 1024 + f0 + tx] = f2bf(tile[tx][r]);
    }
}

// ---------------------------------------------------------------------------
// Fused dconvF (k=11, along f, LDS tiles) + vectorized dconvT (XCD-chunked).
__global__ __launch_bounds__(256)
void dconvFT_k(const u16* __restrict__ in, u16* __restrict__ outT,
               const float* __restrict__ wtrT, u16* __restrict__ outF,
               const float* __restrict__ wF)
{
    const int bid = blockIdx.x;
    if (bid < 2048) {
        dconv7_vec8(in, outT, wtrT, xcd_chunk2048(bid) * 256 + threadIdx.x);
    } else {
        __shared__ float itile[32][44];
        __shared__ float otile[32][33];
        int ib = bid - 2048;
        int f0 = (ib & 31) * 32, t0 = ((ib >> 5) & 31) * 32, b = ib >> 10;
        int tx = threadIdx.x & 31, ty = threadIdx.x >> 5;
        for (int r = ty; r < 32; r += 8)
            for (int c = tx; c < 42; c += 32) {
                int f = f0 - 5 + c;
                itile[r][c] = (f >= 0 && f < 1024)
                    ? bf2f(in[((long long)(b * 1024 + t0 + r)) * 1024 + f]) : 0.f;
            }
        __syncthreads();
        for (int r = ty; r < 32; r += 8) {
            const float* wr = wF + (t0 + r) * 11;
            float acc = 0.f;
            #pragma unroll
            for (int k = 0; k < 11; k++) acc += itile[r][tx + k] * wr[k];
            otile[tx][r] = acc;
        }
        __syncthreads();
        for (int r = ty; r < 32; r += 8)
            outF[((long long)(b * 1024 + f0 + r)) * 1024 + t0 + tx] = f2bf(otile[r][tx]);
    }
}

// Vectorized dconv along t (k=7 pad 3), bf16, XCD-chunked. grid 2048.
__global__ __launch_bounds__(256)
void dconvT_bf_k(const u16* __restrict__ in, u16* __restrict__ out,
                 const float* __restrict__ wtr)
{
    dconv7_vec8(in, out, wtr, xcd_chunk2048(blockIdx.x) * 256 + threadIdx.x);
}

// ---------------------------------------------------------------------------
// Fused QKV post-processing.
__global__ __launch_bounds__(256)
void qkvpack_k(const u16* __restrict__ T3, const float* __restrict__ w,
               const float* __restrict__ wtrQ, const float* __restrict__ bias,
               u16* __restrict__ Qpk, u16* __restrict__ Kpk,
               u16* __restrict__ Vt, float* __restrict__ rowsum)
{
    const int bid = blockIdx.x;
    if (bid < 2048) {
        const int gidx = xcd_chunk2048(bid) * 256 + threadIdx.x;   // 0..524287
        const int f8 = (gidx & 127) * 8;
        const int t  = (gidx >> 7) & 1023;
        const int b  = gidx >> 17;
        float4 b0 = *(const float4*)&bias[f8];
        float4 b1 = *(const float4*)&bias[f8 + 4];
        float aq[8] = {b0.x, b0.y, b0.z, b0.w, b1.x, b1.y, b1.z, b1.w};
        float ak[8] = {b0.x, b0.y, b0.z, b0.w, b1.x, b1.y, b1.z, b1.w};
        #pragma unroll
        for (int k = 0; k < 7; k++) {
            int tt = t + k - 3;
            if (tt >= 0 && tt < 1024) {
                const u16* row = T3 + ((long long)((b << 10) + tt)) * 3072 + f8;
                short8 vq = *(const short8*)&row[0];
                short8 vk = *(const short8*)&row[1024];
                float4 wa = *(const float4*)&wtrQ[k * 1024 + f8];
                float4 wb = *(const float4*)&wtrQ[k * 1024 + f8 + 4];
                aq[0] += bf2f((u16)vq[0]) * wa.x;  ak[0] += bf2f((u16)vk[0]) * wa.x;
                aq[1] += bf2f((u16)vq[1]) * wa.y;  ak[1] += bf2f((u16)vk[1]) * wa.y;
                aq[2] += bf2f((u16)vq[2]) * wa.z;  ak[2] += bf2f((u16)vk[2]) * wa.z;
                aq[3] += bf2f((u16)vq[3]) * wa.w;  ak[3] += bf2f((u16)vk[3]) * wa.w;
                aq[4] += bf2f((u16)vq[4]) * wb.x;  ak[4] += bf2f((u16)vk[4]) * wb.x;
                aq[5] += bf2f((u16)vq[5]) * wb.y;  ak[5] += bf2f((u16)vk[5]) * wb.y;
                aq[6] += bf2f((u16)vq[6]) * wb.z;  ak[6] += bf2f((u16)vk[6]) * wb.z;
                aq[7] += bf2f((u16)vq[7]) * wb.w;  ak[7] += bf2f((u16)vk[7]) * wb.w;
            }
        }
        const int band = f8 >> 8, d = f8 & 255, z = (b << 2) | band;
        const long long base = (long long)z * 262144 + t * 256 + d;
        short8 oq, ok;
        #pragma unroll
        for (int i = 0; i < 8; i++) {
            oq[i] = (short)f2bf(aq[i]);
            ok[i] = (short)f2bf(ak[i]);
        }
        *(short8*)&Qpk[base] = oq;
        *(short8*)&Kpk[base] = ok;
    } else if (bid < 6144) {
        __shared__ float itile[38][32];
        __shared__ float otile[32][33];
        int vb = bid - 2048;
        int f0 = (vb & 31) * 32, t0 = ((vb >> 5) & 31) * 32, b = vb >> 10;
        int tx = threadIdx.x & 31, ty = threadIdx.x >> 5;
        for (int i = threadIdx.x; i < 38 * 32; i += 256) {
            int r = i >> 5, c = i & 31;
            int t = t0 - 3 + r;
            itile[r][c] = (t >= 0 && t < 1024)
                ? bf2f(T3[((long long)(b * 1024 + t)) * 3072 + 2048 + f0 + c]) : 0.f;
        }
        __syncthreads();
        for (int r = ty; r < 32; r += 8) {
            const float* wr = w + (f0 + tx) * 7;
            float acc = bias[f0 + tx];
            #pragma unroll
            for (int k = 0; k < 7; k++) acc += itile[r + k][tx] * wr[k];
            otile[tx][r] = acc;
        }
        __syncthreads();
        for (int r = ty; r < 32; r += 8)
            Vt[((long long)(b * 1024 + f0 + r)) * 1024 + t0 + tx] = f2bf(otile[r][tx]);
    } else {
        int i = (bid - 6144) * 256 + threadIdx.x;  // 16384 floats
        rowsum[i] = 0.f;
    }
}

// Output head: reads bf16 X.
__global__ __launch_bounds__(256)
void out_k(const float* __restrict__ src, const u16* __restrict__ X,
           const float* __restrict__ ow, float* __restrict__ out)
{
    __shared__ float tile[32][33];
    int b = blockIdx.z;
    int f0 = blockIdx.y * 32, t0 = blockIdx.x * 32;
    for (int r = threadIdx.y; r < 32; r += 8)
        tile[r][threadIdx.x] = bf2f(X[((long long)b * 1024 + t0 + r) * 1024 + f0 + threadIdx.x]);
    __syncthreads();
    float w00 = ow[0], w01 = ow[1], w02 = ow[2];
    float w10 = ow[3], w11 = ow[4], w12 = ow[5];
    for (int r = threadIdx.y; r < 32; r += 8) {
        int f = f0 + r, t = t0 + threadIdx.x;
        float s0 = src[(((long long)b * 2 + 0) * 1025 + f) * 1024 + t];
        float s1 = src[(((long long)b * 2 + 1) * 1025 + f) * 1024 + t];
        float xv = tile[threadIdx.x][r];
        float v0 = fminf(fmaxf(w00 * s0 + w01 * s1 + w02 * xv, 0.f), 6.f) * (1.f / 6.f);
        float v1 = fminf(fmaxf(w10 * s0 + w11 * s1 + w12 * xv, 0.f), 6.f) * (1.f / 6.f);
        out[(((long long)b * 2 + 0) * 1025 + f) * 1024 + t] = v0;
        out[(((long long)b * 2 + 1) * 1025 + f) * 1024 + t] = v1;
        if (f == 1023) {
            out[(((long long)b * 2 + 0) * 1025 + 1024) * 1024 + t] = v0;
            out[(((long long)b * 2 + 1) * 1025 + 1024) * 1024 + t] = v1;
        }
    }
}

// ---------------------------------------------------------------------------
extern "C" void kernel_launch(void* const* d_in, const int* in_sizes, int n_in,
                              void* d_out, int out_size, void* d_ws, size_t ws_size,
                              hipStream_t stream)
{
    const float* src    = (const float*)d_in[0];
    const float* in_w   = (const float*)d_in[1];
    const float* ln1_g  = (const float*)d_in[2];
    const float* ln1_b  = (const float*)d_in[3];
    const float* glu_w  = (const float*)d_in[4];
    const float* ln2_g  = (const float*)d_in[5];
    const float* ln2_b  = (const float*)d_in[6];
    const float* c1L_dw = (const float*)d_in[7];
    const float* c1L_pw = (const float*)d_in[8];
    const float* c1R_dw = (const float*)d_in[9];
    const float* c1R_pw = (const float*)d_in[10];
    const float* ln3_g  = (const float*)d_in[11];
    const float* ln3_b  = (const float*)d_in[12];
    const float* c1M_dw = (const float*)d_in[13];
    const float* c1M_pw = (const float*)d_in[14];
    const float* ln4_g  = (const float*)d_in[15];
    const float* ln4_b  = (const float*)d_in[16];
    const float* q_w    = (const float*)d_in[17];
    const float* q_b    = (const float*)d_in[18];
    const float* qc_w   = (const float*)d_in[19];
    const float* qc_b   = (const float*)d_in[20];
    const float* k_w    = (const float*)d_in[21];
    const float* k_b    = (const float*)d_in[22];
    const float* v_w    = (const float*)d_in[23];
    const float* v_b    = (const float*)d_in[24];
    const float* o_w    = (const float*)d_in[25];
    const float* o_b    = (const float*)d_in[26];
    const float* er     = (const float*)d_in[27];
    const float* ln5_g  = (const float*)d_in[28];
    const float* ln5_b  = (const float*)d_in[29];
    const float* c2_w   = (const float*)d_in[30];
    const float* c3_w   = (const float*)d_in[31];
    const float* out_w  = (const float*)d_in[32];
    float* out = (float*)d_out;

    const size_t MB = 1ull << 20;
    if (ws_size < 162 * MB) return;
    char* wsb = (char*)d_ws;
    u16* X       = (u16*)(wsb + 0);           // 8 MB bf16 residual
    u16* SB      = (u16*)(wsb + 8 * MB);      // 8 MB bf16 hL (SBL)
    float* rowsum= (float*)(wsb + 16 * MB);   // 64 KB (free window, no alias)
    u16* SBR     = (u16*)(wsb + 24 * MB);     // 4 MB bf16 hR (4096x512)
    u16* Qpk     = (u16*)(wsb + 32 * MB);     // 8 MB q-pack (z,t,256)
    u16* Kpk     = (u16*)(wsb + 40 * MB);     // 8 MB k-pack (z,t,256)
    u16* Hbf     = (u16*)(wsb + 64 * MB);     // 8 MB ln outputs
    u16* T1bf    = (u16*)(wsb + 72 * MB);     // 8 MB dconv temps
    u16* T3      = (u16*)(wsb + 72 * MB);     // 24 MB QKV (4096x3072)
    u16* AO      = (u16*)(wsb + 80 * MB);     // 8 MB AO (B,T,F)
    u16* T2bf    = (u16*)(wsb + 96 * MB);     // 8 MB dconvF out (c1L)
    u16* Vt      = (u16*)(wsb + 96 * MB);     // reuse: 8 MB V^T (b,f,t)
    u16* Sbf     = (u16*)(wsb + 104 * MB);    // 32 MB scores (16,1024,1024)
    u16* Gbf     = (u16*)(wsb + 104 * MB);    // reuse: 16 MB ffn mid
    u16* W0      = (u16*)(wsb + 136 * MB);    // bf16 weights

    u16* glu_wb  = W0;
    u16* c1L_pwb = W0 + 2097152;
    u16* c1R_pwb = W0 + 3145728;
    u16* c1M_pwb = W0 + 3670016;
    u16* qkv_wb  = W0 + 4718592;   // q,k,v contiguous (3072 x 1024)
    u16* o_wb    = W0 + 7864320;
    u16* c2_wb   = W0 + 8912896;
    u16* c3_wb   = W0 + 11010048;
    u16* ertb    = W0 + 13107200;  // 262144 (t-major er transpose, shared)
    float* qkvb  = (float*)(W0 + 13369344);  // 3072 fp32
    float* wtrb  = qkvb + 3072;    // 3 x 7168 fp32 transposed dconv weights
    float* wtrR  = wtrb;           // c1R_dw  [7][1024]
    float* wtrM  = wtrb + 7168;    // c1M_dw  [7][1024]
    float* wtrQ  = wtrb + 14336;   // qc_w    [7][1024]

    const dim3 blk256(256);
    const dim3 tgrid(32, 32, NB);
    const dim3 tblk(32, 8);

    // --- 1. weight prep + input projection (fused, independent work) ---
    CastArgs ca;
    ca.s[0] = glu_w;  ca.s[1] = c1L_pw; ca.s[2] = c1R_pw; ca.s[3] = c1M_pw;
    ca.s[4] = q_w;    ca.s[5] = k_w;    ca.s[6] = v_w;    ca.s[7] = o_w;
    ca.s[8] = c2_w;   ca.s[9] = c3_w;
    ca.er = er; ca.qb = q_b; ca.kb = k_b; ca.vb = v_b;
    ca.dwR = c1R_dw; ca.dwM = c1M_dw; ca.dwQ = qc_w;
    ca.ert = ertb; ca.qkvb = qkvb; ca.wtr = wtrb;
    castin_k<<<28672, blk256, 0, stream>>>(ca, W0, src, in_w, X);

    // 2-4. h = ln1(x); x += glu(h @ glu_w^T)  [fused]
    ln_bf_k<<<4096, blk256, 0, stream>>>(X, Hbf, ln1_g, ln1_b);
    glugemm_k<<<dim3(16, 32, 1), blk256, 0, stream>>>(
        Hbf, glu_wb, glu_wb + 1048576, X);
    // 5. h = ln2(x)
    ln_bf_k<<<4096, blk256, 0, stream>>>(X, Hbf, ln2_g, ln2_b);
    // 6. both depthwise convs of h (fused; dconvT vectorized + XCD-chunked)
    dconvFT_k<<<6144, blk256, 0, stream>>>(Hbf, T1bf, wtrR, T2bf, c1L_dw);
    // 7. merged c1L+c1R -> SBL, SBR (independent, 1024 blocks = 4/CU)
    c1lr_k<<<1024, blk256, 0, stream>>>(c1L_pwb, T2bf, T1bf, c1R_pwb, SB, SBR);
    // 8. h = ln3(SBL + [SBR|0])
    ln_add_bf_k<<<4096, blk256, 0, stream>>>(SB, SBR, Hbf, ln3_g, ln3_b);
    // 9-10. x += dconvT(h) @ c1M_pw^T  [128x64 BK=128, 2 blk/CU]
    dconvT_bf_k<<<2048, blk256, 0, stream>>>(Hbf, T1bf, wtrM);
    gemm_bf<128, 64, 128, 0, 3><<<dim3(16, 32, 1), blk256, 0, stream>>>(
        T1bf, c1M_pwb, X, 1024, 1024, 1024, 1024, 0, 0, 0, nullptr, 1.f);
    // 11. h = ln4(x)
    ln_bf_k<<<4096, blk256, 0, stream>>>(X, Hbf, ln4_g, ln4_b);
    // 12. fused QKV GEMM (4096x3072x1024) -> T3 bf16  [128x128 BK=64, 3/CU]
    gemm_bf<128, 128, 64, 0, 2><<<dim3(24, 32, 1), blk256, 0, stream>>>(
        Hbf, qkv_wb, T3, 1024, 1024, 1024, 3072, 0, 0, 0, qkvb, 1.f);
    // 13. qc convs: q/k pack (XCD-chunked) + V transpose + rowsum zero
    qkvpack_k<<<6208, blk256, 0, stream>>>(T3, qc_w, wtrQ, qc_b, Qpk, Kpk, Vt, rowsum);
    // 14. S = exp((QK^T + rel-pos)/32) + rowsum; plane->XCD affinity
    sgemm_exp_k<<<1024, blk256, 0, stream>>>(Qpk, Kpk, ertb, Sbf, rowsum, 0.03125f);
    // 15. AO = (S @ V) / rowsum; plane->XCD affinity; [128x64 BK=128]
    aogemm_k<<<512, blk256, 0, stream>>>(Sbf, Vt, rowsum, AO);
    // 16. x += AO @ o_w^T + o_b  [128x64 BK=128, 2 blk/CU]
    gemm_bf<128, 64, 128, 0, 3><<<dim3(16, 32, 1), blk256, 0, stream>>>(
        AO, o_wb, X, 1024, 1024, 1024, 1024, 0, 0, 0, o_b, 1.f);
    // 17-18. h = ln5(x); mid = relu(h @ c2_w^T)^2  [128x128 BK=64, 2/CU]
    ln_bf_k<<<4096, blk256, 0, stream>>>(X, Hbf, ln5_g, ln5_b);
    gemm_bf<128, 128, 64, 2, 2><<<dim3(16, 32, 1), blk256, 0, stream>>>(
        Hbf, c2_wb, Gbf, 1024, 1024, 1024, 2048, 0, 0, 0, nullptr, 1.f);
    // 19. x += mid @ c3_w^T  [128x64 BK=128, 2 blk/CU]
    gemm_bf<128, 64, 128, 0, 3><<<dim3(16, 32, 1), blk256, 0, stream>>>(
        Gbf, c3_wb, X, 2048, 2048, 2048, 1024, 0, 0, 0, nullptr, 1.f);
    // 20. output head
    out_k<<<tgrid, tblk, 0, stream>>>(src, X, out_w, out);
}